// Round 1
// baseline (1924.965 us; speedup 1.0000x reference)
//
#include <hip/hip_runtime.h>

#define NN 100000
#define NE 1600000
#define NF 128
#define NC 40
#define BN_EPS 1e-5f

// ---------------- CSR build ----------------

__global__ __launch_bounds__(256) void deg_kernel(const int* __restrict__ dst, int* __restrict__ deg) {
    int e = blockIdx.x * blockDim.x + threadIdx.x;
    if (e < NE) atomicAdd(&deg[dst[e]], 1);
}

__global__ __launch_bounds__(1024) void scan_kernel(const int* __restrict__ deg,
                                                    int* __restrict__ row_ptr,
                                                    float* __restrict__ inv_cnt) {
    __shared__ int lds[1024];
    int t = threadIdx.x;
    const int chunk = (NN + 1023) / 1024;  // 98
    int lo = t * chunk;
    int hi = lo + chunk; if (hi > NN) hi = NN;
    int s = 0;
    for (int i = lo; i < hi; ++i) s += deg[i];
    lds[t] = s;
    __syncthreads();
    for (int off = 1; off < 1024; off <<= 1) {
        int v = (t >= off) ? lds[t - off] : 0;
        __syncthreads();
        lds[t] += v;
        __syncthreads();
    }
    int base = lds[t] - s;  // exclusive prefix
    for (int i = lo; i < hi; ++i) {
        int d = deg[i];
        row_ptr[i] = base;
        inv_cnt[i] = 1.0f / (float)(d > 0 ? d : 1);
        base += d;
    }
    if (t == 1023) row_ptr[NN] = base;
}

__global__ __launch_bounds__(256) void fill_kernel(const int* __restrict__ src,
                                                   const int* __restrict__ dst,
                                                   const int* __restrict__ row_ptr,
                                                   int* __restrict__ cursor,
                                                   int* __restrict__ csr) {
    int e = blockIdx.x * blockDim.x + threadIdx.x;
    if (e < NE) {
        int d = dst[e];
        int pos = atomicAdd(&cursor[d], 1);
        csr[row_ptr[d] + pos] = src[e];
    }
}

// ---------------- mean aggregation (gather-reduce over CSR) ----------------

__global__ __launch_bounds__(128) void agg_mean128(const float* __restrict__ X,
                                                   const int* __restrict__ csr,
                                                   const int* __restrict__ row_ptr,
                                                   const float* __restrict__ inv_cnt,
                                                   float* __restrict__ out) {
    int n = blockIdx.x;
    int t = threadIdx.x;
    int s = row_ptr[n], e = row_ptr[n + 1];
    float acc = 0.f;
    int i = s;
    for (; i + 4 <= e; i += 4) {
        int s0 = csr[i], s1 = csr[i + 1], s2 = csr[i + 2], s3 = csr[i + 3];
        acc += X[(size_t)s0 * NF + t];
        acc += X[(size_t)s1 * NF + t];
        acc += X[(size_t)s2 * NF + t];
        acc += X[(size_t)s3 * NF + t];
    }
    for (; i < e; ++i) acc += X[(size_t)csr[i] * NF + t];
    out[(size_t)n * NF + t] = acc * inv_cnt[n];
}

__global__ __launch_bounds__(64) void agg40_add_kernel(const float* __restrict__ T,
                                                       const float* __restrict__ Z,
                                                       const int* __restrict__ csr,
                                                       const int* __restrict__ row_ptr,
                                                       const float* __restrict__ inv_cnt,
                                                       float* __restrict__ out) {
    int n = blockIdx.x;
    int t = threadIdx.x;
    if (t >= NC) return;
    int s = row_ptr[n], e = row_ptr[n + 1];
    float acc = 0.f;
    int i = s;
    for (; i + 4 <= e; i += 4) {
        int s0 = csr[i], s1 = csr[i + 1], s2 = csr[i + 2], s3 = csr[i + 3];
        acc += T[(size_t)s0 * NC + t];
        acc += T[(size_t)s1 * NC + t];
        acc += T[(size_t)s2 * NC + t];
        acc += T[(size_t)s3 * NC + t];
    }
    for (; i < e; ++i) acc += T[(size_t)csr[i] * NC + t];
    out[(size_t)n * NC + t] = acc * inv_cnt[n] + Z[(size_t)n * NC + t];
}

// ---------------- dense: OUT = A@Wl.T + X@Wr.T + b (opt relu) ----------------
// Block: 256 threads -> 32 rows x 128 cols tile. Thread: 4 rows x 4 cols.
// In-place over A is safe: block stages its own 32 rows of A/X in LDS first.

template <bool RELU>
__global__ __launch_bounds__(256) void lin128_kernel(const float* A, const float* X,
                                                     const float* __restrict__ Wl,
                                                     const float* __restrict__ Wr,
                                                     const float* __restrict__ b,
                                                     float* out) {
    __shared__ float ldsA[32 * NF];
    __shared__ float ldsX[32 * NF];
    int tid = threadIdx.x;
    int R0 = blockIdx.x * 32;

    const float4* A4 = (const float4*)(A + (size_t)R0 * NF);
    const float4* X4 = (const float4*)(X + (size_t)R0 * NF);
    float4* lA4 = (float4*)ldsA;
    float4* lX4 = (float4*)ldsX;
#pragma unroll
    for (int v = 0; v < 4; ++v) {
        int fi = tid + v * 256;  // 1024 float4 = 32x128 floats
        lA4[fi] = A4[fi];
        lX4[fi] = X4[fi];
    }
    __syncthreads();

    int tx = tid & 31;  // col group: cols 4*tx..4*tx+3
    int ty = tid >> 5;  // 0..7: rows 4*ty..4*ty+3
    int jb = tx * 4;
    int rb = ty * 4;

    float acc[4][4];
#pragma unroll
    for (int r = 0; r < 4; ++r)
#pragma unroll
        for (int j = 0; j < 4; ++j) acc[r][j] = 0.f;

    for (int k4 = 0; k4 < NF / 4; ++k4) {
        float4 wl[4], wr[4];
#pragma unroll
        for (int jj = 0; jj < 4; ++jj) {
            wl[jj] = *(const float4*)&Wl[(size_t)(jb + jj) * NF + k4 * 4];
            wr[jj] = *(const float4*)&Wr[(size_t)(jb + jj) * NF + k4 * 4];
        }
#pragma unroll
        for (int rr = 0; rr < 4; ++rr) {
            float4 a = *(const float4*)&ldsA[(rb + rr) * NF + k4 * 4];
            float4 xv = *(const float4*)&ldsX[(rb + rr) * NF + k4 * 4];
#pragma unroll
            for (int jj = 0; jj < 4; ++jj) {
                acc[rr][jj] += a.x * wl[jj].x + a.y * wl[jj].y + a.z * wl[jj].z + a.w * wl[jj].w;
                acc[rr][jj] += xv.x * wr[jj].x + xv.y * wr[jj].y + xv.z * wr[jj].z + xv.w * wr[jj].w;
            }
        }
    }

    float4 bv = *(const float4*)&b[jb];
#pragma unroll
    for (int rr = 0; rr < 4; ++rr) {
        float4 o;
        o.x = acc[rr][0] + bv.x;
        o.y = acc[rr][1] + bv.y;
        o.z = acc[rr][2] + bv.z;
        o.w = acc[rr][3] + bv.w;
        if (RELU) {
            o.x = fmaxf(o.x, 0.f); o.y = fmaxf(o.y, 0.f);
            o.z = fmaxf(o.z, 0.f); o.w = fmaxf(o.w, 0.f);
        }
        *(float4*)&out[(size_t)(R0 + rb + rr) * NF + jb] = o;
    }
}

// conv2 dense: out1 = X@W2l.T (to be aggregated), out2 = X@W2r.T + b2
// Block: 256 threads -> 16 rows x 40 cols (64 col-lanes, 40 active).
__global__ __launch_bounds__(256) void lin40x2_kernel(const float* __restrict__ X,
                                                      const float* __restrict__ Wl,
                                                      const float* __restrict__ Wr,
                                                      const float* __restrict__ b,
                                                      float* __restrict__ out1,
                                                      float* __restrict__ out2) {
    __shared__ float ldsX[16 * NF];
    int tid = threadIdx.x;
    int R0 = blockIdx.x * 16;
    const float4* X4 = (const float4*)(X + (size_t)R0 * NF);
    float4* lX4 = (float4*)ldsX;
    lX4[tid] = X4[tid];
    lX4[tid + 256] = X4[tid + 256];
    __syncthreads();

    int j = tid & 63;
    int ty = tid >> 6;  // 0..3
    bool act = (j < NC);
    int jc = act ? j : 0;

    float acc1[4] = {0.f, 0.f, 0.f, 0.f};
    float acc2[4] = {0.f, 0.f, 0.f, 0.f};
    for (int k4 = 0; k4 < NF / 4; ++k4) {
        float4 wl = *(const float4*)&Wl[(size_t)jc * NF + k4 * 4];
        float4 wr = *(const float4*)&Wr[(size_t)jc * NF + k4 * 4];
#pragma unroll
        for (int rr = 0; rr < 4; ++rr) {
            float4 xv = *(const float4*)&ldsX[(ty + rr * 4) * NF + k4 * 4];
            acc1[rr] += xv.x * wl.x + xv.y * wl.y + xv.z * wl.z + xv.w * wl.w;
            acc2[rr] += xv.x * wr.x + xv.y * wr.y + xv.z * wr.z + xv.w * wr.w;
        }
    }
    if (act) {
        float bj = b[j];
#pragma unroll
        for (int rr = 0; rr < 4; ++rr) {
            int r = R0 + ty + rr * 4;
            out1[(size_t)r * NC + j] = acc1[rr];
            out2[(size_t)r * NC + j] = acc2[rr] + bj;
        }
    }
}

// ---------------- batch norm (training-mode, biased var) ----------------

__global__ void bn_stats_kernel(const float* __restrict__ X, float* __restrict__ sums, int F) {
    int t = threadIdx.x;
    if (t >= F) return;
    float s = 0.f, s2 = 0.f;
    for (int r = blockIdx.x; r < NN; r += gridDim.x) {
        float v = X[(size_t)r * F + t];
        s += v;
        s2 += v * v;
    }
    atomicAdd(&sums[t], s);
    atomicAdd(&sums[F + t], s2);
}

template <bool RELU>
__global__ __launch_bounds__(256) void bn_apply_kernel(float* __restrict__ X,
                                                       const float* __restrict__ sums,
                                                       const float* __restrict__ g,
                                                       const float* __restrict__ be,
                                                       int F, float invN) {
    size_t idx = (size_t)blockIdx.x * blockDim.x + threadIdx.x;
    size_t total = (size_t)NN * F;
    if (idx >= total) return;
    int t = (int)(idx % F);
    float mu = sums[t] * invN;
    float var = sums[F + t] * invN - mu * mu;
    float scale = rsqrtf(var + BN_EPS) * g[t];
    float v = (X[idx] - mu) * scale + be[t];
    if (RELU) v = fmaxf(v, 0.f);
    X[idx] = v;
}

// ---------------- launch ----------------

extern "C" void kernel_launch(void* const* d_in, const int* in_sizes, int n_in,
                              void* d_out, int out_size, void* d_ws, size_t ws_size,
                              hipStream_t stream) {
    const float* x   = (const float*)d_in[0];
    const int*   ei  = (const int*)d_in[1];
    const int*   srcv = ei;
    const int*   dstv = ei + NE;
    const float* W1l = (const float*)d_in[2];
    const float* b1  = (const float*)d_in[3];
    const float* W1r = (const float*)d_in[4];
    const float* Wxl = (const float*)d_in[5];
    const float* bx  = (const float*)d_in[6];
    const float* Wxr = (const float*)d_in[7];
    const float* W2l = (const float*)d_in[8];
    const float* b2  = (const float*)d_in[9];
    const float* W2r = (const float*)d_in[10];
    const float* g3  = (const float*)d_in[11];
    const float* be3 = (const float*)d_in[12];
    const float* g2  = (const float*)d_in[13];
    const float* be2 = (const float*)d_in[14];
    float* out = (float*)d_out;

    // workspace carve (all offsets 16B aligned)
    char* w = (char*)d_ws;
    float* h_a = (float*)w; w += (size_t)NN * NF * 4;   // 51.2 MB
    float* h_b = (float*)w; w += (size_t)NN * NF * 4;   // 51.2 MB
    int* csr     = (int*)w; w += (size_t)NE * 4;        // 6.4 MB
    int* row_ptr = (int*)w; w += (size_t)(NN + 4) * 4;
    int* deg     = (int*)w; w += (size_t)NN * 4;
    int* cursor  = (int*)w; w += (size_t)NN * 4;
    float* inv_cnt = (float*)w; w += (size_t)NN * 4;
    float* bnbuf   = (float*)w; w += 2 * NF * 4;

    // ---- CSR build (shared by all three convs) ----
    hipMemsetAsync(deg, 0, (size_t)NN * 4, stream);
    hipMemsetAsync(cursor, 0, (size_t)NN * 4, stream);
    deg_kernel<<<(NE + 255) / 256, 256, 0, stream>>>(dstv, deg);
    scan_kernel<<<1, 1024, 0, stream>>>(deg, row_ptr, inv_cnt);
    fill_kernel<<<(NE + 255) / 256, 256, 0, stream>>>(srcv, dstv, row_ptr, cursor, csr);

    // ---- conv1: h1 = relu(mean(x)@W1l.T + b1 + x@W1r.T) -> h_b ----
    agg_mean128<<<NN, 128, 0, stream>>>(x, csr, row_ptr, inv_cnt, h_b);
    lin128_kernel<true><<<NN / 32, 256, 0, stream>>>(h_b, x, W1l, W1r, b1, h_b);

    // ---- convx: h2 = mean(h1)@Wxl.T + bx + h1@Wxr.T -> h_a ----
    agg_mean128<<<NN, 128, 0, stream>>>(h_b, csr, row_ptr, inv_cnt, h_a);
    lin128_kernel<false><<<NN / 32, 256, 0, stream>>>(h_a, h_b, Wxl, Wxr, bx, h_a);

    // ---- batch_norm3 + relu (in place on h_a) ----
    hipMemsetAsync(bnbuf, 0, 2 * NF * 4, stream);
    bn_stats_kernel<<<256, 128, 0, stream>>>(h_a, bnbuf, NF);
    bn_apply_kernel<true><<<(NN * NF + 255) / 256, 256, 0, stream>>>(h_a, bnbuf, g3, be3, NF, 1.0f / NN);

    // ---- conv2 (transform-first): t40 = h@W2l.T, z40 = h@W2r.T + b2 ----
    float* t40 = h_b;                      // h1 dead; reuse
    float* z40 = h_b + (size_t)NN * NC;
    lin40x2_kernel<<<NN / 16, 256, 0, stream>>>(h_a, W2l, W2r, b2, t40, z40);
    agg40_add_kernel<<<NN, 64, 0, stream>>>(t40, z40, csr, row_ptr, inv_cnt, out);

    // ---- batch_norm2 (in place on out) ----
    hipMemsetAsync(bnbuf, 0, 2 * NC * 4, stream);
    bn_stats_kernel<<<256, 64, 0, stream>>>(out, bnbuf, NC);
    bn_apply_kernel<false><<<(NN * NC + 255) / 256, 256, 0, stream>>>(out, bnbuf, g2, be2, NC, 1.0f / NN);
}

// Round 2
// 1166.867 us; speedup vs baseline: 1.6497x; 1.6497x over previous
//
#include <hip/hip_runtime.h>
#include <hip/hip_bf16.h>

#define NN 100000
#define NE 1600000
#define NF 128
#define NC 40
#define BN_EPS 1e-5f

typedef __attribute__((ext_vector_type(8))) short short8;
typedef __attribute__((ext_vector_type(4))) float float4v;

__device__ __forceinline__ unsigned short f2b(float f) {
    __hip_bfloat16 h = __float2bfloat16(f);
    return *reinterpret_cast<unsigned short*>(&h);
}
__device__ __forceinline__ float b2f_hi(unsigned u) {  // high 16 bits as bf16
    return __uint_as_float(u & 0xffff0000u);
}
__device__ __forceinline__ float b2f_lo(unsigned u) {  // low 16 bits as bf16
    return __uint_as_float(u << 16);
}

// ---------------- CSR build ----------------

__global__ __launch_bounds__(256) void deg_kernel(const int* __restrict__ dst, int* __restrict__ deg) {
    int e = blockIdx.x * blockDim.x + threadIdx.x;
    if (e < NE) atomicAdd(&deg[dst[e]], 1);
}

__global__ __launch_bounds__(1024) void scan_kernel(const int* __restrict__ deg,
                                                    int* __restrict__ row_ptr,
                                                    float* __restrict__ inv_cnt) {
    __shared__ int lds[1024];
    int t = threadIdx.x;
    const int chunk = (NN + 1023) / 1024;  // 98
    int lo = t * chunk;
    int hi = lo + chunk; if (hi > NN) hi = NN;
    int s = 0;
    for (int i = lo; i < hi; ++i) s += deg[i];
    lds[t] = s;
    __syncthreads();
    for (int off = 1; off < 1024; off <<= 1) {
        int v = (t >= off) ? lds[t - off] : 0;
        __syncthreads();
        lds[t] += v;
        __syncthreads();
    }
    int base = lds[t] - s;  // exclusive prefix
    for (int i = lo; i < hi; ++i) {
        int d = deg[i];
        row_ptr[i] = base;
        inv_cnt[i] = 1.0f / (float)(d > 0 ? d : 1);
        base += d;
    }
    if (t == 1023) row_ptr[NN] = base;
}

__global__ __launch_bounds__(256) void fill_kernel(const int* __restrict__ src,
                                                   const int* __restrict__ dst,
                                                   const int* __restrict__ row_ptr,
                                                   int* __restrict__ cursor,
                                                   int* __restrict__ csr) {
    int e = blockIdx.x * blockDim.x + threadIdx.x;
    if (e < NE) {
        int d = dst[e];
        int pos = atomicAdd(&cursor[d], 1);
        csr[row_ptr[d] + pos] = src[e];
    }
}

// ---------------- fp32 -> bf16 bulk convert ----------------

__global__ __launch_bounds__(256) void f2b4_kernel(const float* __restrict__ in,
                                                   unsigned short* __restrict__ out, int n4) {
    int i = blockIdx.x * 256 + threadIdx.x;
    if (i < n4) {
        float4 v = ((const float4*)in)[i];
        ushort4 o;
        o.x = f2b(v.x); o.y = f2b(v.y); o.z = f2b(v.z); o.w = f2b(v.w);
        ((ushort4*)out)[i] = o;
    }
}

// ---------------- pack W into MFMA B-fragment order ----------------
// B[k][n], k in [0,256): k<128 -> Wl[n][k]; k>=128 -> Wr[n][k-128].
// Bp layout: idx = ((kk*8 + nt)*64 + lane)*8 + j
//   n = nt*16 + (lane&15); k = kk*32 + (lane>>4)*8 + j

__global__ __launch_bounds__(64) void pack_w_kernel(const float* __restrict__ Wl,
                                                    const float* __restrict__ Wr,
                                                    unsigned short* __restrict__ Bp) {
    int nt = blockIdx.x & 7;
    int kk = blockIdx.x >> 3;
    int lane = threadIdx.x;
    int n = nt * 16 + (lane & 15);
    int kb = kk * 32 + (lane >> 4) * 8;
    size_t base = ((size_t)(kk * 8 + nt) * 64 + lane) * 8;
#pragma unroll
    for (int j = 0; j < 8; ++j) {
        int k = kb + j;
        float v = (k < NF) ? Wl[(size_t)n * NF + k] : Wr[(size_t)n * NF + (k - NF)];
        Bp[base + j] = f2b(v);
    }
}

// ---------------- mean aggregation over CSR (bf16 table, fp32 accum) ----------------
// one wave per node; lane covers features 2*lane, 2*lane+1 (4B load per lane per edge)

__global__ __launch_bounds__(256) void agg_mean_bf16(const unsigned short* __restrict__ X,
                                                     const int* __restrict__ csr,
                                                     const int* __restrict__ row_ptr,
                                                     const float* __restrict__ inv_cnt,
                                                     unsigned short* __restrict__ out) {
    int wave = threadIdx.x >> 6;
    int lane = threadIdx.x & 63;
    int n = blockIdx.x * 4 + wave;
    if (n >= NN) return;
    int s = row_ptr[n], e = row_ptr[n + 1];
    float a0 = 0.f, a1 = 0.f;
    int i = s;
    for (; i + 4 <= e; i += 4) {
        int s0 = csr[i], s1 = csr[i + 1], s2 = csr[i + 2], s3 = csr[i + 3];
        unsigned u0 = *(const unsigned*)(X + (size_t)s0 * NF + lane * 2);
        unsigned u1 = *(const unsigned*)(X + (size_t)s1 * NF + lane * 2);
        unsigned u2 = *(const unsigned*)(X + (size_t)s2 * NF + lane * 2);
        unsigned u3 = *(const unsigned*)(X + (size_t)s3 * NF + lane * 2);
        a0 += b2f_lo(u0) + b2f_lo(u1) + b2f_lo(u2) + b2f_lo(u3);
        a1 += b2f_hi(u0) + b2f_hi(u1) + b2f_hi(u2) + b2f_hi(u3);
    }
    for (; i < e; ++i) {
        unsigned u = *(const unsigned*)(X + (size_t)csr[i] * NF + lane * 2);
        a0 += b2f_lo(u);
        a1 += b2f_hi(u);
    }
    float ic = inv_cnt[n];
    unsigned short o0 = f2b(a0 * ic), o1 = f2b(a1 * ic);
    *(unsigned*)(out + (size_t)n * NF + lane * 2) = (unsigned)o0 | ((unsigned)o1 << 16);
}

// ---------------- MFMA linear: OUT = [A|X](bf16) @ Bp + bias ----------------
// block = 256 thr = 4 waves; tile 64 rows x 128 cols; K = 256 in 8 steps of 32.
// wave w owns rows [blk*64 + w*16, +16); 8 n-tiles of 16 cols.

template <bool RELU, bool OUT_BF16>
__global__ __launch_bounds__(256) void lin_mfma_kernel(const unsigned short* __restrict__ Ab,
                                                       const unsigned short* __restrict__ Xb,
                                                       const unsigned short* __restrict__ Bp,
                                                       const float* __restrict__ bias,
                                                       unsigned short* __restrict__ outb,
                                                       float* __restrict__ outf) {
    __shared__ unsigned short ldsB[32768];  // 64 KB
    int tid = threadIdx.x;
    {
        const float4* srcp = (const float4*)Bp;
        float4* dstp = (float4*)ldsB;
#pragma unroll
        for (int i = 0; i < 16; ++i) dstp[tid + i * 256] = srcp[tid + i * 256];
    }
    __syncthreads();

    int wave = tid >> 6;
    int lane = tid & 63;
    int quad = lane >> 4;
    int row = blockIdx.x * 64 + wave * 16 + (lane & 15);
    int rowc = row < NN ? row : (NN - 1);
    const unsigned short* arow = Ab + (size_t)rowc * NF;
    const unsigned short* xrow = Xb + (size_t)rowc * NF;

    float4v acc[8];
#pragma unroll
    for (int nt = 0; nt < 8; ++nt) acc[nt] = (float4v){0.f, 0.f, 0.f, 0.f};

#pragma unroll
    for (int kk = 0; kk < 8; ++kk) {
        int kb = (kk & 3) * 32 + quad * 8;
        const unsigned short* asrc = (kk < 4) ? arow : xrow;
        short8 afrag = *(const short8*)(asrc + kb);
#pragma unroll
        for (int nt = 0; nt < 8; ++nt) {
            short8 bfrag = *(const short8*)(ldsB + ((size_t)(kk * 8 + nt) * 64 + lane) * 8);
            acc[nt] = __builtin_amdgcn_mfma_f32_16x16x32_bf16(afrag, bfrag, acc[nt], 0, 0, 0);
        }
    }

    // D: row = blk*64 + wave*16 + quad*4 + r ; col = nt*16 + (lane&15)
    int orow = blockIdx.x * 64 + wave * 16 + quad * 4;
    int col = lane & 15;
#pragma unroll
    for (int nt = 0; nt < 8; ++nt) {
        int c = nt * 16 + col;
        float bv = bias[c];
#pragma unroll
        for (int r = 0; r < 4; ++r) {
            int rr = orow + r;
            if (rr < NN) {
                float v = acc[nt][r] + bv;
                if (RELU) v = fmaxf(v, 0.f);
                if (OUT_BF16) outb[(size_t)rr * NF + c] = f2b(v);
                else outf[(size_t)rr * NF + c] = v;
            }
        }
    }
}

// ---------------- conv2 dense (fp32): out1 = X@W2l.T, out2 = X@W2r.T + b2 ----------------

__global__ __launch_bounds__(256) void lin40x2_kernel(const float* __restrict__ X,
                                                      const float* __restrict__ Wl,
                                                      const float* __restrict__ Wr,
                                                      const float* __restrict__ b,
                                                      float* __restrict__ out1,
                                                      float* __restrict__ out2) {
    __shared__ float ldsX[16 * NF];
    int tid = threadIdx.x;
    int R0 = blockIdx.x * 16;
    const float4* X4 = (const float4*)(X + (size_t)R0 * NF);
    float4* lX4 = (float4*)ldsX;
    lX4[tid] = X4[tid];
    lX4[tid + 256] = X4[tid + 256];
    __syncthreads();

    int j = tid & 63;
    int ty = tid >> 6;  // 0..3
    bool act = (j < NC);
    int jc = act ? j : 0;

    float acc1[4] = {0.f, 0.f, 0.f, 0.f};
    float acc2[4] = {0.f, 0.f, 0.f, 0.f};
    for (int k4 = 0; k4 < NF / 4; ++k4) {
        float4 wl = *(const float4*)&Wl[(size_t)jc * NF + k4 * 4];
        float4 wr = *(const float4*)&Wr[(size_t)jc * NF + k4 * 4];
#pragma unroll
        for (int rr = 0; rr < 4; ++rr) {
            float4 xv = *(const float4*)&ldsX[(ty + rr * 4) * NF + k4 * 4];
            acc1[rr] += xv.x * wl.x + xv.y * wl.y + xv.z * wl.z + xv.w * wl.w;
            acc2[rr] += xv.x * wr.x + xv.y * wr.y + xv.z * wr.z + xv.w * wr.w;
        }
    }
    if (act) {
        float bj = b[j];
#pragma unroll
        for (int rr = 0; rr < 4; ++rr) {
            int r = R0 + ty + rr * 4;
            out1[(size_t)r * NC + j] = acc1[rr];
            out2[(size_t)r * NC + j] = acc2[rr] + bj;
        }
    }
}

__global__ __launch_bounds__(64) void agg40_add_kernel(const float* __restrict__ T,
                                                       const float* __restrict__ Z,
                                                       const int* __restrict__ csr,
                                                       const int* __restrict__ row_ptr,
                                                       const float* __restrict__ inv_cnt,
                                                       float* __restrict__ out) {
    int n = blockIdx.x;
    int t = threadIdx.x;
    if (t >= NC) return;
    int s = row_ptr[n], e = row_ptr[n + 1];
    float acc = 0.f;
    int i = s;
    for (; i + 4 <= e; i += 4) {
        int s0 = csr[i], s1 = csr[i + 1], s2 = csr[i + 2], s3 = csr[i + 3];
        acc += T[(size_t)s0 * NC + t];
        acc += T[(size_t)s1 * NC + t];
        acc += T[(size_t)s2 * NC + t];
        acc += T[(size_t)s3 * NC + t];
    }
    for (; i < e; ++i) acc += T[(size_t)csr[i] * NC + t];
    out[(size_t)n * NC + t] = acc * inv_cnt[n] + Z[(size_t)n * NC + t];
}

// ---------------- batch norm (training-mode, biased var) ----------------

__global__ void bn_stats_kernel(const float* __restrict__ X, float* __restrict__ sums, int F) {
    int t = threadIdx.x;
    if (t >= F) return;
    float s = 0.f, s2 = 0.f;
    for (int r = blockIdx.x; r < NN; r += gridDim.x) {
        float v = X[(size_t)r * F + t];
        s += v;
        s2 += v * v;
    }
    atomicAdd(&sums[t], s);
    atomicAdd(&sums[F + t], s2);
}

template <bool RELU>
__global__ __launch_bounds__(256) void bn_apply_kernel(float* __restrict__ X,
                                                       const float* __restrict__ sums,
                                                       const float* __restrict__ g,
                                                       const float* __restrict__ be,
                                                       int F, float invN) {
    size_t idx = (size_t)blockIdx.x * blockDim.x + threadIdx.x;
    size_t total = (size_t)NN * F;
    if (idx >= total) return;
    int t = (int)(idx % F);
    float mu = sums[t] * invN;
    float var = sums[F + t] * invN - mu * mu;
    float scale = rsqrtf(var + BN_EPS) * g[t];
    float v = (X[idx] - mu) * scale + be[t];
    if (RELU) v = fmaxf(v, 0.f);
    X[idx] = v;
}

// ---------------- launch ----------------

extern "C" void kernel_launch(void* const* d_in, const int* in_sizes, int n_in,
                              void* d_out, int out_size, void* d_ws, size_t ws_size,
                              hipStream_t stream) {
    const float* x   = (const float*)d_in[0];
    const int*   ei  = (const int*)d_in[1];
    const int*   srcv = ei;
    const int*   dstv = ei + NE;
    const float* W1l = (const float*)d_in[2];
    const float* b1  = (const float*)d_in[3];
    const float* W1r = (const float*)d_in[4];
    const float* Wxl = (const float*)d_in[5];
    const float* bx  = (const float*)d_in[6];
    const float* Wxr = (const float*)d_in[7];
    const float* W2l = (const float*)d_in[8];
    const float* b2  = (const float*)d_in[9];
    const float* W2r = (const float*)d_in[10];
    const float* g3  = (const float*)d_in[11];
    const float* be3 = (const float*)d_in[12];
    const float* g2  = (const float*)d_in[13];
    const float* be2 = (const float*)d_in[14];
    float* out = (float*)d_out;

    // workspace carve (16B aligned)
    char* w = (char*)d_ws;
    unsigned short* xb   = (unsigned short*)w; w += (size_t)NN * NF * 2;   // 25.6 MB
    unsigned short* h1b  = (unsigned short*)w; w += (size_t)NN * NF * 2;   // 25.6 MB
    unsigned short* aggb = (unsigned short*)w; w += (size_t)NN * NF * 2;   // 25.6 MB
    float* h2f = (float*)w; w += (size_t)NN * NF * 4;                      // 51.2 MB
    int* csr     = (int*)w; w += (size_t)NE * 4;                           // 6.4 MB
    int* row_ptr = (int*)w; w += (size_t)(NN + 4) * 4;
    int* deg     = (int*)w; w += (size_t)NN * 4;
    int* cursor  = (int*)w; w += (size_t)NN * 4;
    float* inv_cnt = (float*)w; w += (size_t)NN * 4;
    float* bnbuf   = (float*)w; w += 2 * NF * 4;
    unsigned short* Bp1 = (unsigned short*)w; w += (size_t)256 * NF * 2;   // 64 KB
    unsigned short* Bpx = (unsigned short*)w; w += (size_t)256 * NF * 2;   // 64 KB
    // t40/z40 overlay dead bf16 buffers (xb, h1b used before lin40x2 runs)
    float* t40 = (float*)xb;   // 16 MB < 25.6 MB
    float* z40 = (float*)h1b;  // 16 MB < 25.6 MB

    // ---- CSR build ----
    hipMemsetAsync(deg, 0, (size_t)NN * 4, stream);
    hipMemsetAsync(cursor, 0, (size_t)NN * 4, stream);
    hipMemsetAsync(bnbuf, 0, 2 * NF * 4, stream);
    deg_kernel<<<(NE + 255) / 256, 256, 0, stream>>>(dstv, deg);
    scan_kernel<<<1, 1024, 0, stream>>>(deg, row_ptr, inv_cnt);
    fill_kernel<<<(NE + 255) / 256, 256, 0, stream>>>(srcv, dstv, row_ptr, cursor, csr);

    // ---- prep: x -> bf16; pack weights ----
    f2b4_kernel<<<(NN * NF / 4 + 255) / 256, 256, 0, stream>>>(x, xb, NN * NF / 4);
    pack_w_kernel<<<64, 64, 0, stream>>>(W1l, W1r, Bp1);
    pack_w_kernel<<<64, 64, 0, stream>>>(Wxl, Wxr, Bpx);

    const int nblk_lin = (NN + 63) / 64;  // 1563

    // ---- conv1: h1 = relu([mean(x)|x] @ Bp1 + b1) -> h1b (bf16) ----
    agg_mean_bf16<<<(NN + 3) / 4, 256, 0, stream>>>(xb, csr, row_ptr, inv_cnt, aggb);
    lin_mfma_kernel<true, true><<<nblk_lin, 256, 0, stream>>>(aggb, xb, Bp1, b1, h1b, nullptr);

    // ---- convx: h2 = [mean(h1)|h1] @ Bpx + bx -> h2f (fp32) ----
    agg_mean_bf16<<<(NN + 3) / 4, 256, 0, stream>>>(h1b, csr, row_ptr, inv_cnt, aggb);
    lin_mfma_kernel<false, false><<<nblk_lin, 256, 0, stream>>>(aggb, h1b, Bpx, bx, nullptr, h2f);

    // ---- batch_norm3 + relu (in place on h2f) ----
    bn_stats_kernel<<<256, 128, 0, stream>>>(h2f, bnbuf, NF);
    bn_apply_kernel<true><<<(NN * NF + 255) / 256, 256, 0, stream>>>(h2f, bnbuf, g3, be3, NF, 1.0f / NN);

    // ---- conv2 (transform-first) ----
    lin40x2_kernel<<<NN / 16, 256, 0, stream>>>(h2f, W2l, W2r, b2, t40, z40);
    agg40_add_kernel<<<NN, 64, 0, stream>>>(t40, z40, csr, row_ptr, inv_cnt, out);

    // ---- batch_norm2 (in place on out) ----
    hipMemsetAsync(bnbuf, 0, 2 * NC * 4, stream);
    bn_stats_kernel<<<256, 64, 0, stream>>>(out, bnbuf, NC);
    bn_apply_kernel<false><<<(NN * NC + 255) / 256, 256, 0, stream>>>(out, bnbuf, g2, be2, NC, 1.0f / NN);
}

// Round 3
// 966.817 us; speedup vs baseline: 1.9910x; 1.2069x over previous
//
#include <hip/hip_runtime.h>
#include <hip/hip_bf16.h>

#define NN 100000
#define NE 1600000
#define NF 128
#define NC 40
#define BN_EPS 1e-5f

typedef __attribute__((ext_vector_type(8))) short short8;
typedef __attribute__((ext_vector_type(4))) float float4v;

__device__ __forceinline__ unsigned short f2b(float f) {
    __hip_bfloat16 h = __float2bfloat16(f);
    return *reinterpret_cast<unsigned short*>(&h);
}
__device__ __forceinline__ float b2f_hi(unsigned u) { return __uint_as_float(u & 0xffff0000u); }
__device__ __forceinline__ float b2f_lo(unsigned u) { return __uint_as_float(u << 16); }

// ---------------- CSR build ----------------

__global__ __launch_bounds__(256) void deg_kernel(const int* __restrict__ dst, int* __restrict__ deg) {
    int e = blockIdx.x * blockDim.x + threadIdx.x;
    if (e < NE) atomicAdd(&deg[dst[e]], 1);
}

// hierarchical exclusive scan over deg[NN]
__global__ __launch_bounds__(1024) void scan1_kernel(const int* __restrict__ deg,
                                                     int* __restrict__ row_loc,
                                                     int* __restrict__ blocksum) {
    __shared__ int lds[1024];
    int t = threadIdx.x;
    int i = blockIdx.x * 1024 + t;
    int v = (i < NN) ? deg[i] : 0;
    lds[t] = v;
    __syncthreads();
    for (int off = 1; off < 1024; off <<= 1) {
        int u = (t >= off) ? lds[t - off] : 0;
        __syncthreads();
        lds[t] += u;
        __syncthreads();
    }
    if (i < NN) row_loc[i] = lds[t] - v;  // exclusive within block
    if (t == 1023) blocksum[blockIdx.x] = lds[1023];
}

__global__ __launch_bounds__(128) void scan2_kernel(int* __restrict__ blocksum, int nb) {
    __shared__ int lds[128];
    int t = threadIdx.x;
    int v = (t < nb) ? blocksum[t] : 0;
    lds[t] = v;
    __syncthreads();
    for (int off = 1; off < 128; off <<= 1) {
        int u = (t >= off) ? lds[t - off] : 0;
        __syncthreads();
        lds[t] += u;
        __syncthreads();
    }
    if (t < nb) blocksum[t] = lds[t] - v;  // exclusive block offsets
}

__global__ __launch_bounds__(1024) void scan3_kernel(const int* __restrict__ deg,
                                                     const int* __restrict__ row_loc,
                                                     const int* __restrict__ blockoff,
                                                     int* __restrict__ row_ptr,
                                                     float* __restrict__ inv_cnt) {
    int i = blockIdx.x * 1024 + threadIdx.x;
    if (i < NN) {
        row_ptr[i] = blockoff[blockIdx.x] + row_loc[i];
        int d = deg[i];
        inv_cnt[i] = 1.0f / (float)(d > 0 ? d : 1);
    }
    if (i == 0) row_ptr[NN] = NE;
}

__global__ __launch_bounds__(256) void fill_kernel(const int* __restrict__ src,
                                                   const int* __restrict__ dst,
                                                   const int* __restrict__ row_ptr,
                                                   int* __restrict__ cursor,
                                                   int* __restrict__ csr) {
    int e = blockIdx.x * blockDim.x + threadIdx.x;
    if (e < NE) {
        int d = dst[e];
        int pos = atomicAdd(&cursor[d], 1);
        csr[row_ptr[d] + pos] = src[e];
    }
}

// ---------------- fp32 -> bf16 bulk convert ----------------

__global__ __launch_bounds__(256) void f2b4_kernel(const float* __restrict__ in,
                                                   unsigned short* __restrict__ out, int n4) {
    int i = blockIdx.x * 256 + threadIdx.x;
    if (i < n4) {
        float4 v = ((const float4*)in)[i];
        ushort4 o;
        o.x = f2b(v.x); o.y = f2b(v.y); o.z = f2b(v.z); o.w = f2b(v.w);
        ((ushort4*)out)[i] = o;
    }
}

// ---------------- pack W into MFMA B-fragment order ----------------

__global__ __launch_bounds__(64) void pack_w_kernel(const float* __restrict__ Wl,
                                                    const float* __restrict__ Wr,
                                                    unsigned short* __restrict__ Bp) {
    int nt = blockIdx.x & 7;
    int kk = blockIdx.x >> 3;
    int lane = threadIdx.x;
    int n = nt * 16 + (lane & 15);
    int kb = kk * 32 + (lane >> 4) * 8;
    size_t base = ((size_t)(kk * 8 + nt) * 64 + lane) * 8;
#pragma unroll
    for (int j = 0; j < 8; ++j) {
        int k = kb + j;
        float v = (k < NF) ? Wl[(size_t)n * NF + k] : Wr[(size_t)n * NF + (k - NF)];
        Bp[base + j] = f2b(v);
    }
}

// ---------------- mean aggregation over CSR (bf16 table, fp32 accum) ----------------

__global__ __launch_bounds__(256) void agg_mean_bf16(const unsigned short* __restrict__ X,
                                                     const int* __restrict__ csr,
                                                     const int* __restrict__ row_ptr,
                                                     const float* __restrict__ inv_cnt,
                                                     unsigned short* __restrict__ out) {
    int wave = threadIdx.x >> 6;
    int lane = threadIdx.x & 63;
    int n = blockIdx.x * 4 + wave;
    if (n >= NN) return;
    int s = row_ptr[n], e = row_ptr[n + 1];
    float a0 = 0.f, a1 = 0.f;
    int i = s;
    for (; i + 4 <= e; i += 4) {
        int s0 = csr[i], s1 = csr[i + 1], s2 = csr[i + 2], s3 = csr[i + 3];
        unsigned u0 = *(const unsigned*)(X + (size_t)s0 * NF + lane * 2);
        unsigned u1 = *(const unsigned*)(X + (size_t)s1 * NF + lane * 2);
        unsigned u2 = *(const unsigned*)(X + (size_t)s2 * NF + lane * 2);
        unsigned u3 = *(const unsigned*)(X + (size_t)s3 * NF + lane * 2);
        a0 += b2f_lo(u0) + b2f_lo(u1) + b2f_lo(u2) + b2f_lo(u3);
        a1 += b2f_hi(u0) + b2f_hi(u1) + b2f_hi(u2) + b2f_hi(u3);
    }
    for (; i < e; ++i) {
        unsigned u = *(const unsigned*)(X + (size_t)csr[i] * NF + lane * 2);
        a0 += b2f_lo(u);
        a1 += b2f_hi(u);
    }
    float ic = inv_cnt[n];
    unsigned short o0 = f2b(a0 * ic), o1 = f2b(a1 * ic);
    *(unsigned*)(out + (size_t)n * NF + lane * 2) = (unsigned)o0 | ((unsigned)o1 << 16);
}

// ---------------- MFMA linear ----------------

template <bool RELU, bool OUT_BF16>
__global__ __launch_bounds__(256) void lin_mfma_kernel(const unsigned short* __restrict__ Ab,
                                                       const unsigned short* __restrict__ Xb,
                                                       const unsigned short* __restrict__ Bp,
                                                       const float* __restrict__ bias,
                                                       unsigned short* __restrict__ outb,
                                                       float* __restrict__ outf) {
    __shared__ unsigned short ldsB[32768];  // 64 KB
    int tid = threadIdx.x;
    {
        const float4* srcp = (const float4*)Bp;
        float4* dstp = (float4*)ldsB;
#pragma unroll
        for (int i = 0; i < 16; ++i) dstp[tid + i * 256] = srcp[tid + i * 256];
    }
    __syncthreads();

    int wave = tid >> 6;
    int lane = tid & 63;
    int quad = lane >> 4;
    int row = blockIdx.x * 64 + wave * 16 + (lane & 15);
    int rowc = row < NN ? row : (NN - 1);
    const unsigned short* arow = Ab + (size_t)rowc * NF;
    const unsigned short* xrow = Xb + (size_t)rowc * NF;

    float4v acc[8];
#pragma unroll
    for (int nt = 0; nt < 8; ++nt) acc[nt] = (float4v){0.f, 0.f, 0.f, 0.f};

#pragma unroll
    for (int kk = 0; kk < 8; ++kk) {
        int kb = (kk & 3) * 32 + quad * 8;
        const unsigned short* asrc = (kk < 4) ? arow : xrow;
        short8 afrag = *(const short8*)(asrc + kb);
#pragma unroll
        for (int nt = 0; nt < 8; ++nt) {
            short8 bfrag = *(const short8*)(ldsB + ((size_t)(kk * 8 + nt) * 64 + lane) * 8);
            acc[nt] = __builtin_amdgcn_mfma_f32_16x16x32_bf16(afrag, bfrag, acc[nt], 0, 0, 0);
        }
    }

    int orow = blockIdx.x * 64 + wave * 16 + quad * 4;
    int col = lane & 15;
#pragma unroll
    for (int nt = 0; nt < 8; ++nt) {
        int c = nt * 16 + col;
        float bv = bias[c];
#pragma unroll
        for (int r = 0; r < 4; ++r) {
            int rr = orow + r;
            if (rr < NN) {
                float v = acc[nt][r] + bv;
                if (RELU) v = fmaxf(v, 0.f);
                if (OUT_BF16) outb[(size_t)rr * NF + c] = f2b(v);
                else outf[(size_t)rr * NF + c] = v;
            }
        }
    }
}

// ---------------- conv2 dense: t40(bf16) = X@W2l.T, z40(fp32) = X@W2r.T + b2 ----------------

__global__ __launch_bounds__(256) void lin40x2_kernel(const float* __restrict__ X,
                                                      const float* __restrict__ Wl,
                                                      const float* __restrict__ Wr,
                                                      const float* __restrict__ b,
                                                      unsigned short* __restrict__ out1,
                                                      float* __restrict__ out2) {
    __shared__ float ldsX[16 * NF];
    int tid = threadIdx.x;
    int R0 = blockIdx.x * 16;
    const float4* X4 = (const float4*)(X + (size_t)R0 * NF);
    float4* lX4 = (float4*)ldsX;
    lX4[tid] = X4[tid];
    lX4[tid + 256] = X4[tid + 256];
    __syncthreads();

    int j = tid & 63;
    int ty = tid >> 6;  // 0..3
    bool act = (j < NC);
    int jc = act ? j : 0;

    float acc1[4] = {0.f, 0.f, 0.f, 0.f};
    float acc2[4] = {0.f, 0.f, 0.f, 0.f};
    for (int k4 = 0; k4 < NF / 4; ++k4) {
        float4 wl = *(const float4*)&Wl[(size_t)jc * NF + k4 * 4];
        float4 wr = *(const float4*)&Wr[(size_t)jc * NF + k4 * 4];
#pragma unroll
        for (int rr = 0; rr < 4; ++rr) {
            float4 xv = *(const float4*)&ldsX[(ty + rr * 4) * NF + k4 * 4];
            acc1[rr] += xv.x * wl.x + xv.y * wl.y + xv.z * wl.z + xv.w * wl.w;
            acc2[rr] += xv.x * wr.x + xv.y * wr.y + xv.z * wr.z + xv.w * wr.w;
        }
    }
    if (act) {
        float bj = b[j];
#pragma unroll
        for (int rr = 0; rr < 4; ++rr) {
            int r = R0 + ty + rr * 4;
            out1[(size_t)r * NC + j] = f2b(acc1[rr]);
            out2[(size_t)r * NC + j] = acc2[rr] + bj;
        }
    }
}

// lanes 0..19 each own feature pair (2*lane, 2*lane+1); T is bf16
__global__ __launch_bounds__(256) void agg40_add_bf16(const unsigned short* __restrict__ T,
                                                      const float* __restrict__ Z,
                                                      const int* __restrict__ csr,
                                                      const int* __restrict__ row_ptr,
                                                      const float* __restrict__ inv_cnt,
                                                      float* __restrict__ out) {
    int wave = threadIdx.x >> 6;
    int lane = threadIdx.x & 63;
    int n = blockIdx.x * 4 + wave;
    if (n >= NN || lane >= 20) return;
    int s = row_ptr[n], e = row_ptr[n + 1];
    float a0 = 0.f, a1 = 0.f;
    int i = s;
    for (; i + 4 <= e; i += 4) {
        int s0 = csr[i], s1 = csr[i + 1], s2 = csr[i + 2], s3 = csr[i + 3];
        unsigned u0 = *(const unsigned*)(T + (size_t)s0 * NC + lane * 2);
        unsigned u1 = *(const unsigned*)(T + (size_t)s1 * NC + lane * 2);
        unsigned u2 = *(const unsigned*)(T + (size_t)s2 * NC + lane * 2);
        unsigned u3 = *(const unsigned*)(T + (size_t)s3 * NC + lane * 2);
        a0 += b2f_lo(u0) + b2f_lo(u1) + b2f_lo(u2) + b2f_lo(u3);
        a1 += b2f_hi(u0) + b2f_hi(u1) + b2f_hi(u2) + b2f_hi(u3);
    }
    for (; i < e; ++i) {
        unsigned u = *(const unsigned*)(T + (size_t)csr[i] * NC + lane * 2);
        a0 += b2f_lo(u);
        a1 += b2f_hi(u);
    }
    float ic = inv_cnt[n];
    const float2 zv = *(const float2*)(Z + (size_t)n * NC + lane * 2);
    float2 o;
    o.x = a0 * ic + zv.x;
    o.y = a1 * ic + zv.y;
    *(float2*)(out + (size_t)n * NC + lane * 2) = o;
}

// ---------------- batch norm (training-mode, biased var) ----------------

__global__ void bn_stats_kernel(const float* __restrict__ X, float* __restrict__ sums, int F) {
    int t = threadIdx.x;
    if (t >= F) return;
    float s = 0.f, s2 = 0.f;
    for (int r = blockIdx.x; r < NN; r += gridDim.x) {
        float v = X[(size_t)r * F + t];
        s += v;
        s2 += v * v;
    }
    atomicAdd(&sums[t], s);
    atomicAdd(&sums[F + t], s2);
}

template <bool RELU>
__global__ __launch_bounds__(256) void bn_apply_kernel(float* __restrict__ X,
                                                       const float* __restrict__ sums,
                                                       const float* __restrict__ g,
                                                       const float* __restrict__ be,
                                                       int F, float invN) {
    size_t idx = (size_t)blockIdx.x * blockDim.x + threadIdx.x;
    size_t total = (size_t)NN * F;
    if (idx >= total) return;
    int t = (int)(idx % F);
    float mu = sums[t] * invN;
    float var = sums[F + t] * invN - mu * mu;
    float scale = rsqrtf(var + BN_EPS) * g[t];
    float v = (X[idx] - mu) * scale + be[t];
    if (RELU) v = fmaxf(v, 0.f);
    X[idx] = v;
}

// ---------------- launch ----------------

extern "C" void kernel_launch(void* const* d_in, const int* in_sizes, int n_in,
                              void* d_out, int out_size, void* d_ws, size_t ws_size,
                              hipStream_t stream) {
    const float* x   = (const float*)d_in[0];
    const int*   ei  = (const int*)d_in[1];
    const int*   srcv = ei;
    const int*   dstv = ei + NE;
    const float* W1l = (const float*)d_in[2];
    const float* b1  = (const float*)d_in[3];
    const float* W1r = (const float*)d_in[4];
    const float* Wxl = (const float*)d_in[5];
    const float* bx  = (const float*)d_in[6];
    const float* Wxr = (const float*)d_in[7];
    const float* W2l = (const float*)d_in[8];
    const float* b2  = (const float*)d_in[9];
    const float* W2r = (const float*)d_in[10];
    const float* g3  = (const float*)d_in[11];
    const float* be3 = (const float*)d_in[12];
    const float* g2  = (const float*)d_in[13];
    const float* be2 = (const float*)d_in[14];
    float* out = (float*)d_out;

    // workspace carve (16B aligned)
    char* w = (char*)d_ws;
    unsigned short* xb   = (unsigned short*)w; w += (size_t)NN * NF * 2;   // 25.6 MB
    unsigned short* h1b  = (unsigned short*)w; w += (size_t)NN * NF * 2;   // 25.6 MB
    unsigned short* aggb = (unsigned short*)w; w += (size_t)NN * NF * 2;   // 25.6 MB
    float* h2f = (float*)w; w += (size_t)NN * NF * 4;                      // 51.2 MB
    int* csr     = (int*)w; w += (size_t)NE * 4;                           // 6.4 MB
    int* row_ptr = (int*)w; w += (size_t)(NN + 4) * 4;
    int* deg     = (int*)w; w += (size_t)NN * 4;
    int* cursor  = (int*)w; w += (size_t)NN * 4;
    int* row_loc = (int*)w; w += (size_t)NN * 4;
    int* blocksum = (int*)w; w += 128 * 4;
    float* inv_cnt = (float*)w; w += (size_t)NN * 4;
    float* bnbuf   = (float*)w; w += 2 * NF * 4;
    unsigned short* Bp1 = (unsigned short*)w; w += (size_t)256 * NF * 2;   // 64 KB
    unsigned short* Bpx = (unsigned short*)w; w += (size_t)256 * NF * 2;   // 64 KB
    // overlays: conv2 temporaries live in dead bf16 buffers
    unsigned short* t40 = xb;        // 8 MB < 25.6 MB (xb dead after conv1)
    float* z40 = (float*)h1b;        // 16 MB < 25.6 MB (h1b dead after convx)

    const int nscan = (NN + 1023) / 1024;  // 98

    // ---- CSR build ----
    hipMemsetAsync(deg, 0, (size_t)NN * 4, stream);
    hipMemsetAsync(cursor, 0, (size_t)NN * 4, stream);
    hipMemsetAsync(bnbuf, 0, 2 * NF * 4, stream);
    deg_kernel<<<(NE + 255) / 256, 256, 0, stream>>>(dstv, deg);
    scan1_kernel<<<nscan, 1024, 0, stream>>>(deg, row_loc, blocksum);
    scan2_kernel<<<1, 128, 0, stream>>>(blocksum, nscan);
    scan3_kernel<<<nscan, 1024, 0, stream>>>(deg, row_loc, blocksum, row_ptr, inv_cnt);
    fill_kernel<<<(NE + 255) / 256, 256, 0, stream>>>(srcv, dstv, row_ptr, cursor, csr);

    // ---- prep: x -> bf16; pack weights ----
    f2b4_kernel<<<(NN * NF / 4 + 255) / 256, 256, 0, stream>>>(x, xb, NN * NF / 4);
    pack_w_kernel<<<64, 64, 0, stream>>>(W1l, W1r, Bp1);
    pack_w_kernel<<<64, 64, 0, stream>>>(Wxl, Wxr, Bpx);

    const int nblk_lin = (NN + 63) / 64;  // 1563

    // ---- conv1: h1 = relu([mean(x)|x] @ Bp1 + b1) -> h1b (bf16) ----
    agg_mean_bf16<<<(NN + 3) / 4, 256, 0, stream>>>(xb, csr, row_ptr, inv_cnt, aggb);
    lin_mfma_kernel<true, true><<<nblk_lin, 256, 0, stream>>>(aggb, xb, Bp1, b1, h1b, nullptr);

    // ---- convx: h2 = [mean(h1)|h1] @ Bpx + bx -> h2f (fp32) ----
    agg_mean_bf16<<<(NN + 3) / 4, 256, 0, stream>>>(h1b, csr, row_ptr, inv_cnt, aggb);
    lin_mfma_kernel<false, false><<<nblk_lin, 256, 0, stream>>>(aggb, h1b, Bpx, bx, nullptr, h2f);

    // ---- batch_norm3 + relu (in place on h2f) ----
    bn_stats_kernel<<<256, 128, 0, stream>>>(h2f, bnbuf, NF);
    bn_apply_kernel<true><<<(NN * NF + 255) / 256, 256, 0, stream>>>(h2f, bnbuf, g3, be3, NF, 1.0f / NN);

    // ---- conv2 (transform-first) ----
    lin40x2_kernel<<<NN / 16, 256, 0, stream>>>(h2f, W2l, W2r, b2, t40, z40);
    agg40_add_bf16<<<(NN + 3) / 4, 256, 0, stream>>>(t40, z40, csr, row_ptr, inv_cnt, out);

    // ---- batch_norm2 (in place on out) ----
    hipMemsetAsync(bnbuf, 0, 2 * NC * 4, stream);
    bn_stats_kernel<<<256, 64, 0, stream>>>(out, bnbuf, NC);
    bn_apply_kernel<false><<<(NN * NC + 255) / 256, 256, 0, stream>>>(out, bnbuf, g2, be2, NC, 1.0f / NN);
}

// Round 4
// 838.228 us; speedup vs baseline: 2.2965x; 1.1534x over previous
//
#include <hip/hip_runtime.h>
#include <hip/hip_bf16.h>

#define NN 100000
#define NE 1600000
#define NF 128
#define NC 40
#define BN_EPS 1e-5f

typedef __attribute__((ext_vector_type(8))) short short8;
typedef __attribute__((ext_vector_type(4))) float float4v;

__device__ __forceinline__ unsigned short f2b(float f) {
    __hip_bfloat16 h = __float2bfloat16(f);
    return *reinterpret_cast<unsigned short*>(&h);
}
__device__ __forceinline__ float b2f_hi(unsigned u) { return __uint_as_float(u & 0xffff0000u); }
__device__ __forceinline__ float b2f_lo(unsigned u) { return __uint_as_float(u << 16); }

// ---------------- CSR build ----------------

__global__ __launch_bounds__(256) void deg_kernel(const int* __restrict__ dst, int* __restrict__ deg) {
    int e = blockIdx.x * blockDim.x + threadIdx.x;
    if (e < NE) atomicAdd(&deg[dst[e]], 1);
}

__global__ __launch_bounds__(1024) void scan1_kernel(const int* __restrict__ deg,
                                                     int* __restrict__ row_loc,
                                                     int* __restrict__ blocksum) {
    __shared__ int lds[1024];
    int t = threadIdx.x;
    int i = blockIdx.x * 1024 + t;
    int v = (i < NN) ? deg[i] : 0;
    lds[t] = v;
    __syncthreads();
    for (int off = 1; off < 1024; off <<= 1) {
        int u = (t >= off) ? lds[t - off] : 0;
        __syncthreads();
        lds[t] += u;
        __syncthreads();
    }
    if (i < NN) row_loc[i] = lds[t] - v;
    if (t == 1023) blocksum[blockIdx.x] = lds[1023];
}

__global__ __launch_bounds__(128) void scan2_kernel(int* __restrict__ blocksum, int nb) {
    __shared__ int lds[128];
    int t = threadIdx.x;
    int v = (t < nb) ? blocksum[t] : 0;
    lds[t] = v;
    __syncthreads();
    for (int off = 1; off < 128; off <<= 1) {
        int u = (t >= off) ? lds[t - off] : 0;
        __syncthreads();
        lds[t] += u;
        __syncthreads();
    }
    if (t < nb) blocksum[t] = lds[t] - v;
}

__global__ __launch_bounds__(1024) void scan3_kernel(const int* __restrict__ deg,
                                                     const int* __restrict__ row_loc,
                                                     const int* __restrict__ blockoff,
                                                     int* __restrict__ row_ptr,
                                                     float* __restrict__ inv_cnt) {
    int i = blockIdx.x * 1024 + threadIdx.x;
    if (i < NN) {
        row_ptr[i] = blockoff[blockIdx.x] + row_loc[i];
        int d = deg[i];
        inv_cnt[i] = 1.0f / (float)(d > 0 ? d : 1);
    }
    if (i == 0) row_ptr[NN] = NE;
}

__global__ __launch_bounds__(256) void fill_kernel(const int* __restrict__ src,
                                                   const int* __restrict__ dst,
                                                   const int* __restrict__ row_ptr,
                                                   int* __restrict__ cursor,
                                                   int* __restrict__ csr) {
    int e = blockIdx.x * blockDim.x + threadIdx.x;
    if (e < NE) {
        int d = dst[e];
        int pos = atomicAdd(&cursor[d], 1);
        csr[row_ptr[d] + pos] = src[e];
    }
}

// ---------------- fp32 -> bf16 bulk convert ----------------

__global__ __launch_bounds__(256) void f2b4_kernel(const float* __restrict__ in,
                                                   unsigned short* __restrict__ out, int n4) {
    int i = blockIdx.x * 256 + threadIdx.x;
    if (i < n4) {
        float4 v = ((const float4*)in)[i];
        ushort4 o;
        o.x = f2b(v.x); o.y = f2b(v.y); o.z = f2b(v.z); o.w = f2b(v.w);
        ((ushort4*)out)[i] = o;
    }
}

// ---------------- pack W into MFMA B-fragment order (K=256, N=128) ----------------

__global__ __launch_bounds__(64) void pack_w_kernel(const float* __restrict__ Wl,
                                                    const float* __restrict__ Wr,
                                                    unsigned short* __restrict__ Bp) {
    int nt = blockIdx.x & 7;
    int kk = blockIdx.x >> 3;
    int lane = threadIdx.x;
    int n = nt * 16 + (lane & 15);
    int kb = kk * 32 + (lane >> 4) * 8;
    size_t base = ((size_t)(kk * 8 + nt) * 64 + lane) * 8;
#pragma unroll
    for (int j = 0; j < 8; ++j) {
        int k = kb + j;
        float v = (k < NF) ? Wl[(size_t)n * NF + k] : Wr[(size_t)n * NF + (k - NF)];
        Bp[base + j] = f2b(v);
    }
}

// pack for conv2: K=128, N=80 (cols 0..39 = W2l, 40..79 = W2r). 20 blocks.
__global__ __launch_bounds__(64) void pack_w80_kernel(const float* __restrict__ Wl,
                                                      const float* __restrict__ Wr,
                                                      unsigned short* __restrict__ Bp) {
    int nt = blockIdx.x % 5;
    int kk = blockIdx.x / 5;
    int lane = threadIdx.x;
    int n = nt * 16 + (lane & 15);
    int kb = kk * 32 + (lane >> 4) * 8;
    size_t base = ((size_t)(kk * 5 + nt) * 64 + lane) * 8;
#pragma unroll
    for (int j = 0; j < 8; ++j) {
        int k = kb + j;
        float v = (n < NC) ? Wl[(size_t)n * NF + k] : Wr[(size_t)(n - NC) * NF + k];
        Bp[base + j] = f2b(v);
    }
}

// ---------------- mean aggregation over CSR (bf16 table, fp32 accum) ----------------

__global__ __launch_bounds__(256) void agg_mean_bf16(const unsigned short* __restrict__ X,
                                                     const int* __restrict__ csr,
                                                     const int* __restrict__ row_ptr,
                                                     const float* __restrict__ inv_cnt,
                                                     unsigned short* __restrict__ out) {
    int wave = threadIdx.x >> 6;
    int lane = threadIdx.x & 63;
    int n = blockIdx.x * 4 + wave;
    if (n >= NN) return;
    int s = row_ptr[n], e = row_ptr[n + 1];
    float a0 = 0.f, a1 = 0.f;
    int i = s;
    for (; i + 4 <= e; i += 4) {
        int s0 = csr[i], s1 = csr[i + 1], s2 = csr[i + 2], s3 = csr[i + 3];
        unsigned u0 = *(const unsigned*)(X + (size_t)s0 * NF + lane * 2);
        unsigned u1 = *(const unsigned*)(X + (size_t)s1 * NF + lane * 2);
        unsigned u2 = *(const unsigned*)(X + (size_t)s2 * NF + lane * 2);
        unsigned u3 = *(const unsigned*)(X + (size_t)s3 * NF + lane * 2);
        a0 += b2f_lo(u0) + b2f_lo(u1) + b2f_lo(u2) + b2f_lo(u3);
        a1 += b2f_hi(u0) + b2f_hi(u1) + b2f_hi(u2) + b2f_hi(u3);
    }
    for (; i < e; ++i) {
        unsigned u = *(const unsigned*)(X + (size_t)csr[i] * NF + lane * 2);
        a0 += b2f_lo(u);
        a1 += b2f_hi(u);
    }
    float ic = inv_cnt[n];
    unsigned short o0 = f2b(a0 * ic), o1 = f2b(a1 * ic);
    *(unsigned*)(out + (size_t)n * NF + lane * 2) = (unsigned)o0 | ((unsigned)o1 << 16);
}

// ---------------- MFMA linear (128-out, K=256) ----------------

template <bool RELU, bool OUT_BF16>
__global__ __launch_bounds__(256) void lin_mfma_kernel(const unsigned short* __restrict__ Ab,
                                                       const unsigned short* __restrict__ Xb,
                                                       const unsigned short* __restrict__ Bp,
                                                       const float* __restrict__ bias,
                                                       unsigned short* __restrict__ outb,
                                                       float* __restrict__ outf) {
    __shared__ unsigned short ldsB[32768];  // 64 KB
    int tid = threadIdx.x;
    {
        const float4* srcp = (const float4*)Bp;
        float4* dstp = (float4*)ldsB;
#pragma unroll
        for (int i = 0; i < 16; ++i) dstp[tid + i * 256] = srcp[tid + i * 256];
    }
    __syncthreads();

    int wave = tid >> 6;
    int lane = tid & 63;
    int quad = lane >> 4;
    int row = blockIdx.x * 64 + wave * 16 + (lane & 15);
    int rowc = row < NN ? row : (NN - 1);
    const unsigned short* arow = Ab + (size_t)rowc * NF;
    const unsigned short* xrow = Xb + (size_t)rowc * NF;

    float4v acc[8];
#pragma unroll
    for (int nt = 0; nt < 8; ++nt) acc[nt] = (float4v){0.f, 0.f, 0.f, 0.f};

#pragma unroll
    for (int kk = 0; kk < 8; ++kk) {
        int kb = (kk & 3) * 32 + quad * 8;
        const unsigned short* asrc = (kk < 4) ? arow : xrow;
        short8 afrag = *(const short8*)(asrc + kb);
#pragma unroll
        for (int nt = 0; nt < 8; ++nt) {
            short8 bfrag = *(const short8*)(ldsB + ((size_t)(kk * 8 + nt) * 64 + lane) * 8);
            acc[nt] = __builtin_amdgcn_mfma_f32_16x16x32_bf16(afrag, bfrag, acc[nt], 0, 0, 0);
        }
    }

    int orow = blockIdx.x * 64 + wave * 16 + quad * 4;
    int col = lane & 15;
#pragma unroll
    for (int nt = 0; nt < 8; ++nt) {
        int c = nt * 16 + col;
        float bv = bias[c];
#pragma unroll
        for (int r = 0; r < 4; ++r) {
            int rr = orow + r;
            if (rr < NN) {
                float v = acc[nt][r] + bv;
                if (RELU) v = fmaxf(v, 0.f);
                if (OUT_BF16) outb[(size_t)rr * NF + c] = f2b(v);
                else outf[(size_t)rr * NF + c] = v;
            }
        }
    }
}

// ---------------- MFMA linear for conv2 (80-out, K=128) ----------------
// t40 (cols 0..39, bf16, no bias) ; z40 (cols 40..79 -> W2r proj, fp32, +b2)

__global__ __launch_bounds__(256) void lin80_mfma_kernel(const unsigned short* __restrict__ Xb,
                                                         const unsigned short* __restrict__ Bp,
                                                         const float* __restrict__ b2,
                                                         unsigned short* __restrict__ t40,
                                                         float* __restrict__ z40) {
    __shared__ unsigned short ldsB[10240];  // 20 KB: 4 kk * 5 nt * 64 lanes * 8
    int tid = threadIdx.x;
    {
        const float4* srcp = (const float4*)Bp;
        float4* dstp = (float4*)ldsB;
#pragma unroll
        for (int i = 0; i < 5; ++i) dstp[tid + i * 256] = srcp[tid + i * 256];
    }
    __syncthreads();

    int wave = tid >> 6;
    int lane = tid & 63;
    int quad = lane >> 4;
    int row = blockIdx.x * 64 + wave * 16 + (lane & 15);
    int rowc = row < NN ? row : (NN - 1);
    const unsigned short* xrow = Xb + (size_t)rowc * NF;

    float4v acc[5];
#pragma unroll
    for (int nt = 0; nt < 5; ++nt) acc[nt] = (float4v){0.f, 0.f, 0.f, 0.f};

#pragma unroll
    for (int kk = 0; kk < 4; ++kk) {
        int kb = kk * 32 + quad * 8;
        short8 afrag = *(const short8*)(xrow + kb);
#pragma unroll
        for (int nt = 0; nt < 5; ++nt) {
            short8 bfrag = *(const short8*)(ldsB + ((size_t)(kk * 5 + nt) * 64 + lane) * 8);
            acc[nt] = __builtin_amdgcn_mfma_f32_16x16x32_bf16(afrag, bfrag, acc[nt], 0, 0, 0);
        }
    }

    int orow = blockIdx.x * 64 + wave * 16 + quad * 4;
    int col = lane & 15;
#pragma unroll
    for (int nt = 0; nt < 5; ++nt) {
        int c = nt * 16 + col;
#pragma unroll
        for (int r = 0; r < 4; ++r) {
            int rr = orow + r;
            if (rr < NN) {
                float v = acc[nt][r];
                if (c < NC) {
                    t40[(size_t)rr * NC + c] = f2b(v);
                } else {
                    z40[(size_t)rr * NC + (c - NC)] = v + b2[c - NC];
                }
            }
        }
    }
}

// lanes 0..19 each own feature pair (2*lane, 2*lane+1); T is bf16
__global__ __launch_bounds__(256) void agg40_add_bf16(const unsigned short* __restrict__ T,
                                                      const float* __restrict__ Z,
                                                      const int* __restrict__ csr,
                                                      const int* __restrict__ row_ptr,
                                                      const float* __restrict__ inv_cnt,
                                                      float* __restrict__ out) {
    int wave = threadIdx.x >> 6;
    int lane = threadIdx.x & 63;
    int n = blockIdx.x * 4 + wave;
    if (n >= NN || lane >= 20) return;
    int s = row_ptr[n], e = row_ptr[n + 1];
    float a0 = 0.f, a1 = 0.f;
    int i = s;
    for (; i + 4 <= e; i += 4) {
        int s0 = csr[i], s1 = csr[i + 1], s2 = csr[i + 2], s3 = csr[i + 3];
        unsigned u0 = *(const unsigned*)(T + (size_t)s0 * NC + lane * 2);
        unsigned u1 = *(const unsigned*)(T + (size_t)s1 * NC + lane * 2);
        unsigned u2 = *(const unsigned*)(T + (size_t)s2 * NC + lane * 2);
        unsigned u3 = *(const unsigned*)(T + (size_t)s3 * NC + lane * 2);
        a0 += b2f_lo(u0) + b2f_lo(u1) + b2f_lo(u2) + b2f_lo(u3);
        a1 += b2f_hi(u0) + b2f_hi(u1) + b2f_hi(u2) + b2f_hi(u3);
    }
    for (; i < e; ++i) {
        unsigned u = *(const unsigned*)(T + (size_t)csr[i] * NC + lane * 2);
        a0 += b2f_lo(u);
        a1 += b2f_hi(u);
    }
    float ic = inv_cnt[n];
    const float2 zv = *(const float2*)(Z + (size_t)n * NC + lane * 2);
    float2 o;
    o.x = a0 * ic + zv.x;
    o.y = a1 * ic + zv.y;
    *(float2*)(out + (size_t)n * NC + lane * 2) = o;
}

// ---------------- batch norm (training-mode, biased var) ----------------

__global__ void bn_stats_kernel(const float* __restrict__ X, float* __restrict__ sums, int F) {
    int t = threadIdx.x;
    if (t >= F) return;
    float s = 0.f, s2 = 0.f;
    for (int r = blockIdx.x; r < NN; r += gridDim.x) {
        float v = X[(size_t)r * F + t];
        s += v;
        s2 += v * v;
    }
    atomicAdd(&sums[t], s);
    atomicAdd(&sums[F + t], s2);
}

// BN3 apply + relu, emit bf16 (conv2 input)
__global__ __launch_bounds__(256) void bn_apply_relu_b16_kernel(const float* __restrict__ X,
                                                                const float* __restrict__ sums,
                                                                const float* __restrict__ g,
                                                                const float* __restrict__ be,
                                                                unsigned short* __restrict__ outb,
                                                                float invN) {
    size_t idx = (size_t)blockIdx.x * blockDim.x + threadIdx.x;
    if (idx >= (size_t)NN * NF) return;
    int t = (int)(idx % NF);
    float mu = sums[t] * invN;
    float var = sums[NF + t] * invN - mu * mu;
    float scale = rsqrtf(var + BN_EPS) * g[t];
    float v = (X[idx] - mu) * scale + be[t];
    v = fmaxf(v, 0.f);
    outb[idx] = f2b(v);
}

template <bool RELU>
__global__ __launch_bounds__(256) void bn_apply_kernel(float* __restrict__ X,
                                                       const float* __restrict__ sums,
                                                       const float* __restrict__ g,
                                                       const float* __restrict__ be,
                                                       int F, float invN) {
    size_t idx = (size_t)blockIdx.x * blockDim.x + threadIdx.x;
    size_t total = (size_t)NN * F;
    if (idx >= total) return;
    int t = (int)(idx % F);
    float mu = sums[t] * invN;
    float var = sums[F + t] * invN - mu * mu;
    float scale = rsqrtf(var + BN_EPS) * g[t];
    float v = (X[idx] - mu) * scale + be[t];
    if (RELU) v = fmaxf(v, 0.f);
    X[idx] = v;
}

// ---------------- launch ----------------

extern "C" void kernel_launch(void* const* d_in, const int* in_sizes, int n_in,
                              void* d_out, int out_size, void* d_ws, size_t ws_size,
                              hipStream_t stream) {
    const float* x   = (const float*)d_in[0];
    const int*   ei  = (const int*)d_in[1];
    const int*   srcv = ei;
    const int*   dstv = ei + NE;
    const float* W1l = (const float*)d_in[2];
    const float* b1  = (const float*)d_in[3];
    const float* W1r = (const float*)d_in[4];
    const float* Wxl = (const float*)d_in[5];
    const float* bx  = (const float*)d_in[6];
    const float* Wxr = (const float*)d_in[7];
    const float* W2l = (const float*)d_in[8];
    const float* b2  = (const float*)d_in[9];
    const float* W2r = (const float*)d_in[10];
    const float* g3  = (const float*)d_in[11];
    const float* be3 = (const float*)d_in[12];
    const float* g2  = (const float*)d_in[13];
    const float* be2 = (const float*)d_in[14];
    float* out = (float*)d_out;

    // workspace carve (16B aligned)
    char* w = (char*)d_ws;
    unsigned short* xb   = (unsigned short*)w; w += (size_t)NN * NF * 2;   // 25.6 MB
    unsigned short* h1b  = (unsigned short*)w; w += (size_t)NN * NF * 2;   // 25.6 MB
    unsigned short* aggb = (unsigned short*)w; w += (size_t)NN * NF * 2;   // 25.6 MB
    float* h2f = (float*)w; w += (size_t)NN * NF * 4;                      // 51.2 MB
    int* csr     = (int*)w; w += (size_t)NE * 4;                           // 6.4 MB
    int* row_ptr = (int*)w; w += (size_t)(NN + 4) * 4;
    int* deg     = (int*)w; w += (size_t)NN * 4;
    int* cursor  = (int*)w; w += (size_t)NN * 4;
    int* row_loc = (int*)w; w += (size_t)NN * 4;
    int* blocksum = (int*)w; w += 128 * 4;
    float* inv_cnt = (float*)w; w += (size_t)NN * 4;
    float* bnbuf   = (float*)w; w += 2 * NF * 4;
    unsigned short* Bp1 = (unsigned short*)w; w += (size_t)256 * NF * 2;   // 64 KB
    unsigned short* Bpx = (unsigned short*)w; w += (size_t)256 * NF * 2;   // 64 KB
    unsigned short* Bp2 = (unsigned short*)w; w += (size_t)128 * 80 * 2;   // 20 KB
    // overlays: conv2 temporaries live in dead buffers
    unsigned short* h2b = aggb;      // bf16 h2 (aggb dead after convx lin)
    unsigned short* t40 = xb;        // 8 MB  (xb dead after conv1)
    float* z40 = (float*)h1b;        // 16 MB (h1b dead after convx)

    const int nscan = (NN + 1023) / 1024;  // 98

    // ---- CSR build ----
    hipMemsetAsync(deg, 0, (size_t)NN * 4, stream);
    hipMemsetAsync(cursor, 0, (size_t)NN * 4, stream);
    hipMemsetAsync(bnbuf, 0, 2 * NF * 4, stream);
    deg_kernel<<<(NE + 255) / 256, 256, 0, stream>>>(dstv, deg);
    scan1_kernel<<<nscan, 1024, 0, stream>>>(deg, row_loc, blocksum);
    scan2_kernel<<<1, 128, 0, stream>>>(blocksum, nscan);
    scan3_kernel<<<nscan, 1024, 0, stream>>>(deg, row_loc, blocksum, row_ptr, inv_cnt);
    fill_kernel<<<(NE + 255) / 256, 256, 0, stream>>>(srcv, dstv, row_ptr, cursor, csr);

    // ---- prep: x -> bf16; pack weights ----
    f2b4_kernel<<<(NN * NF / 4 + 255) / 256, 256, 0, stream>>>(x, xb, NN * NF / 4);
    pack_w_kernel<<<64, 64, 0, stream>>>(W1l, W1r, Bp1);
    pack_w_kernel<<<64, 64, 0, stream>>>(Wxl, Wxr, Bpx);
    pack_w80_kernel<<<20, 64, 0, stream>>>(W2l, W2r, Bp2);

    const int nblk_lin = (NN + 63) / 64;  // 1563

    // ---- conv1: h1 = relu([mean(x)|x] @ Bp1 + b1) -> h1b (bf16) ----
    agg_mean_bf16<<<(NN + 3) / 4, 256, 0, stream>>>(xb, csr, row_ptr, inv_cnt, aggb);
    lin_mfma_kernel<true, true><<<nblk_lin, 256, 0, stream>>>(aggb, xb, Bp1, b1, h1b, nullptr);

    // ---- convx: h2 = [mean(h1)|h1] @ Bpx + bx -> h2f (fp32) ----
    agg_mean_bf16<<<(NN + 3) / 4, 256, 0, stream>>>(h1b, csr, row_ptr, inv_cnt, aggb);
    lin_mfma_kernel<false, false><<<nblk_lin, 256, 0, stream>>>(aggb, h1b, Bpx, bx, nullptr, h2f);

    // ---- batch_norm3 + relu -> h2b (bf16) ----
    bn_stats_kernel<<<256, 128, 0, stream>>>(h2f, bnbuf, NF);
    bn_apply_relu_b16_kernel<<<(NN * NF + 255) / 256, 256, 0, stream>>>(h2f, bnbuf, g3, be3, h2b, 1.0f / NN);

    // ---- conv2 (transform-first, MFMA) ----
    lin80_mfma_kernel<<<nblk_lin, 256, 0, stream>>>(h2b, Bp2, b2, t40, z40);
    agg40_add_bf16<<<(NN + 3) / 4, 256, 0, stream>>>(t40, z40, csr, row_ptr, inv_cnt, out);

    // ---- batch_norm2 (in place on out) ----
    hipMemsetAsync(bnbuf, 0, 2 * NC * 4, stream);
    bn_stats_kernel<<<256, 64, 0, stream>>>(out, bnbuf, NC);
    bn_apply_kernel<false><<<(NN * NC + 255) / 256, 256, 0, stream>>>(out, bnbuf, g2, be2, NC, 1.0f / NN);
}

// Round 5
// 672.644 us; speedup vs baseline: 2.8618x; 1.2462x over previous
//
#include <hip/hip_runtime.h>
#include <hip/hip_bf16.h>

#define NN 100000
#define NE 1600000
#define NF 128
#define NC 40
#define BN_EPS 1e-5f

typedef __attribute__((ext_vector_type(8))) short short8;
typedef __attribute__((ext_vector_type(4))) float float4v;

__device__ __forceinline__ unsigned short f2b(float f) {
    __hip_bfloat16 h = __float2bfloat16(f);
    return *reinterpret_cast<unsigned short*>(&h);
}
__device__ __forceinline__ float b2f_hi(unsigned u) { return __uint_as_float(u & 0xffff0000u); }
__device__ __forceinline__ float b2f_lo(unsigned u) { return __uint_as_float(u << 16); }

// ---------------- CSR build ----------------

__global__ __launch_bounds__(256) void deg_kernel(const int* __restrict__ dst, int* __restrict__ deg) {
    int e = blockIdx.x * blockDim.x + threadIdx.x;
    if (e < NE) atomicAdd(&deg[dst[e]], 1);
}

__global__ __launch_bounds__(1024) void scan1_kernel(const int* __restrict__ deg,
                                                     int* __restrict__ row_loc,
                                                     int* __restrict__ blocksum) {
    __shared__ int lds[1024];
    int t = threadIdx.x;
    int i = blockIdx.x * 1024 + t;
    int v = (i < NN) ? deg[i] : 0;
    lds[t] = v;
    __syncthreads();
    for (int off = 1; off < 1024; off <<= 1) {
        int u = (t >= off) ? lds[t - off] : 0;
        __syncthreads();
        lds[t] += u;
        __syncthreads();
    }
    if (i < NN) row_loc[i] = lds[t] - v;
    if (t == 1023) blocksum[blockIdx.x] = lds[1023];
}

__global__ __launch_bounds__(128) void scan2_kernel(int* __restrict__ blocksum, int nb) {
    __shared__ int lds[128];
    int t = threadIdx.x;
    int v = (t < nb) ? blocksum[t] : 0;
    lds[t] = v;
    __syncthreads();
    for (int off = 1; off < 128; off <<= 1) {
        int u = (t >= off) ? lds[t - off] : 0;
        __syncthreads();
        lds[t] += u;
        __syncthreads();
    }
    if (t < nb) blocksum[t] = lds[t] - v;
}

__global__ __launch_bounds__(1024) void scan3_kernel(const int* __restrict__ deg,
                                                     const int* __restrict__ row_loc,
                                                     const int* __restrict__ blockoff,
                                                     int* __restrict__ row_ptr,
                                                     float* __restrict__ inv_cnt) {
    int i = blockIdx.x * 1024 + threadIdx.x;
    if (i < NN) {
        row_ptr[i] = blockoff[blockIdx.x] + row_loc[i];
        int d = deg[i];
        inv_cnt[i] = 1.0f / (float)(d > 0 ? d : 1);
    }
    if (i == 0) row_ptr[NN] = NE;
}

__global__ __launch_bounds__(256) void fill_kernel(const int* __restrict__ src,
                                                   const int* __restrict__ dst,
                                                   const int* __restrict__ row_ptr,
                                                   int* __restrict__ cursor,
                                                   int* __restrict__ csr) {
    int e = blockIdx.x * blockDim.x + threadIdx.x;
    if (e < NE) {
        int d = dst[e];
        int pos = atomicAdd(&cursor[d], 1);
        csr[row_ptr[d] + pos] = src[e];
    }
}

// ---------------- fp32 -> bf16 bulk convert ----------------

__global__ __launch_bounds__(256) void f2b4_kernel(const float* __restrict__ in,
                                                   unsigned short* __restrict__ out, int n4) {
    int i = blockIdx.x * 256 + threadIdx.x;
    if (i < n4) {
        float4 v = ((const float4*)in)[i];
        ushort4 o;
        o.x = f2b(v.x); o.y = f2b(v.y); o.z = f2b(v.z); o.w = f2b(v.w);
        ((ushort4*)out)[i] = o;
    }
}

// ---------------- pack W into MFMA B-fragment order (K=256, N=128) ----------------

__global__ __launch_bounds__(64) void pack_w_kernel(const float* __restrict__ Wl,
                                                    const float* __restrict__ Wr,
                                                    unsigned short* __restrict__ Bp) {
    int nt = blockIdx.x & 7;
    int kk = blockIdx.x >> 3;
    int lane = threadIdx.x;
    int n = nt * 16 + (lane & 15);
    int kb = kk * 32 + (lane >> 4) * 8;
    size_t base = ((size_t)(kk * 8 + nt) * 64 + lane) * 8;
#pragma unroll
    for (int j = 0; j < 8; ++j) {
        int k = kb + j;
        float v = (k < NF) ? Wl[(size_t)n * NF + k] : Wr[(size_t)n * NF + (k - NF)];
        Bp[base + j] = f2b(v);
    }
}

// pack for conv2: K=128, N=80 (cols 0..39 = W2l, 40..79 = W2r). 20 blocks.
__global__ __launch_bounds__(64) void pack_w80_kernel(const float* __restrict__ Wl,
                                                      const float* __restrict__ Wr,
                                                      unsigned short* __restrict__ Bp) {
    int nt = blockIdx.x % 5;
    int kk = blockIdx.x / 5;
    int lane = threadIdx.x;
    int n = nt * 16 + (lane & 15);
    int kb = kk * 32 + (lane >> 4) * 8;
    size_t base = ((size_t)(kk * 5 + nt) * 64 + lane) * 8;
#pragma unroll
    for (int j = 0; j < 8; ++j) {
        int k = kb + j;
        float v = (n < NC) ? Wl[(size_t)n * NF + k] : Wr[(size_t)(n - NC) * NF + k];
        Bp[base + j] = f2b(v);
    }
}

// ---------------- mean aggregation over CSR (bf16 table, fp32 accum) ----------------

__global__ __launch_bounds__(256) void agg_mean_bf16(const unsigned short* __restrict__ X,
                                                     const int* __restrict__ csr,
                                                     const int* __restrict__ row_ptr,
                                                     const float* __restrict__ inv_cnt,
                                                     unsigned short* __restrict__ out) {
    int wave = threadIdx.x >> 6;
    int lane = threadIdx.x & 63;
    int n = blockIdx.x * 4 + wave;
    if (n >= NN) return;
    int s = row_ptr[n], e = row_ptr[n + 1];
    float a0 = 0.f, a1 = 0.f;
    int i = s;
    for (; i + 4 <= e; i += 4) {
        int s0 = csr[i], s1 = csr[i + 1], s2 = csr[i + 2], s3 = csr[i + 3];
        unsigned u0 = *(const unsigned*)(X + (size_t)s0 * NF + lane * 2);
        unsigned u1 = *(const unsigned*)(X + (size_t)s1 * NF + lane * 2);
        unsigned u2 = *(const unsigned*)(X + (size_t)s2 * NF + lane * 2);
        unsigned u3 = *(const unsigned*)(X + (size_t)s3 * NF + lane * 2);
        a0 += b2f_lo(u0) + b2f_lo(u1) + b2f_lo(u2) + b2f_lo(u3);
        a1 += b2f_hi(u0) + b2f_hi(u1) + b2f_hi(u2) + b2f_hi(u3);
    }
    for (; i < e; ++i) {
        unsigned u = *(const unsigned*)(X + (size_t)csr[i] * NF + lane * 2);
        a0 += b2f_lo(u);
        a1 += b2f_hi(u);
    }
    float ic = inv_cnt[n];
    unsigned short o0 = f2b(a0 * ic), o1 = f2b(a1 * ic);
    *(unsigned*)(out + (size_t)n * NF + lane * 2) = (unsigned)o0 | ((unsigned)o1 << 16);
}

// ---------------- MFMA linear (128-out, K=256) ----------------

template <bool RELU, bool OUT_BF16>
__global__ __launch_bounds__(256) void lin_mfma_kernel(const unsigned short* __restrict__ Ab,
                                                       const unsigned short* __restrict__ Xb,
                                                       const unsigned short* __restrict__ Bp,
                                                       const float* __restrict__ bias,
                                                       unsigned short* __restrict__ outb,
                                                       float* __restrict__ outf) {
    __shared__ unsigned short ldsB[32768];  // 64 KB
    int tid = threadIdx.x;
    {
        const float4* srcp = (const float4*)Bp;
        float4* dstp = (float4*)ldsB;
#pragma unroll
        for (int i = 0; i < 16; ++i) dstp[tid + i * 256] = srcp[tid + i * 256];
    }
    __syncthreads();

    int wave = tid >> 6;
    int lane = tid & 63;
    int quad = lane >> 4;
    int row = blockIdx.x * 64 + wave * 16 + (lane & 15);
    int rowc = row < NN ? row : (NN - 1);
    const unsigned short* arow = Ab + (size_t)rowc * NF;
    const unsigned short* xrow = Xb + (size_t)rowc * NF;

    float4v acc[8];
#pragma unroll
    for (int nt = 0; nt < 8; ++nt) acc[nt] = (float4v){0.f, 0.f, 0.f, 0.f};

#pragma unroll
    for (int kk = 0; kk < 8; ++kk) {
        int kb = (kk & 3) * 32 + quad * 8;
        const unsigned short* asrc = (kk < 4) ? arow : xrow;
        short8 afrag = *(const short8*)(asrc + kb);
#pragma unroll
        for (int nt = 0; nt < 8; ++nt) {
            short8 bfrag = *(const short8*)(ldsB + ((size_t)(kk * 8 + nt) * 64 + lane) * 8);
            acc[nt] = __builtin_amdgcn_mfma_f32_16x16x32_bf16(afrag, bfrag, acc[nt], 0, 0, 0);
        }
    }

    int orow = blockIdx.x * 64 + wave * 16 + quad * 4;
    int col = lane & 15;
#pragma unroll
    for (int nt = 0; nt < 8; ++nt) {
        int c = nt * 16 + col;
        float bv = bias[c];
#pragma unroll
        for (int r = 0; r < 4; ++r) {
            int rr = orow + r;
            if (rr < NN) {
                float v = acc[nt][r] + bv;
                if (RELU) v = fmaxf(v, 0.f);
                if (OUT_BF16) outb[(size_t)rr * NF + c] = f2b(v);
                else outf[(size_t)rr * NF + c] = v;
            }
        }
    }
}

// ---------------- MFMA linear for conv2 (80-out, K=128) ----------------

__global__ __launch_bounds__(256) void lin80_mfma_kernel(const unsigned short* __restrict__ Xb,
                                                         const unsigned short* __restrict__ Bp,
                                                         const float* __restrict__ b2,
                                                         unsigned short* __restrict__ t40,
                                                         float* __restrict__ z40) {
    __shared__ unsigned short ldsB[10240];  // 20 KB
    int tid = threadIdx.x;
    {
        const float4* srcp = (const float4*)Bp;
        float4* dstp = (float4*)ldsB;
#pragma unroll
        for (int i = 0; i < 5; ++i) dstp[tid + i * 256] = srcp[tid + i * 256];
    }
    __syncthreads();

    int wave = tid >> 6;
    int lane = tid & 63;
    int quad = lane >> 4;
    int row = blockIdx.x * 64 + wave * 16 + (lane & 15);
    int rowc = row < NN ? row : (NN - 1);
    const unsigned short* xrow = Xb + (size_t)rowc * NF;

    float4v acc[5];
#pragma unroll
    for (int nt = 0; nt < 5; ++nt) acc[nt] = (float4v){0.f, 0.f, 0.f, 0.f};

#pragma unroll
    for (int kk = 0; kk < 4; ++kk) {
        int kb = kk * 32 + quad * 8;
        short8 afrag = *(const short8*)(xrow + kb);
#pragma unroll
        for (int nt = 0; nt < 5; ++nt) {
            short8 bfrag = *(const short8*)(ldsB + ((size_t)(kk * 5 + nt) * 64 + lane) * 8);
            acc[nt] = __builtin_amdgcn_mfma_f32_16x16x32_bf16(afrag, bfrag, acc[nt], 0, 0, 0);
        }
    }

    int orow = blockIdx.x * 64 + wave * 16 + quad * 4;
    int col = lane & 15;
#pragma unroll
    for (int nt = 0; nt < 5; ++nt) {
        int c = nt * 16 + col;
#pragma unroll
        for (int r = 0; r < 4; ++r) {
            int rr = orow + r;
            if (rr < NN) {
                float v = acc[nt][r];
                if (c < NC) {
                    t40[(size_t)rr * NC + c] = f2b(v);
                } else {
                    z40[(size_t)rr * NC + (c - NC)] = v + b2[c - NC];
                }
            }
        }
    }
}

// lanes 0..19 each own feature pair (2*lane, 2*lane+1); T is bf16
__global__ __launch_bounds__(256) void agg40_add_bf16(const unsigned short* __restrict__ T,
                                                      const float* __restrict__ Z,
                                                      const int* __restrict__ csr,
                                                      const int* __restrict__ row_ptr,
                                                      const float* __restrict__ inv_cnt,
                                                      float* __restrict__ out) {
    int wave = threadIdx.x >> 6;
    int lane = threadIdx.x & 63;
    int n = blockIdx.x * 4 + wave;
    if (n >= NN || lane >= 20) return;
    int s = row_ptr[n], e = row_ptr[n + 1];
    float a0 = 0.f, a1 = 0.f;
    int i = s;
    for (; i + 4 <= e; i += 4) {
        int s0 = csr[i], s1 = csr[i + 1], s2 = csr[i + 2], s3 = csr[i + 3];
        unsigned u0 = *(const unsigned*)(T + (size_t)s0 * NC + lane * 2);
        unsigned u1 = *(const unsigned*)(T + (size_t)s1 * NC + lane * 2);
        unsigned u2 = *(const unsigned*)(T + (size_t)s2 * NC + lane * 2);
        unsigned u3 = *(const unsigned*)(T + (size_t)s3 * NC + lane * 2);
        a0 += b2f_lo(u0) + b2f_lo(u1) + b2f_lo(u2) + b2f_lo(u3);
        a1 += b2f_hi(u0) + b2f_hi(u1) + b2f_hi(u2) + b2f_hi(u3);
    }
    for (; i < e; ++i) {
        unsigned u = *(const unsigned*)(T + (size_t)csr[i] * NC + lane * 2);
        a0 += b2f_lo(u);
        a1 += b2f_hi(u);
    }
    float ic = inv_cnt[n];
    const float2 zv = *(const float2*)(Z + (size_t)n * NC + lane * 2);
    float2 o;
    o.x = a0 * ic + zv.x;
    o.y = a1 * ic + zv.y;
    *(float2*)(out + (size_t)n * NC + lane * 2) = o;
}

// ---------------- batch norm stats: parallel column reduction ----------------
// Each thread owns a FIXED float4 column group (stride = grid*256 float4s is a
// multiple of F/4), accumulates sum/sumsq in registers; LDS fold; F*2 global
// atomics per block. Launch grid: BN_GRID blocks.
#define BN_GRID 640  // 640*256 divisible by 10 (F=40) and 32 (F=128)

template <int F>
__global__ __launch_bounds__(256) void bn_stats2_kernel(const float* __restrict__ X,
                                                        float* __restrict__ sums) {
    __shared__ float ls[2 * F];
    int tid = threadIdx.x;
    for (int i = tid; i < 2 * F; i += 256) ls[i] = 0.f;
    __syncthreads();

    const int total4 = NN * F / 4;
    const int stride = BN_GRID * 256;
    int i0 = blockIdx.x * 256 + tid;
    int c0 = (i0 * 4) % F;  // fixed across iterations (stride*4 % F == 0)
    float s0 = 0.f, s1 = 0.f, s2 = 0.f, s3 = 0.f;
    float q0 = 0.f, q1 = 0.f, q2 = 0.f, q3 = 0.f;
    for (int i = i0; i < total4; i += stride) {
        float4 v = ((const float4*)X)[i];
        s0 += v.x; q0 += v.x * v.x;
        s1 += v.y; q1 += v.y * v.y;
        s2 += v.z; q2 += v.z * v.z;
        s3 += v.w; q3 += v.w * v.w;
    }
    atomicAdd(&ls[c0 + 0], s0); atomicAdd(&ls[F + c0 + 0], q0);
    atomicAdd(&ls[c0 + 1], s1); atomicAdd(&ls[F + c0 + 1], q1);
    atomicAdd(&ls[c0 + 2], s2); atomicAdd(&ls[F + c0 + 2], q2);
    atomicAdd(&ls[c0 + 3], s3); atomicAdd(&ls[F + c0 + 3], q3);
    __syncthreads();
    for (int i = tid; i < 2 * F; i += 256) atomicAdd(&sums[i], ls[i]);
}

// BN3 apply + relu, emit bf16 (conv2 input)
__global__ __launch_bounds__(256) void bn_apply_relu_b16_kernel(const float* __restrict__ X,
                                                                const float* __restrict__ sums,
                                                                const float* __restrict__ g,
                                                                const float* __restrict__ be,
                                                                unsigned short* __restrict__ outb,
                                                                float invN) {
    size_t idx = (size_t)blockIdx.x * blockDim.x + threadIdx.x;
    if (idx >= (size_t)NN * NF) return;
    int t = (int)(idx & (NF - 1));
    float mu = sums[t] * invN;
    float var = sums[NF + t] * invN - mu * mu;
    float scale = rsqrtf(var + BN_EPS) * g[t];
    float v = (X[idx] - mu) * scale + be[t];
    v = fmaxf(v, 0.f);
    outb[idx] = f2b(v);
}

template <bool RELU>
__global__ __launch_bounds__(256) void bn_apply_kernel(float* __restrict__ X,
                                                       const float* __restrict__ sums,
                                                       const float* __restrict__ g,
                                                       const float* __restrict__ be,
                                                       int F, float invN) {
    size_t idx = (size_t)blockIdx.x * blockDim.x + threadIdx.x;
    size_t total = (size_t)NN * F;
    if (idx >= total) return;
    int t = (int)(idx % F);
    float mu = sums[t] * invN;
    float var = sums[F + t] * invN - mu * mu;
    float scale = rsqrtf(var + BN_EPS) * g[t];
    float v = (X[idx] - mu) * scale + be[t];
    if (RELU) v = fmaxf(v, 0.f);
    X[idx] = v;
}

// ---------------- launch ----------------

extern "C" void kernel_launch(void* const* d_in, const int* in_sizes, int n_in,
                              void* d_out, int out_size, void* d_ws, size_t ws_size,
                              hipStream_t stream) {
    const float* x   = (const float*)d_in[0];
    const int*   ei  = (const int*)d_in[1];
    const int*   srcv = ei;
    const int*   dstv = ei + NE;
    const float* W1l = (const float*)d_in[2];
    const float* b1  = (const float*)d_in[3];
    const float* W1r = (const float*)d_in[4];
    const float* Wxl = (const float*)d_in[5];
    const float* bx  = (const float*)d_in[6];
    const float* Wxr = (const float*)d_in[7];
    const float* W2l = (const float*)d_in[8];
    const float* b2  = (const float*)d_in[9];
    const float* W2r = (const float*)d_in[10];
    const float* g3  = (const float*)d_in[11];
    const float* be3 = (const float*)d_in[12];
    const float* g2  = (const float*)d_in[13];
    const float* be2 = (const float*)d_in[14];
    float* out = (float*)d_out;

    // workspace carve (16B aligned)
    char* w = (char*)d_ws;
    unsigned short* xb   = (unsigned short*)w; w += (size_t)NN * NF * 2;   // 25.6 MB
    unsigned short* h1b  = (unsigned short*)w; w += (size_t)NN * NF * 2;   // 25.6 MB
    unsigned short* aggb = (unsigned short*)w; w += (size_t)NN * NF * 2;   // 25.6 MB
    float* h2f = (float*)w; w += (size_t)NN * NF * 4;                      // 51.2 MB
    int* csr     = (int*)w; w += (size_t)NE * 4;                           // 6.4 MB
    int* row_ptr = (int*)w; w += (size_t)(NN + 4) * 4;
    int* deg     = (int*)w; w += (size_t)NN * 4;
    int* cursor  = (int*)w; w += (size_t)NN * 4;
    int* row_loc = (int*)w; w += (size_t)NN * 4;
    int* blocksum = (int*)w; w += 128 * 4;
    float* inv_cnt = (float*)w; w += (size_t)NN * 4;
    float* bnbuf   = (float*)w; w += 2 * NF * 4;
    unsigned short* Bp1 = (unsigned short*)w; w += (size_t)256 * NF * 2;   // 64 KB
    unsigned short* Bpx = (unsigned short*)w; w += (size_t)256 * NF * 2;   // 64 KB
    unsigned short* Bp2 = (unsigned short*)w; w += (size_t)128 * 80 * 2;   // 20 KB
    // overlays
    unsigned short* h2b = aggb;
    unsigned short* t40 = xb;
    float* z40 = (float*)h1b;

    const int nscan = (NN + 1023) / 1024;  // 98

    // ---- CSR build ----
    hipMemsetAsync(deg, 0, (size_t)NN * 4, stream);
    hipMemsetAsync(cursor, 0, (size_t)NN * 4, stream);
    hipMemsetAsync(bnbuf, 0, 2 * NF * 4, stream);
    deg_kernel<<<(NE + 255) / 256, 256, 0, stream>>>(dstv, deg);
    scan1_kernel<<<nscan, 1024, 0, stream>>>(deg, row_loc, blocksum);
    scan2_kernel<<<1, 128, 0, stream>>>(blocksum, nscan);
    scan3_kernel<<<nscan, 1024, 0, stream>>>(deg, row_loc, blocksum, row_ptr, inv_cnt);
    fill_kernel<<<(NE + 255) / 256, 256, 0, stream>>>(srcv, dstv, row_ptr, cursor, csr);

    // ---- prep: x -> bf16; pack weights ----
    f2b4_kernel<<<(NN * NF / 4 + 255) / 256, 256, 0, stream>>>(x, xb, NN * NF / 4);
    pack_w_kernel<<<64, 64, 0, stream>>>(W1l, W1r, Bp1);
    pack_w_kernel<<<64, 64, 0, stream>>>(Wxl, Wxr, Bpx);
    pack_w80_kernel<<<20, 64, 0, stream>>>(W2l, W2r, Bp2);

    const int nblk_lin = (NN + 63) / 64;  // 1563

    // ---- conv1: h1 = relu([mean(x)|x] @ Bp1 + b1) -> h1b (bf16) ----
    agg_mean_bf16<<<(NN + 3) / 4, 256, 0, stream>>>(xb, csr, row_ptr, inv_cnt, aggb);
    lin_mfma_kernel<true, true><<<nblk_lin, 256, 0, stream>>>(aggb, xb, Bp1, b1, h1b, nullptr);

    // ---- convx: h2 = [mean(h1)|h1] @ Bpx + bx -> h2f (fp32) ----
    agg_mean_bf16<<<(NN + 3) / 4, 256, 0, stream>>>(h1b, csr, row_ptr, inv_cnt, aggb);
    lin_mfma_kernel<false, false><<<nblk_lin, 256, 0, stream>>>(aggb, h1b, Bpx, bx, nullptr, h2f);

    // ---- batch_norm3 + relu -> h2b (bf16) ----
    bn_stats2_kernel<NF><<<BN_GRID, 256, 0, stream>>>(h2f, bnbuf);
    bn_apply_relu_b16_kernel<<<(NN * NF + 255) / 256, 256, 0, stream>>>(h2f, bnbuf, g3, be3, h2b, 1.0f / NN);

    // ---- conv2 (transform-first, MFMA) ----
    lin80_mfma_kernel<<<nblk_lin, 256, 0, stream>>>(h2b, Bp2, b2, t40, z40);
    agg40_add_bf16<<<(NN + 3) / 4, 256, 0, stream>>>(t40, z40, csr, row_ptr, inv_cnt, out);

    // ---- batch_norm2 (in place on out) ----
    hipMemsetAsync(bnbuf, 0, 2 * NC * 4, stream);
    bn_stats2_kernel<NC><<<BN_GRID, 256, 0, stream>>>(out, bnbuf);
    bn_apply_kernel<false><<<(NN * NC + 255) / 256, 256, 0, stream>>>(out, bnbuf, g2, be2, NC, 1.0f / NN);
}

// Round 6
// 662.561 us; speedup vs baseline: 2.9053x; 1.0152x over previous
//
#include <hip/hip_runtime.h>
#include <hip/hip_bf16.h>

#define NN 100000
#define NE 1600000
#define NF 128
#define NC 40
#define BN_EPS 1e-5f

typedef __attribute__((ext_vector_type(8))) short short8;
typedef __attribute__((ext_vector_type(4))) float float4v;

__device__ __forceinline__ unsigned short f2b(float f) {
    __hip_bfloat16 h = __float2bfloat16(f);
    return *reinterpret_cast<unsigned short*>(&h);
}
__device__ __forceinline__ float b2f_hi(unsigned u) { return __uint_as_float(u & 0xffff0000u); }
__device__ __forceinline__ float b2f_lo(unsigned u) { return __uint_as_float(u << 16); }

// ---------------- CSR build ----------------

__global__ __launch_bounds__(256) void deg_kernel(const int* __restrict__ dst, int* __restrict__ deg) {
    int e = blockIdx.x * blockDim.x + threadIdx.x;
    if (e < NE) atomicAdd(&deg[dst[e]], 1);
}

__global__ __launch_bounds__(1024) void scan1_kernel(const int* __restrict__ deg,
                                                     int* __restrict__ row_loc,
                                                     int* __restrict__ blocksum) {
    __shared__ int lds[1024];
    int t = threadIdx.x;
    int i = blockIdx.x * 1024 + t;
    int v = (i < NN) ? deg[i] : 0;
    lds[t] = v;
    __syncthreads();
    for (int off = 1; off < 1024; off <<= 1) {
        int u = (t >= off) ? lds[t - off] : 0;
        __syncthreads();
        lds[t] += u;
        __syncthreads();
    }
    if (i < NN) row_loc[i] = lds[t] - v;
    if (t == 1023) blocksum[blockIdx.x] = lds[1023];
}

__global__ __launch_bounds__(128) void scan2_kernel(int* __restrict__ blocksum, int nb) {
    __shared__ int lds[128];
    int t = threadIdx.x;
    int v = (t < nb) ? blocksum[t] : 0;
    lds[t] = v;
    __syncthreads();
    for (int off = 1; off < 128; off <<= 1) {
        int u = (t >= off) ? lds[t - off] : 0;
        __syncthreads();
        lds[t] += u;
        __syncthreads();
    }
    if (t < nb) blocksum[t] = lds[t] - v;
}

__global__ __launch_bounds__(1024) void scan3_kernel(const int* __restrict__ deg,
                                                     const int* __restrict__ row_loc,
                                                     const int* __restrict__ blockoff,
                                                     int* __restrict__ row_ptr,
                                                     float* __restrict__ inv_cnt) {
    int i = blockIdx.x * 1024 + threadIdx.x;
    if (i < NN) {
        row_ptr[i] = blockoff[blockIdx.x] + row_loc[i];
        int d = deg[i];
        inv_cnt[i] = 1.0f / (float)(d > 0 ? d : 1);
    }
    if (i == 0) row_ptr[NN] = NE;
}

// XCD-bucketed CSR fill: bucket = blockIdx & 7 (round-robin block->XCD heuristic).
// Each bucket owns a 12500-node dst range, so each csr cache line is written by
// (ideally) ONE XCD's L2 -> full-line writebacks instead of 16x partial-line
// amplification. All buckets sweep the edge list in lockstep (L3-friendly).
#define FILL_CHUNKS 128
__global__ __launch_bounds__(256) void fill_bucket_kernel(const int* __restrict__ src,
                                                          const int* __restrict__ dst,
                                                          const int* __restrict__ row_ptr,
                                                          int* __restrict__ cursor,
                                                          int* __restrict__ csr) {
    const int bucket = blockIdx.x & 7;
    const int chunk = blockIdx.x >> 3;
    const int nlo = bucket * (NN / 8);
    const int nhi = nlo + (NN / 8);
    const int stride = FILL_CHUNKS * 256;
    for (int e = chunk * 256 + threadIdx.x; e < NE; e += stride) {
        int d = dst[e];
        if (d >= nlo && d < nhi) {
            int pos = atomicAdd(&cursor[d], 1);
            csr[row_ptr[d] + pos] = src[e];
        }
    }
}

// ---------------- fp32 -> bf16 bulk convert ----------------

__global__ __launch_bounds__(256) void f2b4_kernel(const float* __restrict__ in,
                                                   unsigned short* __restrict__ out, int n4) {
    int i = blockIdx.x * 256 + threadIdx.x;
    if (i < n4) {
        float4 v = ((const float4*)in)[i];
        ushort4 o;
        o.x = f2b(v.x); o.y = f2b(v.y); o.z = f2b(v.z); o.w = f2b(v.w);
        ((ushort4*)out)[i] = o;
    }
}

// ---------------- pack W into MFMA B-fragment order (K=256, N=128) ----------------

__global__ __launch_bounds__(64) void pack_w_kernel(const float* __restrict__ Wl,
                                                    const float* __restrict__ Wr,
                                                    unsigned short* __restrict__ Bp) {
    int nt = blockIdx.x & 7;
    int kk = blockIdx.x >> 3;
    int lane = threadIdx.x;
    int n = nt * 16 + (lane & 15);
    int kb = kk * 32 + (lane >> 4) * 8;
    size_t base = ((size_t)(kk * 8 + nt) * 64 + lane) * 8;
#pragma unroll
    for (int j = 0; j < 8; ++j) {
        int k = kb + j;
        float v = (k < NF) ? Wl[(size_t)n * NF + k] : Wr[(size_t)n * NF + (k - NF)];
        Bp[base + j] = f2b(v);
    }
}

// pack for conv2: K=128, N=80 (cols 0..39 = W2l, 40..79 = W2r). 20 blocks.
__global__ __launch_bounds__(64) void pack_w80_kernel(const float* __restrict__ Wl,
                                                      const float* __restrict__ Wr,
                                                      unsigned short* __restrict__ Bp) {
    int nt = blockIdx.x % 5;
    int kk = blockIdx.x / 5;
    int lane = threadIdx.x;
    int n = nt * 16 + (lane & 15);
    int kb = kk * 32 + (lane >> 4) * 8;
    size_t base = ((size_t)(kk * 5 + nt) * 64 + lane) * 8;
#pragma unroll
    for (int j = 0; j < 8; ++j) {
        int k = kb + j;
        float v = (n < NC) ? Wl[(size_t)n * NF + k] : Wr[(size_t)(n - NC) * NF + k];
        Bp[base + j] = f2b(v);
    }
}

// ---------------- mean aggregation over CSR (bf16 table, fp32 accum) ----------------

__global__ __launch_bounds__(256) void agg_mean_bf16(const unsigned short* __restrict__ X,
                                                     const int* __restrict__ csr,
                                                     const int* __restrict__ row_ptr,
                                                     const float* __restrict__ inv_cnt,
                                                     unsigned short* __restrict__ out) {
    int wave = threadIdx.x >> 6;
    int lane = threadIdx.x & 63;
    int n = blockIdx.x * 4 + wave;
    if (n >= NN) return;
    int s = row_ptr[n], e = row_ptr[n + 1];
    float a0 = 0.f, a1 = 0.f;
    int i = s;
    for (; i + 4 <= e; i += 4) {
        int s0 = csr[i], s1 = csr[i + 1], s2 = csr[i + 2], s3 = csr[i + 3];
        unsigned u0 = *(const unsigned*)(X + (size_t)s0 * NF + lane * 2);
        unsigned u1 = *(const unsigned*)(X + (size_t)s1 * NF + lane * 2);
        unsigned u2 = *(const unsigned*)(X + (size_t)s2 * NF + lane * 2);
        unsigned u3 = *(const unsigned*)(X + (size_t)s3 * NF + lane * 2);
        a0 += b2f_lo(u0) + b2f_lo(u1) + b2f_lo(u2) + b2f_lo(u3);
        a1 += b2f_hi(u0) + b2f_hi(u1) + b2f_hi(u2) + b2f_hi(u3);
    }
    for (; i < e; ++i) {
        unsigned u = *(const unsigned*)(X + (size_t)csr[i] * NF + lane * 2);
        a0 += b2f_lo(u);
        a1 += b2f_hi(u);
    }
    float ic = inv_cnt[n];
    unsigned short o0 = f2b(a0 * ic), o1 = f2b(a1 * ic);
    *(unsigned*)(out + (size_t)n * NF + lane * 2) = (unsigned)o0 | ((unsigned)o1 << 16);
}

// ---------------- MFMA linear (128-out, K=256) ----------------

template <bool RELU, bool OUT_BF16>
__global__ __launch_bounds__(256) void lin_mfma_kernel(const unsigned short* __restrict__ Ab,
                                                       const unsigned short* __restrict__ Xb,
                                                       const unsigned short* __restrict__ Bp,
                                                       const float* __restrict__ bias,
                                                       unsigned short* __restrict__ outb,
                                                       float* __restrict__ outf) {
    __shared__ unsigned short ldsB[32768];  // 64 KB
    int tid = threadIdx.x;
    {
        const float4* srcp = (const float4*)Bp;
        float4* dstp = (float4*)ldsB;
#pragma unroll
        for (int i = 0; i < 16; ++i) dstp[tid + i * 256] = srcp[tid + i * 256];
    }
    __syncthreads();

    int wave = tid >> 6;
    int lane = tid & 63;
    int quad = lane >> 4;
    int row = blockIdx.x * 64 + wave * 16 + (lane & 15);
    int rowc = row < NN ? row : (NN - 1);
    const unsigned short* arow = Ab + (size_t)rowc * NF;
    const unsigned short* xrow = Xb + (size_t)rowc * NF;

    float4v acc[8];
#pragma unroll
    for (int nt = 0; nt < 8; ++nt) acc[nt] = (float4v){0.f, 0.f, 0.f, 0.f};

#pragma unroll
    for (int kk = 0; kk < 8; ++kk) {
        int kb = (kk & 3) * 32 + quad * 8;
        const unsigned short* asrc = (kk < 4) ? arow : xrow;
        short8 afrag = *(const short8*)(asrc + kb);
#pragma unroll
        for (int nt = 0; nt < 8; ++nt) {
            short8 bfrag = *(const short8*)(ldsB + ((size_t)(kk * 8 + nt) * 64 + lane) * 8);
            acc[nt] = __builtin_amdgcn_mfma_f32_16x16x32_bf16(afrag, bfrag, acc[nt], 0, 0, 0);
        }
    }

    int orow = blockIdx.x * 64 + wave * 16 + quad * 4;
    int col = lane & 15;
#pragma unroll
    for (int nt = 0; nt < 8; ++nt) {
        int c = nt * 16 + col;
        float bv = bias[c];
#pragma unroll
        for (int r = 0; r < 4; ++r) {
            int rr = orow + r;
            if (rr < NN) {
                float v = acc[nt][r] + bv;
                if (RELU) v = fmaxf(v, 0.f);
                if (OUT_BF16) outb[(size_t)rr * NF + c] = f2b(v);
                else outf[(size_t)rr * NF + c] = v;
            }
        }
    }
}

// ---------------- MFMA linear for conv2 (80-out, K=128) ----------------

__global__ __launch_bounds__(256) void lin80_mfma_kernel(const unsigned short* __restrict__ Xb,
                                                         const unsigned short* __restrict__ Bp,
                                                         const float* __restrict__ b2,
                                                         unsigned short* __restrict__ t40,
                                                         float* __restrict__ z40) {
    __shared__ unsigned short ldsB[10240];  // 20 KB
    int tid = threadIdx.x;
    {
        const float4* srcp = (const float4*)Bp;
        float4* dstp = (float4*)ldsB;
#pragma unroll
        for (int i = 0; i < 5; ++i) dstp[tid + i * 256] = srcp[tid + i * 256];
    }
    __syncthreads();

    int wave = tid >> 6;
    int lane = tid & 63;
    int quad = lane >> 4;
    int row = blockIdx.x * 64 + wave * 16 + (lane & 15);
    int rowc = row < NN ? row : (NN - 1);
    const unsigned short* xrow = Xb + (size_t)rowc * NF;

    float4v acc[5];
#pragma unroll
    for (int nt = 0; nt < 5; ++nt) acc[nt] = (float4v){0.f, 0.f, 0.f, 0.f};

#pragma unroll
    for (int kk = 0; kk < 4; ++kk) {
        int kb = kk * 32 + quad * 8;
        short8 afrag = *(const short8*)(xrow + kb);
#pragma unroll
        for (int nt = 0; nt < 5; ++nt) {
            short8 bfrag = *(const short8*)(ldsB + ((size_t)(kk * 5 + nt) * 64 + lane) * 8);
            acc[nt] = __builtin_amdgcn_mfma_f32_16x16x32_bf16(afrag, bfrag, acc[nt], 0, 0, 0);
        }
    }

    int orow = blockIdx.x * 64 + wave * 16 + quad * 4;
    int col = lane & 15;
#pragma unroll
    for (int nt = 0; nt < 5; ++nt) {
        int c = nt * 16 + col;
#pragma unroll
        for (int r = 0; r < 4; ++r) {
            int rr = orow + r;
            if (rr < NN) {
                float v = acc[nt][r];
                if (c < NC) {
                    t40[(size_t)rr * NC + c] = f2b(v);
                } else {
                    z40[(size_t)rr * NC + (c - NC)] = v + b2[c - NC];
                }
            }
        }
    }
}

// lanes 0..19 each own feature pair (2*lane, 2*lane+1); T is bf16
__global__ __launch_bounds__(256) void agg40_add_bf16(const unsigned short* __restrict__ T,
                                                      const float* __restrict__ Z,
                                                      const int* __restrict__ csr,
                                                      const int* __restrict__ row_ptr,
                                                      const float* __restrict__ inv_cnt,
                                                      float* __restrict__ out) {
    int wave = threadIdx.x >> 6;
    int lane = threadIdx.x & 63;
    int n = blockIdx.x * 4 + wave;
    if (n >= NN || lane >= 20) return;
    int s = row_ptr[n], e = row_ptr[n + 1];
    float a0 = 0.f, a1 = 0.f;
    int i = s;
    for (; i + 4 <= e; i += 4) {
        int s0 = csr[i], s1 = csr[i + 1], s2 = csr[i + 2], s3 = csr[i + 3];
        unsigned u0 = *(const unsigned*)(T + (size_t)s0 * NC + lane * 2);
        unsigned u1 = *(const unsigned*)(T + (size_t)s1 * NC + lane * 2);
        unsigned u2 = *(const unsigned*)(T + (size_t)s2 * NC + lane * 2);
        unsigned u3 = *(const unsigned*)(T + (size_t)s3 * NC + lane * 2);
        a0 += b2f_lo(u0) + b2f_lo(u1) + b2f_lo(u2) + b2f_lo(u3);
        a1 += b2f_hi(u0) + b2f_hi(u1) + b2f_hi(u2) + b2f_hi(u3);
    }
    for (; i < e; ++i) {
        unsigned u = *(const unsigned*)(T + (size_t)csr[i] * NC + lane * 2);
        a0 += b2f_lo(u);
        a1 += b2f_hi(u);
    }
    float ic = inv_cnt[n];
    const float2 zv = *(const float2*)(Z + (size_t)n * NC + lane * 2);
    float2 o;
    o.x = a0 * ic + zv.x;
    o.y = a1 * ic + zv.y;
    *(float2*)(out + (size_t)n * NC + lane * 2) = o;
}

// ---------------- batch norm stats: parallel column reduction ----------------
#define BN_GRID 640  // 640*256 divisible by 10 (F=40) and 32 (F=128)

template <int F>
__global__ __launch_bounds__(256) void bn_stats2_kernel(const float* __restrict__ X,
                                                        float* __restrict__ sums) {
    __shared__ float ls[2 * F];
    int tid = threadIdx.x;
    for (int i = tid; i < 2 * F; i += 256) ls[i] = 0.f;
    __syncthreads();

    const int total4 = NN * F / 4;
    const int stride = BN_GRID * 256;
    int i0 = blockIdx.x * 256 + tid;
    int c0 = (i0 * 4) % F;  // fixed across iterations (stride*4 % F == 0)
    float s0 = 0.f, s1 = 0.f, s2 = 0.f, s3 = 0.f;
    float q0 = 0.f, q1 = 0.f, q2 = 0.f, q3 = 0.f;
    for (int i = i0; i < total4; i += stride) {
        float4 v = ((const float4*)X)[i];
        s0 += v.x; q0 += v.x * v.x;
        s1 += v.y; q1 += v.y * v.y;
        s2 += v.z; q2 += v.z * v.z;
        s3 += v.w; q3 += v.w * v.w;
    }
    atomicAdd(&ls[c0 + 0], s0); atomicAdd(&ls[F + c0 + 0], q0);
    atomicAdd(&ls[c0 + 1], s1); atomicAdd(&ls[F + c0 + 1], q1);
    atomicAdd(&ls[c0 + 2], s2); atomicAdd(&ls[F + c0 + 2], q2);
    atomicAdd(&ls[c0 + 3], s3); atomicAdd(&ls[F + c0 + 3], q3);
    __syncthreads();
    for (int i = tid; i < 2 * F; i += 256) atomicAdd(&sums[i], ls[i]);
}

// BN3 apply + relu, emit bf16 (conv2 input)
__global__ __launch_bounds__(256) void bn_apply_relu_b16_kernel(const float* __restrict__ X,
                                                                const float* __restrict__ sums,
                                                                const float* __restrict__ g,
                                                                const float* __restrict__ be,
                                                                unsigned short* __restrict__ outb,
                                                                float invN) {
    size_t idx = (size_t)blockIdx.x * blockDim.x + threadIdx.x;
    if (idx >= (size_t)NN * NF) return;
    int t = (int)(idx & (NF - 1));
    float mu = sums[t] * invN;
    float var = sums[NF + t] * invN - mu * mu;
    float scale = rsqrtf(var + BN_EPS) * g[t];
    float v = (X[idx] - mu) * scale + be[t];
    v = fmaxf(v, 0.f);
    outb[idx] = f2b(v);
}

template <bool RELU>
__global__ __launch_bounds__(256) void bn_apply_kernel(float* __restrict__ X,
                                                       const float* __restrict__ sums,
                                                       const float* __restrict__ g,
                                                       const float* __restrict__ be,
                                                       int F, float invN) {
    size_t idx = (size_t)blockIdx.x * blockDim.x + threadIdx.x;
    size_t total = (size_t)NN * F;
    if (idx >= total) return;
    int t = (int)(idx % F);
    float mu = sums[t] * invN;
    float var = sums[F + t] * invN - mu * mu;
    float scale = rsqrtf(var + BN_EPS) * g[t];
    float v = (X[idx] - mu) * scale + be[t];
    if (RELU) v = fmaxf(v, 0.f);
    X[idx] = v;
}

// ---------------- launch ----------------

extern "C" void kernel_launch(void* const* d_in, const int* in_sizes, int n_in,
                              void* d_out, int out_size, void* d_ws, size_t ws_size,
                              hipStream_t stream) {
    const float* x   = (const float*)d_in[0];
    const int*   ei  = (const int*)d_in[1];
    const int*   srcv = ei;
    const int*   dstv = ei + NE;
    const float* W1l = (const float*)d_in[2];
    const float* b1  = (const float*)d_in[3];
    const float* W1r = (const float*)d_in[4];
    const float* Wxl = (const float*)d_in[5];
    const float* bx  = (const float*)d_in[6];
    const float* Wxr = (const float*)d_in[7];
    const float* W2l = (const float*)d_in[8];
    const float* b2  = (const float*)d_in[9];
    const float* W2r = (const float*)d_in[10];
    const float* g3  = (const float*)d_in[11];
    const float* be3 = (const float*)d_in[12];
    const float* g2  = (const float*)d_in[13];
    const float* be2 = (const float*)d_in[14];
    float* out = (float*)d_out;

    // workspace carve (16B aligned)
    char* w = (char*)d_ws;
    unsigned short* xb   = (unsigned short*)w; w += (size_t)NN * NF * 2;   // 25.6 MB
    unsigned short* h1b  = (unsigned short*)w; w += (size_t)NN * NF * 2;   // 25.6 MB
    unsigned short* aggb = (unsigned short*)w; w += (size_t)NN * NF * 2;   // 25.6 MB
    float* h2f = (float*)w; w += (size_t)NN * NF * 4;                      // 51.2 MB
    int* csr     = (int*)w; w += (size_t)NE * 4;                           // 6.4 MB
    int* row_ptr = (int*)w; w += (size_t)(NN + 4) * 4;
    int* deg     = (int*)w; w += (size_t)NN * 4;
    int* cursor  = (int*)w; w += (size_t)NN * 4;
    int* row_loc = (int*)w; w += (size_t)NN * 4;
    int* blocksum = (int*)w; w += 128 * 4;
    float* inv_cnt = (float*)w; w += (size_t)NN * 4;
    float* bnbuf   = (float*)w; w += 2 * NF * 4;
    unsigned short* Bp1 = (unsigned short*)w; w += (size_t)256 * NF * 2;   // 64 KB
    unsigned short* Bpx = (unsigned short*)w; w += (size_t)256 * NF * 2;   // 64 KB
    unsigned short* Bp2 = (unsigned short*)w; w += (size_t)128 * 80 * 2;   // 20 KB
    // overlays
    unsigned short* h2b = aggb;
    unsigned short* t40 = xb;
    float* z40 = (float*)h1b;

    const int nscan = (NN + 1023) / 1024;  // 98

    // ---- CSR build ----
    hipMemsetAsync(deg, 0, (size_t)NN * 4, stream);
    hipMemsetAsync(cursor, 0, (size_t)NN * 4, stream);
    hipMemsetAsync(bnbuf, 0, 2 * NF * 4, stream);
    deg_kernel<<<(NE + 255) / 256, 256, 0, stream>>>(dstv, deg);
    scan1_kernel<<<nscan, 1024, 0, stream>>>(deg, row_loc, blocksum);
    scan2_kernel<<<1, 128, 0, stream>>>(blocksum, nscan);
    scan3_kernel<<<nscan, 1024, 0, stream>>>(deg, row_loc, blocksum, row_ptr, inv_cnt);
    fill_bucket_kernel<<<FILL_CHUNKS * 8, 256, 0, stream>>>(srcv, dstv, row_ptr, cursor, csr);

    // ---- prep: x -> bf16; pack weights ----
    f2b4_kernel<<<(NN * NF / 4 + 255) / 256, 256, 0, stream>>>(x, xb, NN * NF / 4);
    pack_w_kernel<<<64, 64, 0, stream>>>(W1l, W1r, Bp1);
    pack_w_kernel<<<64, 64, 0, stream>>>(Wxl, Wxr, Bpx);
    pack_w80_kernel<<<20, 64, 0, stream>>>(W2l, W2r, Bp2);

    const int nblk_lin = (NN + 63) / 64;  // 1563

    // ---- conv1: h1 = relu([mean(x)|x] @ Bp1 + b1) -> h1b (bf16) ----
    agg_mean_bf16<<<(NN + 3) / 4, 256, 0, stream>>>(xb, csr, row_ptr, inv_cnt, aggb);
    lin_mfma_kernel<true, true><<<nblk_lin, 256, 0, stream>>>(aggb, xb, Bp1, b1, h1b, nullptr);

    // ---- convx: h2 = [mean(h1)|h1] @ Bpx + bx -> h2f (fp32) ----
    agg_mean_bf16<<<(NN + 3) / 4, 256, 0, stream>>>(h1b, csr, row_ptr, inv_cnt, aggb);
    lin_mfma_kernel<false, false><<<nblk_lin, 256, 0, stream>>>(aggb, h1b, Bpx, bx, nullptr, h2f);

    // ---- batch_norm3 + relu -> h2b (bf16) ----
    bn_stats2_kernel<NF><<<BN_GRID, 256, 0, stream>>>(h2f, bnbuf);
    bn_apply_relu_b16_kernel<<<(NN * NF + 255) / 256, 256, 0, stream>>>(h2f, bnbuf, g3, be3, h2b, 1.0f / NN);

    // ---- conv2 (transform-first, MFMA) ----
    lin80_mfma_kernel<<<nblk_lin, 256, 0, stream>>>(h2b, Bp2, b2, t40, z40);
    agg40_add_bf16<<<(NN + 3) / 4, 256, 0, stream>>>(t40, z40, csr, row_ptr, inv_cnt, out);

    // ---- batch_norm2 (in place on out) ----
    hipMemsetAsync(bnbuf, 0, 2 * NC * 4, stream);
    bn_stats2_kernel<NC><<<BN_GRID, 256, 0, stream>>>(out, bnbuf);
    bn_apply_kernel<false><<<(NN * NC + 255) / 256, 256, 0, stream>>>(out, bnbuf, g2, be2, NC, 1.0f / NN);
}

// Round 7
// 655.573 us; speedup vs baseline: 2.9363x; 1.0107x over previous
//
#include <hip/hip_runtime.h>
#include <hip/hip_bf16.h>

#define NN 100000
#define NE 1600000
#define NF 128
#define NC 40
#define BN_EPS 1e-5f

typedef __attribute__((ext_vector_type(8))) short short8;
typedef __attribute__((ext_vector_type(4))) float float4v;

__device__ __forceinline__ unsigned short f2b(float f) {
    __hip_bfloat16 h = __float2bfloat16(f);
    return *reinterpret_cast<unsigned short*>(&h);
}
__device__ __forceinline__ float b2f_hi(unsigned u) { return __uint_as_float(u & 0xffff0000u); }
__device__ __forceinline__ float b2f_lo(unsigned u) { return __uint_as_float(u << 16); }
__device__ __forceinline__ float b2f16(unsigned short h) { return __uint_as_float(((unsigned)h) << 16); }

// ---------------- CSR build ----------------

__global__ __launch_bounds__(256) void deg_kernel(const int* __restrict__ dst, int* __restrict__ deg) {
    int e = blockIdx.x * blockDim.x + threadIdx.x;
    if (e < NE) atomicAdd(&deg[dst[e]], 1);
}

__global__ __launch_bounds__(1024) void scan1_kernel(const int* __restrict__ deg,
                                                     int* __restrict__ row_loc,
                                                     int* __restrict__ blocksum) {
    __shared__ int lds[1024];
    int t = threadIdx.x;
    int i = blockIdx.x * 1024 + t;
    int v = (i < NN) ? deg[i] : 0;
    lds[t] = v;
    __syncthreads();
    for (int off = 1; off < 1024; off <<= 1) {
        int u = (t >= off) ? lds[t - off] : 0;
        __syncthreads();
        lds[t] += u;
        __syncthreads();
    }
    if (i < NN) row_loc[i] = lds[t] - v;
    if (t == 1023) blocksum[blockIdx.x] = lds[1023];
}

__global__ __launch_bounds__(128) void scan2_kernel(int* __restrict__ blocksum, int nb) {
    __shared__ int lds[128];
    int t = threadIdx.x;
    int v = (t < nb) ? blocksum[t] : 0;
    lds[t] = v;
    __syncthreads();
    for (int off = 1; off < 128; off <<= 1) {
        int u = (t >= off) ? lds[t - off] : 0;
        __syncthreads();
        lds[t] += u;
        __syncthreads();
    }
    if (t < nb) blocksum[t] = lds[t] - v;
}

__global__ __launch_bounds__(1024) void scan3_kernel(const int* __restrict__ deg,
                                                     const int* __restrict__ row_loc,
                                                     const int* __restrict__ blockoff,
                                                     int* __restrict__ row_ptr,
                                                     float* __restrict__ inv_cnt) {
    int i = blockIdx.x * 1024 + threadIdx.x;
    if (i < NN) {
        row_ptr[i] = blockoff[blockIdx.x] + row_loc[i];
        int d = deg[i];
        inv_cnt[i] = 1.0f / (float)(d > 0 ? d : 1);
    }
    if (i == 0) row_ptr[NN] = NE;
}

// XCD-bucketed CSR fill (see round 5 notes: kills 16x partial-line writeback)
#define FILL_CHUNKS 128
__global__ __launch_bounds__(256) void fill_bucket_kernel(const int* __restrict__ src,
                                                          const int* __restrict__ dst,
                                                          const int* __restrict__ row_ptr,
                                                          int* __restrict__ cursor,
                                                          int* __restrict__ csr) {
    const int bucket = blockIdx.x & 7;
    const int chunk = blockIdx.x >> 3;
    const int nlo = bucket * (NN / 8);
    const int nhi = nlo + (NN / 8);
    const int stride = FILL_CHUNKS * 256;
    for (int e = chunk * 256 + threadIdx.x; e < NE; e += stride) {
        int d = dst[e];
        if (d >= nlo && d < nhi) {
            int pos = atomicAdd(&cursor[d], 1);
            csr[row_ptr[d] + pos] = src[e];
        }
    }
}

// ---------------- fp32 -> bf16 bulk convert ----------------

__global__ __launch_bounds__(256) void f2b4_kernel(const float* __restrict__ in,
                                                   unsigned short* __restrict__ out, int n4) {
    int i = blockIdx.x * 256 + threadIdx.x;
    if (i < n4) {
        float4 v = ((const float4*)in)[i];
        ushort4 o;
        o.x = f2b(v.x); o.y = f2b(v.y); o.z = f2b(v.z); o.w = f2b(v.w);
        ((ushort4*)out)[i] = o;
    }
}

// ---------------- pack W into MFMA B-fragment order (K=256, N=128) ----------------

__global__ __launch_bounds__(64) void pack_w_kernel(const float* __restrict__ Wl,
                                                    const float* __restrict__ Wr,
                                                    unsigned short* __restrict__ Bp) {
    int nt = blockIdx.x & 7;
    int kk = blockIdx.x >> 3;
    int lane = threadIdx.x;
    int n = nt * 16 + (lane & 15);
    int kb = kk * 32 + (lane >> 4) * 8;
    size_t base = ((size_t)(kk * 8 + nt) * 64 + lane) * 8;
#pragma unroll
    for (int j = 0; j < 8; ++j) {
        int k = kb + j;
        float v = (k < NF) ? Wl[(size_t)n * NF + k] : Wr[(size_t)n * NF + (k - NF)];
        Bp[base + j] = f2b(v);
    }
}

// pack for conv2: K=128, N=80 (cols 0..39 = W2l, 40..79 = W2r). 20 blocks.
__global__ __launch_bounds__(64) void pack_w80_kernel(const float* __restrict__ Wl,
                                                      const float* __restrict__ Wr,
                                                      unsigned short* __restrict__ Bp) {
    int nt = blockIdx.x % 5;
    int kk = blockIdx.x / 5;
    int lane = threadIdx.x;
    int n = nt * 16 + (lane & 15);
    int kb = kk * 32 + (lane >> 4) * 8;
    size_t base = ((size_t)(kk * 5 + nt) * 64 + lane) * 8;
#pragma unroll
    for (int j = 0; j < 8; ++j) {
        int k = kb + j;
        float v = (n < NC) ? Wl[(size_t)n * NF + k] : Wr[(size_t)(n - NC) * NF + k];
        Bp[base + j] = f2b(v);
    }
}

// ---------------- mean aggregation over CSR (bf16 table, fp32 accum) ----------------
// one wave per node; lane owns features (2*lane, 2*lane+1); 8-deep unroll for MLP.

__global__ __launch_bounds__(256) void agg_mean_bf16(const unsigned short* __restrict__ X,
                                                     const int* __restrict__ csr,
                                                     const int* __restrict__ row_ptr,
                                                     const float* __restrict__ inv_cnt,
                                                     unsigned short* __restrict__ out) {
    int wave = threadIdx.x >> 6;
    int lane = threadIdx.x & 63;
    int n = blockIdx.x * 4 + wave;
    if (n >= NN) return;
    int s = row_ptr[n], e = row_ptr[n + 1];
    float a0 = 0.f, a1 = 0.f;
    int i = s;
    for (; i + 8 <= e; i += 8) {
        int s0 = csr[i],     s1 = csr[i + 1], s2 = csr[i + 2], s3 = csr[i + 3];
        int s4 = csr[i + 4], s5 = csr[i + 5], s6 = csr[i + 6], s7 = csr[i + 7];
        unsigned u0 = *(const unsigned*)(X + (size_t)s0 * NF + lane * 2);
        unsigned u1 = *(const unsigned*)(X + (size_t)s1 * NF + lane * 2);
        unsigned u2 = *(const unsigned*)(X + (size_t)s2 * NF + lane * 2);
        unsigned u3 = *(const unsigned*)(X + (size_t)s3 * NF + lane * 2);
        unsigned u4 = *(const unsigned*)(X + (size_t)s4 * NF + lane * 2);
        unsigned u5 = *(const unsigned*)(X + (size_t)s5 * NF + lane * 2);
        unsigned u6 = *(const unsigned*)(X + (size_t)s6 * NF + lane * 2);
        unsigned u7 = *(const unsigned*)(X + (size_t)s7 * NF + lane * 2);
        a0 += b2f_lo(u0) + b2f_lo(u1) + b2f_lo(u2) + b2f_lo(u3)
            + b2f_lo(u4) + b2f_lo(u5) + b2f_lo(u6) + b2f_lo(u7);
        a1 += b2f_hi(u0) + b2f_hi(u1) + b2f_hi(u2) + b2f_hi(u3)
            + b2f_hi(u4) + b2f_hi(u5) + b2f_hi(u6) + b2f_hi(u7);
    }
    for (; i + 4 <= e; i += 4) {
        int s0 = csr[i], s1 = csr[i + 1], s2 = csr[i + 2], s3 = csr[i + 3];
        unsigned u0 = *(const unsigned*)(X + (size_t)s0 * NF + lane * 2);
        unsigned u1 = *(const unsigned*)(X + (size_t)s1 * NF + lane * 2);
        unsigned u2 = *(const unsigned*)(X + (size_t)s2 * NF + lane * 2);
        unsigned u3 = *(const unsigned*)(X + (size_t)s3 * NF + lane * 2);
        a0 += b2f_lo(u0) + b2f_lo(u1) + b2f_lo(u2) + b2f_lo(u3);
        a1 += b2f_hi(u0) + b2f_hi(u1) + b2f_hi(u2) + b2f_hi(u3);
    }
    for (; i < e; ++i) {
        unsigned u = *(const unsigned*)(X + (size_t)csr[i] * NF + lane * 2);
        a0 += b2f_lo(u);
        a1 += b2f_hi(u);
    }
    float ic = inv_cnt[n];
    unsigned short o0 = f2b(a0 * ic), o1 = f2b(a1 * ic);
    *(unsigned*)(out + (size_t)n * NF + lane * 2) = (unsigned)o0 | ((unsigned)o1 << 16);
}

// ---------------- MFMA linear (128-out, K=256) ----------------

template <bool RELU>
__global__ __launch_bounds__(256) void lin_mfma_kernel(const unsigned short* __restrict__ Ab,
                                                       const unsigned short* __restrict__ Xb,
                                                       const unsigned short* __restrict__ Bp,
                                                       const float* __restrict__ bias,
                                                       unsigned short* __restrict__ outb) {
    __shared__ unsigned short ldsB[32768];  // 64 KB
    int tid = threadIdx.x;
    {
        const float4* srcp = (const float4*)Bp;
        float4* dstp = (float4*)ldsB;
#pragma unroll
        for (int i = 0; i < 16; ++i) dstp[tid + i * 256] = srcp[tid + i * 256];
    }
    __syncthreads();

    int wave = tid >> 6;
    int lane = tid & 63;
    int quad = lane >> 4;
    int row = blockIdx.x * 64 + wave * 16 + (lane & 15);
    int rowc = row < NN ? row : (NN - 1);
    const unsigned short* arow = Ab + (size_t)rowc * NF;
    const unsigned short* xrow = Xb + (size_t)rowc * NF;

    float4v acc[8];
#pragma unroll
    for (int nt = 0; nt < 8; ++nt) acc[nt] = (float4v){0.f, 0.f, 0.f, 0.f};

#pragma unroll
    for (int kk = 0; kk < 8; ++kk) {
        int kb = (kk & 3) * 32 + quad * 8;
        const unsigned short* asrc = (kk < 4) ? arow : xrow;
        short8 afrag = *(const short8*)(asrc + kb);
#pragma unroll
        for (int nt = 0; nt < 8; ++nt) {
            short8 bfrag = *(const short8*)(ldsB + ((size_t)(kk * 8 + nt) * 64 + lane) * 8);
            acc[nt] = __builtin_amdgcn_mfma_f32_16x16x32_bf16(afrag, bfrag, acc[nt], 0, 0, 0);
        }
    }

    int orow = blockIdx.x * 64 + wave * 16 + quad * 4;
    int col = lane & 15;
#pragma unroll
    for (int nt = 0; nt < 8; ++nt) {
        int c = nt * 16 + col;
        float bv = bias[c];
#pragma unroll
        for (int r = 0; r < 4; ++r) {
            int rr = orow + r;
            if (rr < NN) {
                float v = acc[nt][r] + bv;
                if (RELU) v = fmaxf(v, 0.f);
                outb[(size_t)rr * NF + c] = f2b(v);
            }
        }
    }
}

// ---------------- MFMA linear + fused BN stats (convx) ----------------
// Writes bf16 h2 and accumulates column sum/sumsq (pre-BN values) into sums[256].

__global__ __launch_bounds__(256) void lin_mfma_stats_kernel(const unsigned short* __restrict__ Ab,
                                                             const unsigned short* __restrict__ Xb,
                                                             const unsigned short* __restrict__ Bp,
                                                             const float* __restrict__ bias,
                                                             unsigned short* __restrict__ outb,
                                                             float* __restrict__ sums) {
    __shared__ unsigned short ldsB[32768];  // 64 KB (reused as float scratch in epilogue)
    int tid = threadIdx.x;
    {
        const float4* srcp = (const float4*)Bp;
        float4* dstp = (float4*)ldsB;
#pragma unroll
        for (int i = 0; i < 16; ++i) dstp[tid + i * 256] = srcp[tid + i * 256];
    }
    __syncthreads();

    int wave = tid >> 6;
    int lane = tid & 63;
    int quad = lane >> 4;
    int row = blockIdx.x * 64 + wave * 16 + (lane & 15);
    int rowc = row < NN ? row : (NN - 1);
    const unsigned short* arow = Ab + (size_t)rowc * NF;
    const unsigned short* xrow = Xb + (size_t)rowc * NF;

    float4v acc[8];
#pragma unroll
    for (int nt = 0; nt < 8; ++nt) acc[nt] = (float4v){0.f, 0.f, 0.f, 0.f};

#pragma unroll
    for (int kk = 0; kk < 8; ++kk) {
        int kb = (kk & 3) * 32 + quad * 8;
        const unsigned short* asrc = (kk < 4) ? arow : xrow;
        short8 afrag = *(const short8*)(asrc + kb);
#pragma unroll
        for (int nt = 0; nt < 8; ++nt) {
            short8 bfrag = *(const short8*)(ldsB + ((size_t)(kk * 8 + nt) * 64 + lane) * 8);
            acc[nt] = __builtin_amdgcn_mfma_f32_16x16x32_bf16(afrag, bfrag, acc[nt], 0, 0, 0);
        }
    }

    int orow = blockIdx.x * 64 + wave * 16 + quad * 4;
    int col = lane & 15;
    float lsum[8], lsq[8];
#pragma unroll
    for (int nt = 0; nt < 8; ++nt) {
        int c = nt * 16 + col;
        float bv = bias[c];
        lsum[nt] = 0.f; lsq[nt] = 0.f;
#pragma unroll
        for (int r = 0; r < 4; ++r) {
            int rr = orow + r;
            if (rr < NN) {
                float v = acc[nt][r] + bv;
                outb[(size_t)rr * NF + c] = f2b(v);
                lsum[nt] += v;
                lsq[nt] += v * v;
            }
        }
    }

    // block-level fold in LDS (ldsB reused), then 256 global atomics
    __syncthreads();  // all ldsB reads done
    float* ls = (float*)ldsB;
    ls[tid] = 0.f;
    __syncthreads();
#pragma unroll
    for (int nt = 0; nt < 8; ++nt) {
        int c = nt * 16 + col;
        atomicAdd(&ls[c], lsum[nt]);
        atomicAdd(&ls[NF + c], lsq[nt]);
    }
    __syncthreads();
    atomicAdd(&sums[tid], ls[tid]);
}

// ---------------- MFMA linear for conv2 (80-out, K=128) ----------------

__global__ __launch_bounds__(256) void lin80_mfma_kernel(const unsigned short* __restrict__ Xb,
                                                         const unsigned short* __restrict__ Bp,
                                                         const float* __restrict__ b2,
                                                         unsigned short* __restrict__ t40,
                                                         float* __restrict__ z40) {
    __shared__ unsigned short ldsB[10240];  // 20 KB
    int tid = threadIdx.x;
    {
        const float4* srcp = (const float4*)Bp;
        float4* dstp = (float4*)ldsB;
#pragma unroll
        for (int i = 0; i < 5; ++i) dstp[tid + i * 256] = srcp[tid + i * 256];
    }
    __syncthreads();

    int wave = tid >> 6;
    int lane = tid & 63;
    int quad = lane >> 4;
    int row = blockIdx.x * 64 + wave * 16 + (lane & 15);
    int rowc = row < NN ? row : (NN - 1);
    const unsigned short* xrow = Xb + (size_t)rowc * NF;

    float4v acc[5];
#pragma unroll
    for (int nt = 0; nt < 5; ++nt) acc[nt] = (float4v){0.f, 0.f, 0.f, 0.f};

#pragma unroll
    for (int kk = 0; kk < 4; ++kk) {
        int kb = kk * 32 + quad * 8;
        short8 afrag = *(const short8*)(xrow + kb);
#pragma unroll
        for (int nt = 0; nt < 5; ++nt) {
            short8 bfrag = *(const short8*)(ldsB + ((size_t)(kk * 5 + nt) * 64 + lane) * 8);
            acc[nt] = __builtin_amdgcn_mfma_f32_16x16x32_bf16(afrag, bfrag, acc[nt], 0, 0, 0);
        }
    }

    int orow = blockIdx.x * 64 + wave * 16 + quad * 4;
    int col = lane & 15;
#pragma unroll
    for (int nt = 0; nt < 5; ++nt) {
        int c = nt * 16 + col;
#pragma unroll
        for (int r = 0; r < 4; ++r) {
            int rr = orow + r;
            if (rr < NN) {
                float v = acc[nt][r];
                if (c < NC) {
                    t40[(size_t)rr * NC + c] = f2b(v);
                } else {
                    z40[(size_t)rr * NC + (c - NC)] = v + b2[c - NC];
                }
            }
        }
    }
}

// lanes 0..19 each own feature pair (2*lane, 2*lane+1); T is bf16; 8-deep unroll
__global__ __launch_bounds__(256) void agg40_add_bf16(const unsigned short* __restrict__ T,
                                                      const float* __restrict__ Z,
                                                      const int* __restrict__ csr,
                                                      const int* __restrict__ row_ptr,
                                                      const float* __restrict__ inv_cnt,
                                                      float* __restrict__ out) {
    int wave = threadIdx.x >> 6;
    int lane = threadIdx.x & 63;
    int n = blockIdx.x * 4 + wave;
    if (n >= NN || lane >= 20) return;
    int s = row_ptr[n], e = row_ptr[n + 1];
    float a0 = 0.f, a1 = 0.f;
    int i = s;
    for (; i + 8 <= e; i += 8) {
        int s0 = csr[i],     s1 = csr[i + 1], s2 = csr[i + 2], s3 = csr[i + 3];
        int s4 = csr[i + 4], s5 = csr[i + 5], s6 = csr[i + 6], s7 = csr[i + 7];
        unsigned u0 = *(const unsigned*)(T + (size_t)s0 * NC + lane * 2);
        unsigned u1 = *(const unsigned*)(T + (size_t)s1 * NC + lane * 2);
        unsigned u2 = *(const unsigned*)(T + (size_t)s2 * NC + lane * 2);
        unsigned u3 = *(const unsigned*)(T + (size_t)s3 * NC + lane * 2);
        unsigned u4 = *(const unsigned*)(T + (size_t)s4 * NC + lane * 2);
        unsigned u5 = *(const unsigned*)(T + (size_t)s5 * NC + lane * 2);
        unsigned u6 = *(const unsigned*)(T + (size_t)s6 * NC + lane * 2);
        unsigned u7 = *(const unsigned*)(T + (size_t)s7 * NC + lane * 2);
        a0 += b2f_lo(u0) + b2f_lo(u1) + b2f_lo(u2) + b2f_lo(u3)
            + b2f_lo(u4) + b2f_lo(u5) + b2f_lo(u6) + b2f_lo(u7);
        a1 += b2f_hi(u0) + b2f_hi(u1) + b2f_hi(u2) + b2f_hi(u3)
            + b2f_hi(u4) + b2f_hi(u5) + b2f_hi(u6) + b2f_hi(u7);
    }
    for (; i + 4 <= e; i += 4) {
        int s0 = csr[i], s1 = csr[i + 1], s2 = csr[i + 2], s3 = csr[i + 3];
        unsigned u0 = *(const unsigned*)(T + (size_t)s0 * NC + lane * 2);
        unsigned u1 = *(const unsigned*)(T + (size_t)s1 * NC + lane * 2);
        unsigned u2 = *(const unsigned*)(T + (size_t)s2 * NC + lane * 2);
        unsigned u3 = *(const unsigned*)(T + (size_t)s3 * NC + lane * 2);
        a0 += b2f_lo(u0) + b2f_lo(u1) + b2f_lo(u2) + b2f_lo(u3);
        a1 += b2f_hi(u0) + b2f_hi(u1) + b2f_hi(u2) + b2f_hi(u3);
    }
    for (; i < e; ++i) {
        unsigned u = *(const unsigned*)(T + (size_t)csr[i] * NC + lane * 2);
        a0 += b2f_lo(u);
        a1 += b2f_hi(u);
    }
    float ic = inv_cnt[n];
    const float2 zv = *(const float2*)(Z + (size_t)n * NC + lane * 2);
    float2 o;
    o.x = a0 * ic + zv.x;
    o.y = a1 * ic + zv.y;
    *(float2*)(out + (size_t)n * NC + lane * 2) = o;
}

// ---------------- batch norm ----------------
#define BN_GRID 640  // 640*256 divisible by 10 (F=40)

template <int F>
__global__ __launch_bounds__(256) void bn_stats2_kernel(const float* __restrict__ X,
                                                        float* __restrict__ sums) {
    __shared__ float ls[2 * F];
    int tid = threadIdx.x;
    for (int i = tid; i < 2 * F; i += 256) ls[i] = 0.f;
    __syncthreads();

    const int total4 = NN * F / 4;
    const int stride = BN_GRID * 256;
    int i0 = blockIdx.x * 256 + tid;
    int c0 = (i0 * 4) % F;
    float s0 = 0.f, s1 = 0.f, s2 = 0.f, s3 = 0.f;
    float q0 = 0.f, q1 = 0.f, q2 = 0.f, q3 = 0.f;
    for (int i = i0; i < total4; i += stride) {
        float4 v = ((const float4*)X)[i];
        s0 += v.x; q0 += v.x * v.x;
        s1 += v.y; q1 += v.y * v.y;
        s2 += v.z; q2 += v.z * v.z;
        s3 += v.w; q3 += v.w * v.w;
    }
    atomicAdd(&ls[c0 + 0], s0); atomicAdd(&ls[F + c0 + 0], q0);
    atomicAdd(&ls[c0 + 1], s1); atomicAdd(&ls[F + c0 + 1], q1);
    atomicAdd(&ls[c0 + 2], s2); atomicAdd(&ls[F + c0 + 2], q2);
    atomicAdd(&ls[c0 + 3], s3); atomicAdd(&ls[F + c0 + 3], q3);
    __syncthreads();
    for (int i = tid; i < 2 * F; i += 256) atomicAdd(&sums[i], ls[i]);
}

// BN3 apply + relu in place on bf16 h2 (2 elems/thread via 4B word)
__global__ __launch_bounds__(256) void bn3_apply_b16_kernel(unsigned* __restrict__ H,
                                                            const float* __restrict__ sums,
                                                            const float* __restrict__ g,
                                                            const float* __restrict__ be,
                                                            float invN) {
    int idx = blockIdx.x * 256 + threadIdx.x;  // word index, 2 feats per word
    if (idx >= NN * NF / 2) return;
    int t0 = (idx * 2) & (NF - 1);
    float mu0 = sums[t0] * invN, mu1 = sums[t0 + 1] * invN;
    float var0 = sums[NF + t0] * invN - mu0 * mu0;
    float var1 = sums[NF + t0 + 1] * invN - mu1 * mu1;
    float sc0 = rsqrtf(var0 + BN_EPS) * g[t0];
    float sc1 = rsqrtf(var1 + BN_EPS) * g[t0 + 1];
    unsigned u = H[idx];
    float v0 = fmaxf((b2f_lo(u) - mu0) * sc0 + be[t0], 0.f);
    float v1 = fmaxf((b2f_hi(u) - mu1) * sc1 + be[t0 + 1], 0.f);
    H[idx] = (unsigned)f2b(v0) | ((unsigned)f2b(v1) << 16);
}

template <bool RELU>
__global__ __launch_bounds__(256) void bn_apply_kernel(float* __restrict__ X,
                                                       const float* __restrict__ sums,
                                                       const float* __restrict__ g,
                                                       const float* __restrict__ be,
                                                       int F, float invN) {
    size_t idx = (size_t)blockIdx.x * blockDim.x + threadIdx.x;
    size_t total = (size_t)NN * F;
    if (idx >= total) return;
    int t = (int)(idx % F);
    float mu = sums[t] * invN;
    float var = sums[F + t] * invN - mu * mu;
    float scale = rsqrtf(var + BN_EPS) * g[t];
    float v = (X[idx] - mu) * scale + be[t];
    if (RELU) v = fmaxf(v, 0.f);
    X[idx] = v;
}

// ---------------- launch ----------------

extern "C" void kernel_launch(void* const* d_in, const int* in_sizes, int n_in,
                              void* d_out, int out_size, void* d_ws, size_t ws_size,
                              hipStream_t stream) {
    const float* x   = (const float*)d_in[0];
    const int*   ei  = (const int*)d_in[1];
    const int*   srcv = ei;
    const int*   dstv = ei + NE;
    const float* W1l = (const float*)d_in[2];
    const float* b1  = (const float*)d_in[3];
    const float* W1r = (const float*)d_in[4];
    const float* Wxl = (const float*)d_in[5];
    const float* bx  = (const float*)d_in[6];
    const float* Wxr = (const float*)d_in[7];
    const float* W2l = (const float*)d_in[8];
    const float* b2  = (const float*)d_in[9];
    const float* W2r = (const float*)d_in[10];
    const float* g3  = (const float*)d_in[11];
    const float* be3 = (const float*)d_in[12];
    const float* g2  = (const float*)d_in[13];
    const float* be2 = (const float*)d_in[14];
    float* out = (float*)d_out;

    // workspace carve (16B aligned)
    char* w = (char*)d_ws;
    unsigned short* xb   = (unsigned short*)w; w += (size_t)NN * NF * 2;   // 25.6 MB
    unsigned short* h1b  = (unsigned short*)w; w += (size_t)NN * NF * 2;   // 25.6 MB
    unsigned short* aggb = (unsigned short*)w; w += (size_t)NN * NF * 2;   // 25.6 MB
    unsigned short* h2b  = (unsigned short*)w; w += (size_t)NN * NF * 2;   // 25.6 MB
    int* csr     = (int*)w; w += (size_t)NE * 4;                           // 6.4 MB
    int* row_ptr = (int*)w; w += (size_t)(NN + 4) * 4;
    int* deg     = (int*)w; w += (size_t)NN * 4;
    int* cursor  = (int*)w; w += (size_t)NN * 4;
    int* row_loc = (int*)w; w += (size_t)NN * 4;
    int* blocksum = (int*)w; w += 128 * 4;
    float* inv_cnt = (float*)w; w += (size_t)NN * 4;
    float* bnbuf3  = (float*)w; w += 2 * NF * 4;
    float* bnbuf2  = (float*)w; w += 2 * NC * 4;
    unsigned short* Bp1 = (unsigned short*)w; w += (size_t)256 * NF * 2;   // 64 KB
    unsigned short* Bpx = (unsigned short*)w; w += (size_t)256 * NF * 2;   // 64 KB
    unsigned short* Bp2 = (unsigned short*)w; w += (size_t)128 * 80 * 2;   // 20 KB
    // overlays
    unsigned short* t40 = xb;        // dead after conv1
    float* z40 = (float*)h1b;        // dead after convx

    const int nscan = (NN + 1023) / 1024;  // 98

    // ---- CSR build + zeroing ----
    hipMemsetAsync(deg, 0, (size_t)NN * 4, stream);
    hipMemsetAsync(cursor, 0, (size_t)NN * 4, stream);
    hipMemsetAsync(bnbuf3, 0, 2 * NF * 4, stream);
    hipMemsetAsync(bnbuf2, 0, 2 * NC * 4, stream);
    deg_kernel<<<(NE + 255) / 256, 256, 0, stream>>>(dstv, deg);
    scan1_kernel<<<nscan, 1024, 0, stream>>>(deg, row_loc, blocksum);
    scan2_kernel<<<1, 128, 0, stream>>>(blocksum, nscan);
    scan3_kernel<<<nscan, 1024, 0, stream>>>(deg, row_loc, blocksum, row_ptr, inv_cnt);
    fill_bucket_kernel<<<FILL_CHUNKS * 8, 256, 0, stream>>>(srcv, dstv, row_ptr, cursor, csr);

    // ---- prep: x -> bf16; pack weights ----
    f2b4_kernel<<<(NN * NF / 4 + 255) / 256, 256, 0, stream>>>(x, xb, NN * NF / 4);
    pack_w_kernel<<<64, 64, 0, stream>>>(W1l, W1r, Bp1);
    pack_w_kernel<<<64, 64, 0, stream>>>(Wxl, Wxr, Bpx);
    pack_w80_kernel<<<20, 64, 0, stream>>>(W2l, W2r, Bp2);

    const int nblk_lin = (NN + 63) / 64;  // 1563

    // ---- conv1: h1 = relu([mean(x)|x] @ Bp1 + b1) -> h1b (bf16) ----
    agg_mean_bf16<<<(NN + 3) / 4, 256, 0, stream>>>(xb, csr, row_ptr, inv_cnt, aggb);
    lin_mfma_kernel<true><<<nblk_lin, 256, 0, stream>>>(aggb, xb, Bp1, b1, h1b);

    // ---- convx: h2 = [mean(h1)|h1] @ Bpx + bx -> h2b (bf16) + fused BN3 stats ----
    agg_mean_bf16<<<(NN + 3) / 4, 256, 0, stream>>>(h1b, csr, row_ptr, inv_cnt, aggb);
    lin_mfma_stats_kernel<<<nblk_lin, 256, 0, stream>>>(aggb, h1b, Bpx, bx, h2b, bnbuf3);

    // ---- batch_norm3 + relu, in place on bf16 h2 ----
    bn3_apply_b16_kernel<<<(NN * NF / 2 + 255) / 256, 256, 0, stream>>>((unsigned*)h2b, bnbuf3, g3, be3, 1.0f / NN);

    // ---- conv2 (transform-first, MFMA) ----
    lin80_mfma_kernel<<<nblk_lin, 256, 0, stream>>>(h2b, Bp2, b2, t40, z40);
    agg40_add_bf16<<<(NN + 3) / 4, 256, 0, stream>>>(t40, z40, csr, row_ptr, inv_cnt, out);

    // ---- batch_norm2 (in place on out) ----
    bn_stats2_kernel<NC><<<BN_GRID, 256, 0, stream>>>(out, bnbuf2);
    bn_apply_kernel<false><<<(NN * NC + 255) / 256, 256, 0, stream>>>(out, bnbuf2, g2, be2, NC, 1.0f / NN);
}

// Round 8
// 631.781 us; speedup vs baseline: 3.0469x; 1.0377x over previous
//
#include <hip/hip_runtime.h>
#include <hip/hip_bf16.h>

#define NN 100000
#define NE 1600000
#define NF 128
#define NC 40
#define BN_EPS 1e-5f

typedef __attribute__((ext_vector_type(8))) short short8;
typedef __attribute__((ext_vector_type(4))) float float4v;

__device__ __forceinline__ unsigned short f2b(float f) {
    __hip_bfloat16 h = __float2bfloat16(f);
    return *reinterpret_cast<unsigned short*>(&h);
}
__device__ __forceinline__ float b2f_hi(unsigned u) { return __uint_as_float(u & 0xffff0000u); }
__device__ __forceinline__ float b2f_lo(unsigned u) { return __uint_as_float(u << 16); }

// ---------------- CSR build ----------------

__global__ __launch_bounds__(256) void deg_kernel(const int* __restrict__ dst, int* __restrict__ deg) {
    int e = blockIdx.x * blockDim.x + threadIdx.x;
    if (e < NE) atomicAdd(&deg[dst[e]], 1);
}

__global__ __launch_bounds__(1024) void scan1_kernel(const int* __restrict__ deg,
                                                     int* __restrict__ row_loc,
                                                     int* __restrict__ blocksum) {
    __shared__ int lds[1024];
    int t = threadIdx.x;
    int i = blockIdx.x * 1024 + t;
    int v = (i < NN) ? deg[i] : 0;
    lds[t] = v;
    __syncthreads();
    for (int off = 1; off < 1024; off <<= 1) {
        int u = (t >= off) ? lds[t - off] : 0;
        __syncthreads();
        lds[t] += u;
        __syncthreads();
    }
    if (i < NN) row_loc[i] = lds[t] - v;
    if (t == 1023) blocksum[blockIdx.x] = lds[1023];
}

__global__ __launch_bounds__(128) void scan2_kernel(int* __restrict__ blocksum, int nb) {
    __shared__ int lds[128];
    int t = threadIdx.x;
    int v = (t < nb) ? blocksum[t] : 0;
    lds[t] = v;
    __syncthreads();
    for (int off = 1; off < 128; off <<= 1) {
        int u = (t >= off) ? lds[t - off] : 0;
        __syncthreads();
        lds[t] += u;
        __syncthreads();
    }
    if (t < nb) blocksum[t] = lds[t] - v;
}

__global__ __launch_bounds__(1024) void scan3_kernel(const int* __restrict__ deg,
                                                     const int* __restrict__ row_loc,
                                                     const int* __restrict__ blockoff,
                                                     int* __restrict__ row_ptr,
                                                     float* __restrict__ inv_cnt) {
    int i = blockIdx.x * 1024 + threadIdx.x;
    if (i < NN) {
        row_ptr[i] = blockoff[blockIdx.x] + row_loc[i];
        int d = deg[i];
        inv_cnt[i] = 1.0f / (float)(d > 0 ? d : 1);
    }
    if (i == 0) row_ptr[NN] = NE;
}

// XCD-bucketed CSR fill (round 5: kills 16x partial-line writeback)
#define FILL_CHUNKS 128
__global__ __launch_bounds__(256) void fill_bucket_kernel(const int* __restrict__ src,
                                                          const int* __restrict__ dst,
                                                          const int* __restrict__ row_ptr,
                                                          int* __restrict__ cursor,
                                                          int* __restrict__ csr) {
    const int bucket = blockIdx.x & 7;
    const int chunk = blockIdx.x >> 3;
    const int nlo = bucket * (NN / 8);
    const int nhi = nlo + (NN / 8);
    const int stride = FILL_CHUNKS * 256;
    for (int e = chunk * 256 + threadIdx.x; e < NE; e += stride) {
        int d = dst[e];
        if (d >= nlo && d < nhi) {
            int pos = atomicAdd(&cursor[d], 1);
            csr[row_ptr[d] + pos] = src[e];
        }
    }
}

// ---------------- fp32 -> bf16 bulk convert ----------------

__global__ __launch_bounds__(256) void f2b4_kernel(const float* __restrict__ in,
                                                   unsigned short* __restrict__ out, int n4) {
    int i = blockIdx.x * 256 + threadIdx.x;
    if (i < n4) {
        float4 v = ((const float4*)in)[i];
        ushort4 o;
        o.x = f2b(v.x); o.y = f2b(v.y); o.z = f2b(v.z); o.w = f2b(v.w);
        ((ushort4*)out)[i] = o;
    }
}

// ---------------- pack W into MFMA B-fragment order (K=256, N=128) ----------------

__global__ __launch_bounds__(64) void pack_w_kernel(const float* __restrict__ Wl,
                                                    const float* __restrict__ Wr,
                                                    unsigned short* __restrict__ Bp) {
    int nt = blockIdx.x & 7;
    int kk = blockIdx.x >> 3;
    int lane = threadIdx.x;
    int n = nt * 16 + (lane & 15);
    int kb = kk * 32 + (lane >> 4) * 8;
    size_t base = ((size_t)(kk * 8 + nt) * 64 + lane) * 8;
#pragma unroll
    for (int j = 0; j < 8; ++j) {
        int k = kb + j;
        float v = (k < NF) ? Wl[(size_t)n * NF + k] : Wr[(size_t)n * NF + (k - NF)];
        Bp[base + j] = f2b(v);
    }
}

// pack for conv2: K=128, N=80 (cols 0..39 = W2l, 40..79 = W2r). 20 blocks.
__global__ __launch_bounds__(64) void pack_w80_kernel(const float* __restrict__ Wl,
                                                      const float* __restrict__ Wr,
                                                      unsigned short* __restrict__ Bp) {
    int nt = blockIdx.x % 5;
    int kk = blockIdx.x / 5;
    int lane = threadIdx.x;
    int n = nt * 16 + (lane & 15);
    int kb = kk * 32 + (lane >> 4) * 8;
    size_t base = ((size_t)(kk * 5 + nt) * 64 + lane) * 8;
#pragma unroll
    for (int j = 0; j < 8; ++j) {
        int k = kb + j;
        float v = (n < NC) ? Wl[(size_t)n * NF + k] : Wr[(size_t)(n - NC) * NF + k];
        Bp[base + j] = f2b(v);
    }
}

// ---------------- mean aggregation over CSR (bf16 table, fp32 accum) ----------------
// one wave per node; lane owns features (2*lane, 2*lane+1); 8-deep unroll for MLP.

__global__ __launch_bounds__(256) void agg_mean_bf16(const unsigned short* __restrict__ X,
                                                     const int* __restrict__ csr,
                                                     const int* __restrict__ row_ptr,
                                                     const float* __restrict__ inv_cnt,
                                                     unsigned short* __restrict__ out) {
    int wave = threadIdx.x >> 6;
    int lane = threadIdx.x & 63;
    int n = blockIdx.x * 4 + wave;
    if (n >= NN) return;
    int s = row_ptr[n], e = row_ptr[n + 1];
    float a0 = 0.f, a1 = 0.f;
    int i = s;
    for (; i + 8 <= e; i += 8) {
        int s0 = csr[i],     s1 = csr[i + 1], s2 = csr[i + 2], s3 = csr[i + 3];
        int s4 = csr[i + 4], s5 = csr[i + 5], s6 = csr[i + 6], s7 = csr[i + 7];
        unsigned u0 = *(const unsigned*)(X + (size_t)s0 * NF + lane * 2);
        unsigned u1 = *(const unsigned*)(X + (size_t)s1 * NF + lane * 2);
        unsigned u2 = *(const unsigned*)(X + (size_t)s2 * NF + lane * 2);
        unsigned u3 = *(const unsigned*)(X + (size_t)s3 * NF + lane * 2);
        unsigned u4 = *(const unsigned*)(X + (size_t)s4 * NF + lane * 2);
        unsigned u5 = *(const unsigned*)(X + (size_t)s5 * NF + lane * 2);
        unsigned u6 = *(const unsigned*)(X + (size_t)s6 * NF + lane * 2);
        unsigned u7 = *(const unsigned*)(X + (size_t)s7 * NF + lane * 2);
        a0 += b2f_lo(u0) + b2f_lo(u1) + b2f_lo(u2) + b2f_lo(u3)
            + b2f_lo(u4) + b2f_lo(u5) + b2f_lo(u6) + b2f_lo(u7);
        a1 += b2f_hi(u0) + b2f_hi(u1) + b2f_hi(u2) + b2f_hi(u3)
            + b2f_hi(u4) + b2f_hi(u5) + b2f_hi(u6) + b2f_hi(u7);
    }
    for (; i + 4 <= e; i += 4) {
        int s0 = csr[i], s1 = csr[i + 1], s2 = csr[i + 2], s3 = csr[i + 3];
        unsigned u0 = *(const unsigned*)(X + (size_t)s0 * NF + lane * 2);
        unsigned u1 = *(const unsigned*)(X + (size_t)s1 * NF + lane * 2);
        unsigned u2 = *(const unsigned*)(X + (size_t)s2 * NF + lane * 2);
        unsigned u3 = *(const unsigned*)(X + (size_t)s3 * NF + lane * 2);
        a0 += b2f_lo(u0) + b2f_lo(u1) + b2f_lo(u2) + b2f_lo(u3);
        a1 += b2f_hi(u0) + b2f_hi(u1) + b2f_hi(u2) + b2f_hi(u3);
    }
    for (; i < e; ++i) {
        unsigned u = *(const unsigned*)(X + (size_t)csr[i] * NF + lane * 2);
        a0 += b2f_lo(u);
        a1 += b2f_hi(u);
    }
    float ic = inv_cnt[n];
    unsigned short o0 = f2b(a0 * ic), o1 = f2b(a1 * ic);
    *(unsigned*)(out + (size_t)n * NF + lane * 2) = (unsigned)o0 | ((unsigned)o1 << 16);
}

// ---------------- MFMA linear (128-out, K=256), NO LDS ----------------
// B-frags read directly from global (64 KB, L2-hot, coalesced 16B/lane).
// No staging, no barriers; occupancy 5 blocks/CU (vs 2 with 64KB LDS).

template <bool RELU>
__global__ __launch_bounds__(256, 5) void lin_mfma_kernel(const unsigned short* __restrict__ Ab,
                                                          const unsigned short* __restrict__ Xb,
                                                          const unsigned short* __restrict__ Bp,
                                                          const float* __restrict__ bias,
                                                          unsigned short* __restrict__ outb) {
    int tid = threadIdx.x;
    int wave = tid >> 6;
    int lane = tid & 63;
    int quad = lane >> 4;
    int row = blockIdx.x * 64 + wave * 16 + (lane & 15);
    int rowc = row < NN ? row : (NN - 1);
    const unsigned short* arow = Ab + (size_t)rowc * NF;
    const unsigned short* xrow = Xb + (size_t)rowc * NF;
    const short8* Bv = (const short8*)Bp;  // index (kk*8+nt)*64 + lane

    float4v acc[8];
#pragma unroll
    for (int nt = 0; nt < 8; ++nt) acc[nt] = (float4v){0.f, 0.f, 0.f, 0.f};

#pragma unroll
    for (int kk = 0; kk < 8; ++kk) {
        int kb = (kk & 3) * 32 + quad * 8;
        const unsigned short* asrc = (kk < 4) ? arow : xrow;
        short8 afrag = *(const short8*)(asrc + kb);
#pragma unroll
        for (int nt = 0; nt < 8; ++nt) {
            short8 bfrag = Bv[(kk * 8 + nt) * 64 + lane];
            acc[nt] = __builtin_amdgcn_mfma_f32_16x16x32_bf16(afrag, bfrag, acc[nt], 0, 0, 0);
        }
    }

    int orow = blockIdx.x * 64 + wave * 16 + quad * 4;
    int col = lane & 15;
#pragma unroll
    for (int nt = 0; nt < 8; ++nt) {
        int c = nt * 16 + col;
        float bv = bias[c];
#pragma unroll
        for (int r = 0; r < 4; ++r) {
            int rr = orow + r;
            if (rr < NN) {
                float v = acc[nt][r] + bv;
                if (RELU) v = fmaxf(v, 0.f);
                outb[(size_t)rr * NF + c] = f2b(v);
            }
        }
    }
}

// ---------------- MFMA linear for conv2 (80-out, K=128), NO LDS ----------------

__global__ __launch_bounds__(256, 5) void lin80_mfma_kernel(const unsigned short* __restrict__ Xb,
                                                            const unsigned short* __restrict__ Bp,
                                                            const float* __restrict__ b2,
                                                            unsigned short* __restrict__ t40,
                                                            float* __restrict__ z40) {
    int tid = threadIdx.x;
    int wave = tid >> 6;
    int lane = tid & 63;
    int quad = lane >> 4;
    int row = blockIdx.x * 64 + wave * 16 + (lane & 15);
    int rowc = row < NN ? row : (NN - 1);
    const unsigned short* xrow = Xb + (size_t)rowc * NF;
    const short8* Bv = (const short8*)Bp;  // index (kk*5+nt)*64 + lane

    float4v acc[5];
#pragma unroll
    for (int nt = 0; nt < 5; ++nt) acc[nt] = (float4v){0.f, 0.f, 0.f, 0.f};

#pragma unroll
    for (int kk = 0; kk < 4; ++kk) {
        int kb = kk * 32 + quad * 8;
        short8 afrag = *(const short8*)(xrow + kb);
#pragma unroll
        for (int nt = 0; nt < 5; ++nt) {
            short8 bfrag = Bv[(kk * 5 + nt) * 64 + lane];
            acc[nt] = __builtin_amdgcn_mfma_f32_16x16x32_bf16(afrag, bfrag, acc[nt], 0, 0, 0);
        }
    }

    int orow = blockIdx.x * 64 + wave * 16 + quad * 4;
    int col = lane & 15;
#pragma unroll
    for (int nt = 0; nt < 5; ++nt) {
        int c = nt * 16 + col;
#pragma unroll
        for (int r = 0; r < 4; ++r) {
            int rr = orow + r;
            if (rr < NN) {
                float v = acc[nt][r];
                if (c < NC) {
                    t40[(size_t)rr * NC + c] = f2b(v);
                } else {
                    z40[(size_t)rr * NC + (c - NC)] = v + b2[c - NC];
                }
            }
        }
    }
}

// lanes 0..19 each own feature pair (2*lane, 2*lane+1); T is bf16; 8-deep unroll
__global__ __launch_bounds__(256) void agg40_add_bf16(const unsigned short* __restrict__ T,
                                                      const float* __restrict__ Z,
                                                      const int* __restrict__ csr,
                                                      const int* __restrict__ row_ptr,
                                                      const float* __restrict__ inv_cnt,
                                                      float* __restrict__ out) {
    int wave = threadIdx.x >> 6;
    int lane = threadIdx.x & 63;
    int n = blockIdx.x * 4 + wave;
    if (n >= NN || lane >= 20) return;
    int s = row_ptr[n], e = row_ptr[n + 1];
    float a0 = 0.f, a1 = 0.f;
    int i = s;
    for (; i + 8 <= e; i += 8) {
        int s0 = csr[i],     s1 = csr[i + 1], s2 = csr[i + 2], s3 = csr[i + 3];
        int s4 = csr[i + 4], s5 = csr[i + 5], s6 = csr[i + 6], s7 = csr[i + 7];
        unsigned u0 = *(const unsigned*)(T + (size_t)s0 * NC + lane * 2);
        unsigned u1 = *(const unsigned*)(T + (size_t)s1 * NC + lane * 2);
        unsigned u2 = *(const unsigned*)(T + (size_t)s2 * NC + lane * 2);
        unsigned u3 = *(const unsigned*)(T + (size_t)s3 * NC + lane * 2);
        unsigned u4 = *(const unsigned*)(T + (size_t)s4 * NC + lane * 2);
        unsigned u5 = *(const unsigned*)(T + (size_t)s5 * NC + lane * 2);
        unsigned u6 = *(const unsigned*)(T + (size_t)s6 * NC + lane * 2);
        unsigned u7 = *(const unsigned*)(T + (size_t)s7 * NC + lane * 2);
        a0 += b2f_lo(u0) + b2f_lo(u1) + b2f_lo(u2) + b2f_lo(u3)
            + b2f_lo(u4) + b2f_lo(u5) + b2f_lo(u6) + b2f_lo(u7);
        a1 += b2f_hi(u0) + b2f_hi(u1) + b2f_hi(u2) + b2f_hi(u3)
            + b2f_hi(u4) + b2f_hi(u5) + b2f_hi(u6) + b2f_hi(u7);
    }
    for (; i + 4 <= e; i += 4) {
        int s0 = csr[i], s1 = csr[i + 1], s2 = csr[i + 2], s3 = csr[i + 3];
        unsigned u0 = *(const unsigned*)(T + (size_t)s0 * NC + lane * 2);
        unsigned u1 = *(const unsigned*)(T + (size_t)s1 * NC + lane * 2);
        unsigned u2 = *(const unsigned*)(T + (size_t)s2 * NC + lane * 2);
        unsigned u3 = *(const unsigned*)(T + (size_t)s3 * NC + lane * 2);
        a0 += b2f_lo(u0) + b2f_lo(u1) + b2f_lo(u2) + b2f_lo(u3);
        a1 += b2f_hi(u0) + b2f_hi(u1) + b2f_hi(u2) + b2f_hi(u3);
    }
    for (; i < e; ++i) {
        unsigned u = *(const unsigned*)(T + (size_t)csr[i] * NC + lane * 2);
        a0 += b2f_lo(u);
        a1 += b2f_hi(u);
    }
    float ic = inv_cnt[n];
    const float2 zv = *(const float2*)(Z + (size_t)n * NC + lane * 2);
    float2 o;
    o.x = a0 * ic + zv.x;
    o.y = a1 * ic + zv.y;
    *(float2*)(out + (size_t)n * NC + lane * 2) = o;
}

// ---------------- batch norm ----------------
#define BN_GRID 640  // 640*256 divisible by 10 (F=40)

// fp32 input (used for out[NN,40])
template <int F>
__global__ __launch_bounds__(256) void bn_stats2_kernel(const float* __restrict__ X,
                                                        float* __restrict__ sums) {
    __shared__ float ls[2 * F];
    int tid = threadIdx.x;
    for (int i = tid; i < 2 * F; i += 256) ls[i] = 0.f;
    __syncthreads();

    const int total4 = NN * F / 4;
    const int stride = BN_GRID * 256;
    int i0 = blockIdx.x * 256 + tid;
    int c0 = (i0 * 4) % F;
    float s0 = 0.f, s1 = 0.f, s2 = 0.f, s3 = 0.f;
    float q0 = 0.f, q1 = 0.f, q2 = 0.f, q3 = 0.f;
    for (int i = i0; i < total4; i += stride) {
        float4 v = ((const float4*)X)[i];
        s0 += v.x; q0 += v.x * v.x;
        s1 += v.y; q1 += v.y * v.y;
        s2 += v.z; q2 += v.z * v.z;
        s3 += v.w; q3 += v.w * v.w;
    }
    atomicAdd(&ls[c0 + 0], s0); atomicAdd(&ls[F + c0 + 0], q0);
    atomicAdd(&ls[c0 + 1], s1); atomicAdd(&ls[F + c0 + 1], q1);
    atomicAdd(&ls[c0 + 2], s2); atomicAdd(&ls[F + c0 + 2], q2);
    atomicAdd(&ls[c0 + 3], s3); atomicAdd(&ls[F + c0 + 3], q3);
    __syncthreads();
    for (int i = tid; i < 2 * F; i += 256) atomicAdd(&sums[i], ls[i]);
}

// bf16 input (h2b), 8 feats/thread via 16B loads; fixed column group per thread
__global__ __launch_bounds__(256) void bn_stats_b16_kernel(const unsigned short* __restrict__ H,
                                                           float* __restrict__ sums) {
    __shared__ float ls[2 * NF];
    int tid = threadIdx.x;
    for (int i = tid; i < 2 * NF; i += 256) ls[i] = 0.f;
    __syncthreads();

    const int total8 = NN * NF / 8;
    const int stride = BN_GRID * 256;  // *8 feats ≡ 0 mod 128 -> fixed c0
    int i0 = blockIdx.x * 256 + tid;
    int c0 = (i0 * 8) & (NF - 1);
    float s[8], q[8];
#pragma unroll
    for (int j = 0; j < 8; ++j) { s[j] = 0.f; q[j] = 0.f; }
    for (int i = i0; i < total8; i += stride) {
        uint4 u = ((const uint4*)H)[i];
        float v;
        v = b2f_lo(u.x); s[0] += v; q[0] += v * v;
        v = b2f_hi(u.x); s[1] += v; q[1] += v * v;
        v = b2f_lo(u.y); s[2] += v; q[2] += v * v;
        v = b2f_hi(u.y); s[3] += v; q[3] += v * v;
        v = b2f_lo(u.z); s[4] += v; q[4] += v * v;
        v = b2f_hi(u.z); s[5] += v; q[5] += v * v;
        v = b2f_lo(u.w); s[6] += v; q[6] += v * v;
        v = b2f_hi(u.w); s[7] += v; q[7] += v * v;
    }
#pragma unroll
    for (int j = 0; j < 8; ++j) {
        atomicAdd(&ls[c0 + j], s[j]);
        atomicAdd(&ls[NF + c0 + j], q[j]);
    }
    __syncthreads();
    for (int i = tid; i < 2 * NF; i += 256) atomicAdd(&sums[i], ls[i]);
}

// BN3 apply + relu in place on bf16 h2 (2 elems/thread via 4B word)
__global__ __launch_bounds__(256) void bn3_apply_b16_kernel(unsigned* __restrict__ H,
                                                            const float* __restrict__ sums,
                                                            const float* __restrict__ g,
                                                            const float* __restrict__ be,
                                                            float invN) {
    int idx = blockIdx.x * 256 + threadIdx.x;
    if (idx >= NN * NF / 2) return;
    int t0 = (idx * 2) & (NF - 1);
    float mu0 = sums[t0] * invN, mu1 = sums[t0 + 1] * invN;
    float var0 = sums[NF + t0] * invN - mu0 * mu0;
    float var1 = sums[NF + t0 + 1] * invN - mu1 * mu1;
    float sc0 = rsqrtf(var0 + BN_EPS) * g[t0];
    float sc1 = rsqrtf(var1 + BN_EPS) * g[t0 + 1];
    unsigned u = H[idx];
    float v0 = fmaxf((b2f_lo(u) - mu0) * sc0 + be[t0], 0.f);
    float v1 = fmaxf((b2f_hi(u) - mu1) * sc1 + be[t0 + 1], 0.f);
    H[idx] = (unsigned)f2b(v0) | ((unsigned)f2b(v1) << 16);
}

template <bool RELU>
__global__ __launch_bounds__(256) void bn_apply_kernel(float* __restrict__ X,
                                                       const float* __restrict__ sums,
                                                       const float* __restrict__ g,
                                                       const float* __restrict__ be,
                                                       int F, float invN) {
    size_t idx = (size_t)blockIdx.x * blockDim.x + threadIdx.x;
    size_t total = (size_t)NN * F;
    if (idx >= total) return;
    int t = (int)(idx % F);
    float mu = sums[t] * invN;
    float var = sums[F + t] * invN - mu * mu;
    float scale = rsqrtf(var + BN_EPS) * g[t];
    float v = (X[idx] - mu) * scale + be[t];
    if (RELU) v = fmaxf(v, 0.f);
    X[idx] = v;
}

// ---------------- launch ----------------

extern "C" void kernel_launch(void* const* d_in, const int* in_sizes, int n_in,
                              void* d_out, int out_size, void* d_ws, size_t ws_size,
                              hipStream_t stream) {
    const float* x   = (const float*)d_in[0];
    const int*   ei  = (const int*)d_in[1];
    const int*   srcv = ei;
    const int*   dstv = ei + NE;
    const float* W1l = (const float*)d_in[2];
    const float* b1  = (const float*)d_in[3];
    const float* W1r = (const float*)d_in[4];
    const float* Wxl = (const float*)d_in[5];
    const float* bx  = (const float*)d_in[6];
    const float* Wxr = (const float*)d_in[7];
    const float* W2l = (const float*)d_in[8];
    const float* b2  = (const float*)d_in[9];
    const float* W2r = (const float*)d_in[10];
    const float* g3  = (const float*)d_in[11];
    const float* be3 = (const float*)d_in[12];
    const float* g2  = (const float*)d_in[13];
    const float* be2 = (const float*)d_in[14];
    float* out = (float*)d_out;

    // workspace carve (16B aligned)
    char* w = (char*)d_ws;
    unsigned short* xb   = (unsigned short*)w; w += (size_t)NN * NF * 2;   // 25.6 MB
    unsigned short* h1b  = (unsigned short*)w; w += (size_t)NN * NF * 2;   // 25.6 MB
    unsigned short* aggb = (unsigned short*)w; w += (size_t)NN * NF * 2;   // 25.6 MB
    unsigned short* h2b  = (unsigned short*)w; w += (size_t)NN * NF * 2;   // 25.6 MB
    int* csr     = (int*)w; w += (size_t)NE * 4;                           // 6.4 MB
    int* row_ptr = (int*)w; w += (size_t)(NN + 4) * 4;
    int* deg     = (int*)w; w += (size_t)NN * 4;
    int* cursor  = (int*)w; w += (size_t)NN * 4;
    int* row_loc = (int*)w; w += (size_t)NN * 4;
    int* blocksum = (int*)w; w += 128 * 4;
    float* inv_cnt = (float*)w; w += (size_t)NN * 4;
    float* bnbuf3  = (float*)w; w += 2 * NF * 4;
    float* bnbuf2  = (float*)w; w += 2 * NC * 4;
    unsigned short* Bp1 = (unsigned short*)w; w += (size_t)256 * NF * 2;   // 64 KB
    unsigned short* Bpx = (unsigned short*)w; w += (size_t)256 * NF * 2;   // 64 KB
    unsigned short* Bp2 = (unsigned short*)w; w += (size_t)128 * 80 * 2;   // 20 KB
    // overlays
    unsigned short* t40 = xb;        // dead after conv1
    float* z40 = (float*)h1b;        // dead after convx

    const int nscan = (NN + 1023) / 1024;  // 98

    // ---- CSR build + zeroing ----
    hipMemsetAsync(deg, 0, (size_t)NN * 4, stream);
    hipMemsetAsync(cursor, 0, (size_t)NN * 4, stream);
    hipMemsetAsync(bnbuf3, 0, 2 * NF * 4, stream);
    hipMemsetAsync(bnbuf2, 0, 2 * NC * 4, stream);
    deg_kernel<<<(NE + 255) / 256, 256, 0, stream>>>(dstv, deg);
    scan1_kernel<<<nscan, 1024, 0, stream>>>(deg, row_loc, blocksum);
    scan2_kernel<<<1, 128, 0, stream>>>(blocksum, nscan);
    scan3_kernel<<<nscan, 1024, 0, stream>>>(deg, row_loc, blocksum, row_ptr, inv_cnt);
    fill_bucket_kernel<<<FILL_CHUNKS * 8, 256, 0, stream>>>(srcv, dstv, row_ptr, cursor, csr);

    // ---- prep: x -> bf16; pack weights ----
    f2b4_kernel<<<(NN * NF / 4 + 255) / 256, 256, 0, stream>>>(x, xb, NN * NF / 4);
    pack_w_kernel<<<64, 64, 0, stream>>>(W1l, W1r, Bp1);
    pack_w_kernel<<<64, 64, 0, stream>>>(Wxl, Wxr, Bpx);
    pack_w80_kernel<<<20, 64, 0, stream>>>(W2l, W2r, Bp2);

    const int nblk_lin = (NN + 63) / 64;  // 1563

    // ---- conv1: h1 = relu([mean(x)|x] @ Bp1 + b1) -> h1b (bf16) ----
    agg_mean_bf16<<<(NN + 3) / 4, 256, 0, stream>>>(xb, csr, row_ptr, inv_cnt, aggb);
    lin_mfma_kernel<true><<<nblk_lin, 256, 0, stream>>>(aggb, xb, Bp1, b1, h1b);

    // ---- convx: h2 = [mean(h1)|h1] @ Bpx + bx -> h2b (bf16) ----
    agg_mean_bf16<<<(NN + 3) / 4, 256, 0, stream>>>(h1b, csr, row_ptr, inv_cnt, aggb);
    lin_mfma_kernel<false><<<nblk_lin, 256, 0, stream>>>(aggb, h1b, Bpx, bx, h2b);

    // ---- batch_norm3 + relu, stats on bf16 h2, in-place apply ----
    bn_stats_b16_kernel<<<BN_GRID, 256, 0, stream>>>(h2b, bnbuf3);
    bn3_apply_b16_kernel<<<(NN * NF / 2 + 255) / 256, 256, 0, stream>>>((unsigned*)h2b, bnbuf3, g3, be3, 1.0f / NN);

    // ---- conv2 (transform-first, MFMA) ----
    lin80_mfma_kernel<<<nblk_lin, 256, 0, stream>>>(h2b, Bp2, b2, t40, z40);
    agg40_add_bf16<<<(NN + 3) / 4, 256, 0, stream>>>(t40, z40, csr, row_ptr, inv_cnt, out);

    // ---- batch_norm2 (in place on out) ----
    bn_stats2_kernel<NC><<<BN_GRID, 256, 0, stream>>>(out, bnbuf2);
    bn_apply_kernel<false><<<(NN * NC + 255) / 256, 256, 0, stream>>>(out, bnbuf2, g2, be2, NC, 1.0f / NN);
}

// Round 9
// 614.939 us; speedup vs baseline: 3.1303x; 1.0274x over previous
//
#include <hip/hip_runtime.h>
#include <hip/hip_bf16.h>

#define NN 100000
#define NE 1600000
#define NF 128
#define NC 40
#define BN_EPS 1e-5f

#define NB 256          // bucket slots (power of 2); used: (NN+511)>>9 = 196
#define NBU ((NN + 511) >> 9)
#define PT_TILE 4096    // edges per partition tile
#define PT_GRID ((NE + PT_TILE - 1) / PT_TILE)  // 391

typedef __attribute__((ext_vector_type(8))) short short8;
typedef __attribute__((ext_vector_type(4))) float float4v;
typedef __attribute__((ext_vector_type(4))) int int4v;

__device__ __forceinline__ unsigned short f2b(float f) {
    __hip_bfloat16 h = __float2bfloat16(f);
    return *reinterpret_cast<unsigned short*>(&h);
}
__device__ __forceinline__ float b2f_hi(unsigned u) { return __uint_as_float(u & 0xffff0000u); }
__device__ __forceinline__ float b2f_lo(unsigned u) { return __uint_as_float(u << 16); }

// ---------------- CSR build: bucket-partitioned (single-writer regions) ----------------

// Pass A: global bucket histogram (bucket = dst >> 9, 512 nodes/bucket)
__global__ __launch_bounds__(256) void bhist_kernel(const int* __restrict__ dst,
                                                    int* __restrict__ bhist) {
    __shared__ int lh[NB];
    int tid = threadIdx.x;
    lh[tid] = 0;
    __syncthreads();
    int base = blockIdx.x * PT_TILE;
    int cnt = min(PT_TILE, NE - base);
    const int4v* d4 = (const int4v*)(dst + base);
    int cnt4 = cnt >> 2;
    for (int i = tid; i < cnt4; i += 256) {
        int4v d = __builtin_nontemporal_load(d4 + i);
        atomicAdd(&lh[d[0] >> 9], 1);
        atomicAdd(&lh[d[1] >> 9], 1);
        atomicAdd(&lh[d[2] >> 9], 1);
        atomicAdd(&lh[d[3] >> 9], 1);
    }
    __syncthreads();
    if (lh[tid]) atomicAdd(&bhist[tid], lh[tid]);
}

// Pass B: exclusive scan of bhist -> bbase; init bcur
__global__ __launch_bounds__(256) void bscan_kernel(const int* __restrict__ bhist,
                                                    int* __restrict__ bbase,
                                                    int* __restrict__ bcur) {
    __shared__ int lds[NB];
    int t = threadIdx.x;
    int v = bhist[t];
    lds[t] = v;
    __syncthreads();
    for (int off = 1; off < NB; off <<= 1) {
        int u = (t >= off) ? lds[t - off] : 0;
        __syncthreads();
        lds[t] += u;
        __syncthreads();
    }
    int ex = lds[t] - v;
    bbase[t] = ex;
    bcur[t] = ex;
}

// Pass C: partition edges into bucket-contiguous stage[] runs.
// Each (tile,bucket) run is reserved atomically and written by ONE block in a
// short window -> full-line writebacks independent of XCD placement.
__global__ __launch_bounds__(256) void part_kernel(const int* __restrict__ src,
                                                   const int* __restrict__ dst,
                                                   int* __restrict__ bcur,
                                                   int2* __restrict__ stage) {
    __shared__ int2 pairs[PT_TILE];  // 32 KB
    __shared__ int lhist[NB];
    __shared__ int gbase[NB];
    int tid = threadIdx.x;
    int base = blockIdx.x * PT_TILE;
    int cnt = min(PT_TILE, NE - base);
    int cnt4 = cnt >> 2;  // NE and PT_TILE divisible by 4

    lhist[tid] = 0;
    __syncthreads();

    const int4v* d4 = (const int4v*)(dst + base);
    const int4v* s4 = (const int4v*)(src + base);
    for (int i = tid; i < cnt4; i += 256) {
        int4v d = __builtin_nontemporal_load(d4 + i);
        int4v s = __builtin_nontemporal_load(s4 + i);
#pragma unroll
        for (int j = 0; j < 4; ++j) {
            pairs[j * cnt4 + i] = make_int2(d[j], s[j]);
            atomicAdd(&lhist[d[j] >> 9], 1);
        }
    }
    __syncthreads();

    int c = lhist[tid];
    gbase[tid] = (c > 0) ? atomicAdd(&bcur[tid], c) : 0;
    lhist[tid] = 0;  // becomes local scatter cursor
    __syncthreads();

    for (int k = tid; k < cnt; k += 256) {
        int2 p = pairs[k];
        int b = p.x >> 9;
        int pos = atomicAdd(&lhist[b], 1);
        stage[gbase[b] + pos] = p;
    }
}

// Pass D1: per-bucket degree count (atomics confined to 2 KB of deg per block)
__global__ __launch_bounds__(256) void bucket_deg_kernel(const long long* __restrict__ stage,
                                                         const int* __restrict__ bbase,
                                                         const int* __restrict__ bcur,
                                                         int* __restrict__ deg) {
    int b = blockIdx.x;
    int s = bbase[b], e = bcur[b];
    for (int i = s + threadIdx.x; i < e; i += 256) {
        long long p = __builtin_nontemporal_load(stage + i);
        int d = (int)(p & 0xffffffffLL);
        atomicAdd(&deg[d], 1);
    }
}

// row_ptr scan (unchanged)
__global__ __launch_bounds__(1024) void scan1_kernel(const int* __restrict__ deg,
                                                     int* __restrict__ row_loc,
                                                     int* __restrict__ blocksum) {
    __shared__ int lds[1024];
    int t = threadIdx.x;
    int i = blockIdx.x * 1024 + t;
    int v = (i < NN) ? deg[i] : 0;
    lds[t] = v;
    __syncthreads();
    for (int off = 1; off < 1024; off <<= 1) {
        int u = (t >= off) ? lds[t - off] : 0;
        __syncthreads();
        lds[t] += u;
        __syncthreads();
    }
    if (i < NN) row_loc[i] = lds[t] - v;
    if (t == 1023) blocksum[blockIdx.x] = lds[1023];
}

__global__ __launch_bounds__(128) void scan2_kernel(int* __restrict__ blocksum, int nb) {
    __shared__ int lds[128];
    int t = threadIdx.x;
    int v = (t < nb) ? blocksum[t] : 0;
    lds[t] = v;
    __syncthreads();
    for (int off = 1; off < 128; off <<= 1) {
        int u = (t >= off) ? lds[t - off] : 0;
        __syncthreads();
        lds[t] += u;
        __syncthreads();
    }
    if (t < nb) blocksum[t] = lds[t] - v;
}

__global__ __launch_bounds__(1024) void scan3_kernel(const int* __restrict__ deg,
                                                     const int* __restrict__ row_loc,
                                                     const int* __restrict__ blockoff,
                                                     int* __restrict__ row_ptr,
                                                     float* __restrict__ inv_cnt) {
    int i = blockIdx.x * 1024 + threadIdx.x;
    if (i < NN) {
        row_ptr[i] = blockoff[blockIdx.x] + row_loc[i];
        int d = deg[i];
        inv_cnt[i] = 1.0f / (float)(d > 0 ? d : 1);
    }
    if (i == 0) row_ptr[NN] = NE;
}

// Pass D2: per-bucket CSR fill; csr writes confined to the bucket's ~32 KB
// segment, written by ONE block -> full-line writebacks.
__global__ __launch_bounds__(256) void bucket_fill_kernel(const long long* __restrict__ stage,
                                                          const int* __restrict__ bbase,
                                                          const int* __restrict__ bcur,
                                                          const int* __restrict__ row_ptr,
                                                          int* __restrict__ cursor,
                                                          int* __restrict__ csr) {
    int b = blockIdx.x;
    int s = bbase[b], e = bcur[b];
    for (int i = s + threadIdx.x; i < e; i += 256) {
        long long p = __builtin_nontemporal_load(stage + i);
        int d = (int)(p & 0xffffffffLL);
        int sv = (int)(p >> 32);
        int pos = atomicAdd(&cursor[d], 1);
        csr[row_ptr[d] + pos] = sv;
    }
}

// ---------------- fp32 -> bf16 bulk convert ----------------

__global__ __launch_bounds__(256) void f2b4_kernel(const float* __restrict__ in,
                                                   unsigned short* __restrict__ out, int n4) {
    int i = blockIdx.x * 256 + threadIdx.x;
    if (i < n4) {
        float4 v = ((const float4*)in)[i];
        ushort4 o;
        o.x = f2b(v.x); o.y = f2b(v.y); o.z = f2b(v.z); o.w = f2b(v.w);
        ((ushort4*)out)[i] = o;
    }
}

// ---------------- pack W into MFMA B-fragment order (K=256, N=128) ----------------

__global__ __launch_bounds__(64) void pack_w_kernel(const float* __restrict__ Wl,
                                                    const float* __restrict__ Wr,
                                                    unsigned short* __restrict__ Bp) {
    int nt = blockIdx.x & 7;
    int kk = blockIdx.x >> 3;
    int lane = threadIdx.x;
    int n = nt * 16 + (lane & 15);
    int kb = kk * 32 + (lane >> 4) * 8;
    size_t base = ((size_t)(kk * 8 + nt) * 64 + lane) * 8;
#pragma unroll
    for (int j = 0; j < 8; ++j) {
        int k = kb + j;
        float v = (k < NF) ? Wl[(size_t)n * NF + k] : Wr[(size_t)n * NF + (k - NF)];
        Bp[base + j] = f2b(v);
    }
}

// pack for conv2: K=128, N=80 (cols 0..39 = W2l, 40..79 = W2r). 20 blocks.
__global__ __launch_bounds__(64) void pack_w80_kernel(const float* __restrict__ Wl,
                                                      const float* __restrict__ Wr,
                                                      unsigned short* __restrict__ Bp) {
    int nt = blockIdx.x % 5;
    int kk = blockIdx.x / 5;
    int lane = threadIdx.x;
    int n = nt * 16 + (lane & 15);
    int kb = kk * 32 + (lane >> 4) * 8;
    size_t base = ((size_t)(kk * 5 + nt) * 64 + lane) * 8;
#pragma unroll
    for (int j = 0; j < 8; ++j) {
        int k = kb + j;
        float v = (n < NC) ? Wl[(size_t)n * NF + k] : Wr[(size_t)(n - NC) * NF + k];
        Bp[base + j] = f2b(v);
    }
}

// ---------------- mean aggregation over CSR (bf16 table, fp32 accum) ----------------

__global__ __launch_bounds__(256) void agg_mean_bf16(const unsigned short* __restrict__ X,
                                                     const int* __restrict__ csr,
                                                     const int* __restrict__ row_ptr,
                                                     const float* __restrict__ inv_cnt,
                                                     unsigned short* __restrict__ out) {
    int wave = threadIdx.x >> 6;
    int lane = threadIdx.x & 63;
    int n = blockIdx.x * 4 + wave;
    if (n >= NN) return;
    int s = row_ptr[n], e = row_ptr[n + 1];
    float a0 = 0.f, a1 = 0.f;
    int i = s;
    for (; i + 8 <= e; i += 8) {
        int s0 = csr[i],     s1 = csr[i + 1], s2 = csr[i + 2], s3 = csr[i + 3];
        int s4 = csr[i + 4], s5 = csr[i + 5], s6 = csr[i + 6], s7 = csr[i + 7];
        unsigned u0 = *(const unsigned*)(X + (size_t)s0 * NF + lane * 2);
        unsigned u1 = *(const unsigned*)(X + (size_t)s1 * NF + lane * 2);
        unsigned u2 = *(const unsigned*)(X + (size_t)s2 * NF + lane * 2);
        unsigned u3 = *(const unsigned*)(X + (size_t)s3 * NF + lane * 2);
        unsigned u4 = *(const unsigned*)(X + (size_t)s4 * NF + lane * 2);
        unsigned u5 = *(const unsigned*)(X + (size_t)s5 * NF + lane * 2);
        unsigned u6 = *(const unsigned*)(X + (size_t)s6 * NF + lane * 2);
        unsigned u7 = *(const unsigned*)(X + (size_t)s7 * NF + lane * 2);
        a0 += b2f_lo(u0) + b2f_lo(u1) + b2f_lo(u2) + b2f_lo(u3)
            + b2f_lo(u4) + b2f_lo(u5) + b2f_lo(u6) + b2f_lo(u7);
        a1 += b2f_hi(u0) + b2f_hi(u1) + b2f_hi(u2) + b2f_hi(u3)
            + b2f_hi(u4) + b2f_hi(u5) + b2f_hi(u6) + b2f_hi(u7);
    }
    for (; i + 4 <= e; i += 4) {
        int s0 = csr[i], s1 = csr[i + 1], s2 = csr[i + 2], s3 = csr[i + 3];
        unsigned u0 = *(const unsigned*)(X + (size_t)s0 * NF + lane * 2);
        unsigned u1 = *(const unsigned*)(X + (size_t)s1 * NF + lane * 2);
        unsigned u2 = *(const unsigned*)(X + (size_t)s2 * NF + lane * 2);
        unsigned u3 = *(const unsigned*)(X + (size_t)s3 * NF + lane * 2);
        a0 += b2f_lo(u0) + b2f_lo(u1) + b2f_lo(u2) + b2f_lo(u3);
        a1 += b2f_hi(u0) + b2f_hi(u1) + b2f_hi(u2) + b2f_hi(u3);
    }
    for (; i < e; ++i) {
        unsigned u = *(const unsigned*)(X + (size_t)csr[i] * NF + lane * 2);
        a0 += b2f_lo(u);
        a1 += b2f_hi(u);
    }
    float ic = inv_cnt[n];
    unsigned short o0 = f2b(a0 * ic), o1 = f2b(a1 * ic);
    *(unsigned*)(out + (size_t)n * NF + lane * 2) = (unsigned)o0 | ((unsigned)o1 << 16);
}

// ---------------- MFMA linear (128-out, K=256), NO LDS ----------------

template <bool RELU>
__global__ __launch_bounds__(256, 5) void lin_mfma_kernel(const unsigned short* __restrict__ Ab,
                                                          const unsigned short* __restrict__ Xb,
                                                          const unsigned short* __restrict__ Bp,
                                                          const float* __restrict__ bias,
                                                          unsigned short* __restrict__ outb) {
    int tid = threadIdx.x;
    int wave = tid >> 6;
    int lane = tid & 63;
    int quad = lane >> 4;
    int row = blockIdx.x * 64 + wave * 16 + (lane & 15);
    int rowc = row < NN ? row : (NN - 1);
    const unsigned short* arow = Ab + (size_t)rowc * NF;
    const unsigned short* xrow = Xb + (size_t)rowc * NF;
    const short8* Bv = (const short8*)Bp;

    float4v acc[8];
#pragma unroll
    for (int nt = 0; nt < 8; ++nt) acc[nt] = (float4v){0.f, 0.f, 0.f, 0.f};

#pragma unroll
    for (int kk = 0; kk < 8; ++kk) {
        int kb = (kk & 3) * 32 + quad * 8;
        const unsigned short* asrc = (kk < 4) ? arow : xrow;
        short8 afrag = *(const short8*)(asrc + kb);
#pragma unroll
        for (int nt = 0; nt < 8; ++nt) {
            short8 bfrag = Bv[(kk * 8 + nt) * 64 + lane];
            acc[nt] = __builtin_amdgcn_mfma_f32_16x16x32_bf16(afrag, bfrag, acc[nt], 0, 0, 0);
        }
    }

    int orow = blockIdx.x * 64 + wave * 16 + quad * 4;
    int col = lane & 15;
#pragma unroll
    for (int nt = 0; nt < 8; ++nt) {
        int c = nt * 16 + col;
        float bv = bias[c];
#pragma unroll
        for (int r = 0; r < 4; ++r) {
            int rr = orow + r;
            if (rr < NN) {
                float v = acc[nt][r] + bv;
                if (RELU) v = fmaxf(v, 0.f);
                outb[(size_t)rr * NF + c] = f2b(v);
            }
        }
    }
}

// ---------------- MFMA linear for conv2 (80-out, K=128), NO LDS ----------------

__global__ __launch_bounds__(256, 5) void lin80_mfma_kernel(const unsigned short* __restrict__ Xb,
                                                            const unsigned short* __restrict__ Bp,
                                                            const float* __restrict__ b2,
                                                            unsigned short* __restrict__ t40,
                                                            float* __restrict__ z40) {
    int tid = threadIdx.x;
    int wave = tid >> 6;
    int lane = tid & 63;
    int quad = lane >> 4;
    int row = blockIdx.x * 64 + wave * 16 + (lane & 15);
    int rowc = row < NN ? row : (NN - 1);
    const unsigned short* xrow = Xb + (size_t)rowc * NF;
    const short8* Bv = (const short8*)Bp;

    float4v acc[5];
#pragma unroll
    for (int nt = 0; nt < 5; ++nt) acc[nt] = (float4v){0.f, 0.f, 0.f, 0.f};

#pragma unroll
    for (int kk = 0; kk < 4; ++kk) {
        int kb = kk * 32 + quad * 8;
        short8 afrag = *(const short8*)(xrow + kb);
#pragma unroll
        for (int nt = 0; nt < 5; ++nt) {
            short8 bfrag = Bv[(kk * 5 + nt) * 64 + lane];
            acc[nt] = __builtin_amdgcn_mfma_f32_16x16x32_bf16(afrag, bfrag, acc[nt], 0, 0, 0);
        }
    }

    int orow = blockIdx.x * 64 + wave * 16 + quad * 4;
    int col = lane & 15;
#pragma unroll
    for (int nt = 0; nt < 5; ++nt) {
        int c = nt * 16 + col;
#pragma unroll
        for (int r = 0; r < 4; ++r) {
            int rr = orow + r;
            if (rr < NN) {
                float v = acc[nt][r];
                if (c < NC) {
                    t40[(size_t)rr * NC + c] = f2b(v);
                } else {
                    z40[(size_t)rr * NC + (c - NC)] = v + b2[c - NC];
                }
            }
        }
    }
}

// lanes 0..19 each own feature pair (2*lane, 2*lane+1); T is bf16; 8-deep unroll
__global__ __launch_bounds__(256) void agg40_add_bf16(const unsigned short* __restrict__ T,
                                                      const float* __restrict__ Z,
                                                      const int* __restrict__ csr,
                                                      const int* __restrict__ row_ptr,
                                                      const float* __restrict__ inv_cnt,
                                                      float* __restrict__ out) {
    int wave = threadIdx.x >> 6;
    int lane = threadIdx.x & 63;
    int n = blockIdx.x * 4 + wave;
    if (n >= NN || lane >= 20) return;
    int s = row_ptr[n], e = row_ptr[n + 1];
    float a0 = 0.f, a1 = 0.f;
    int i = s;
    for (; i + 8 <= e; i += 8) {
        int s0 = csr[i],     s1 = csr[i + 1], s2 = csr[i + 2], s3 = csr[i + 3];
        int s4 = csr[i + 4], s5 = csr[i + 5], s6 = csr[i + 6], s7 = csr[i + 7];
        unsigned u0 = *(const unsigned*)(T + (size_t)s0 * NC + lane * 2);
        unsigned u1 = *(const unsigned*)(T + (size_t)s1 * NC + lane * 2);
        unsigned u2 = *(const unsigned*)(T + (size_t)s2 * NC + lane * 2);
        unsigned u3 = *(const unsigned*)(T + (size_t)s3 * NC + lane * 2);
        unsigned u4 = *(const unsigned*)(T + (size_t)s4 * NC + lane * 2);
        unsigned u5 = *(const unsigned*)(T + (size_t)s5 * NC + lane * 2);
        unsigned u6 = *(const unsigned*)(T + (size_t)s6 * NC + lane * 2);
        unsigned u7 = *(const unsigned*)(T + (size_t)s7 * NC + lane * 2);
        a0 += b2f_lo(u0) + b2f_lo(u1) + b2f_lo(u2) + b2f_lo(u3)
            + b2f_lo(u4) + b2f_lo(u5) + b2f_lo(u6) + b2f_lo(u7);
        a1 += b2f_hi(u0) + b2f_hi(u1) + b2f_hi(u2) + b2f_hi(u3)
            + b2f_hi(u4) + b2f_hi(u5) + b2f_hi(u6) + b2f_hi(u7);
    }
    for (; i + 4 <= e; i += 4) {
        int s0 = csr[i], s1 = csr[i + 1], s2 = csr[i + 2], s3 = csr[i + 3];
        unsigned u0 = *(const unsigned*)(T + (size_t)s0 * NC + lane * 2);
        unsigned u1 = *(const unsigned*)(T + (size_t)s1 * NC + lane * 2);
        unsigned u2 = *(const unsigned*)(T + (size_t)s2 * NC + lane * 2);
        unsigned u3 = *(const unsigned*)(T + (size_t)s3 * NC + lane * 2);
        a0 += b2f_lo(u0) + b2f_lo(u1) + b2f_lo(u2) + b2f_lo(u3);
        a1 += b2f_hi(u0) + b2f_hi(u1) + b2f_hi(u2) + b2f_hi(u3);
    }
    for (; i < e; ++i) {
        unsigned u = *(const unsigned*)(T + (size_t)csr[i] * NC + lane * 2);
        a0 += b2f_lo(u);
        a1 += b2f_hi(u);
    }
    float ic = inv_cnt[n];
    const float2 zv = *(const float2*)(Z + (size_t)n * NC + lane * 2);
    float2 o;
    o.x = a0 * ic + zv.x;
    o.y = a1 * ic + zv.y;
    *(float2*)(out + (size_t)n * NC + lane * 2) = o;
}

// ---------------- batch norm ----------------
#define BN_GRID 640  // 640*256 divisible by 10 (F=40)

template <int F>
__global__ __launch_bounds__(256) void bn_stats2_kernel(const float* __restrict__ X,
                                                        float* __restrict__ sums) {
    __shared__ float ls[2 * F];
    int tid = threadIdx.x;
    for (int i = tid; i < 2 * F; i += 256) ls[i] = 0.f;
    __syncthreads();

    const int total4 = NN * F / 4;
    const int stride = BN_GRID * 256;
    int i0 = blockIdx.x * 256 + tid;
    int c0 = (i0 * 4) % F;
    float s0 = 0.f, s1 = 0.f, s2 = 0.f, s3 = 0.f;
    float q0 = 0.f, q1 = 0.f, q2 = 0.f, q3 = 0.f;
    for (int i = i0; i < total4; i += stride) {
        float4 v = ((const float4*)X)[i];
        s0 += v.x; q0 += v.x * v.x;
        s1 += v.y; q1 += v.y * v.y;
        s2 += v.z; q2 += v.z * v.z;
        s3 += v.w; q3 += v.w * v.w;
    }
    atomicAdd(&ls[c0 + 0], s0); atomicAdd(&ls[F + c0 + 0], q0);
    atomicAdd(&ls[c0 + 1], s1); atomicAdd(&ls[F + c0 + 1], q1);
    atomicAdd(&ls[c0 + 2], s2); atomicAdd(&ls[F + c0 + 2], q2);
    atomicAdd(&ls[c0 + 3], s3); atomicAdd(&ls[F + c0 + 3], q3);
    __syncthreads();
    for (int i = tid; i < 2 * F; i += 256) atomicAdd(&sums[i], ls[i]);
}

__global__ __launch_bounds__(256) void bn_stats_b16_kernel(const unsigned short* __restrict__ H,
                                                           float* __restrict__ sums) {
    __shared__ float ls[2 * NF];
    int tid = threadIdx.x;
    for (int i = tid; i < 2 * NF; i += 256) ls[i] = 0.f;
    __syncthreads();

    const int total8 = NN * NF / 8;
    const int stride = BN_GRID * 256;
    int i0 = blockIdx.x * 256 + tid;
    int c0 = (i0 * 8) & (NF - 1);
    float s[8], q[8];
#pragma unroll
    for (int j = 0; j < 8; ++j) { s[j] = 0.f; q[j] = 0.f; }
    for (int i = i0; i < total8; i += stride) {
        uint4 u = ((const uint4*)H)[i];
        float v;
        v = b2f_lo(u.x); s[0] += v; q[0] += v * v;
        v = b2f_hi(u.x); s[1] += v; q[1] += v * v;
        v = b2f_lo(u.y); s[2] += v; q[2] += v * v;
        v = b2f_hi(u.y); s[3] += v; q[3] += v * v;
        v = b2f_lo(u.z); s[4] += v; q[4] += v * v;
        v = b2f_hi(u.z); s[5] += v; q[5] += v * v;
        v = b2f_lo(u.w); s[6] += v; q[6] += v * v;
        v = b2f_hi(u.w); s[7] += v; q[7] += v * v;
    }
#pragma unroll
    for (int j = 0; j < 8; ++j) {
        atomicAdd(&ls[c0 + j], s[j]);
        atomicAdd(&ls[NF + c0 + j], q[j]);
    }
    __syncthreads();
    for (int i = tid; i < 2 * NF; i += 256) atomicAdd(&sums[i], ls[i]);
}

__global__ __launch_bounds__(256) void bn3_apply_b16_kernel(unsigned* __restrict__ H,
                                                            const float* __restrict__ sums,
                                                            const float* __restrict__ g,
                                                            const float* __restrict__ be,
                                                            float invN) {
    int idx = blockIdx.x * 256 + threadIdx.x;
    if (idx >= NN * NF / 2) return;
    int t0 = (idx * 2) & (NF - 1);
    float mu0 = sums[t0] * invN, mu1 = sums[t0 + 1] * invN;
    float var0 = sums[NF + t0] * invN - mu0 * mu0;
    float var1 = sums[NF + t0 + 1] * invN - mu1 * mu1;
    float sc0 = rsqrtf(var0 + BN_EPS) * g[t0];
    float sc1 = rsqrtf(var1 + BN_EPS) * g[t0 + 1];
    unsigned u = H[idx];
    float v0 = fmaxf((b2f_lo(u) - mu0) * sc0 + be[t0], 0.f);
    float v1 = fmaxf((b2f_hi(u) - mu1) * sc1 + be[t0 + 1], 0.f);
    H[idx] = (unsigned)f2b(v0) | ((unsigned)f2b(v1) << 16);
}

template <bool RELU>
__global__ __launch_bounds__(256) void bn_apply_kernel(float* __restrict__ X,
                                                       const float* __restrict__ sums,
                                                       const float* __restrict__ g,
                                                       const float* __restrict__ be,
                                                       int F, float invN) {
    size_t idx = (size_t)blockIdx.x * blockDim.x + threadIdx.x;
    size_t total = (size_t)NN * F;
    if (idx >= total) return;
    int t = (int)(idx % F);
    float mu = sums[t] * invN;
    float var = sums[F + t] * invN - mu * mu;
    float scale = rsqrtf(var + BN_EPS) * g[t];
    float v = (X[idx] - mu) * scale + be[t];
    if (RELU) v = fmaxf(v, 0.f);
    X[idx] = v;
}

// ---------------- launch ----------------

extern "C" void kernel_launch(void* const* d_in, const int* in_sizes, int n_in,
                              void* d_out, int out_size, void* d_ws, size_t ws_size,
                              hipStream_t stream) {
    const float* x   = (const float*)d_in[0];
    const int*   ei  = (const int*)d_in[1];
    const int*   srcv = ei;
    const int*   dstv = ei + NE;
    const float* W1l = (const float*)d_in[2];
    const float* b1  = (const float*)d_in[3];
    const float* W1r = (const float*)d_in[4];
    const float* Wxl = (const float*)d_in[5];
    const float* bx  = (const float*)d_in[6];
    const float* Wxr = (const float*)d_in[7];
    const float* W2l = (const float*)d_in[8];
    const float* b2  = (const float*)d_in[9];
    const float* W2r = (const float*)d_in[10];
    const float* g3  = (const float*)d_in[11];
    const float* be3 = (const float*)d_in[12];
    const float* g2  = (const float*)d_in[13];
    const float* be2 = (const float*)d_in[14];
    float* out = (float*)d_out;

    // workspace carve (16B aligned)
    char* w = (char*)d_ws;
    unsigned short* xb   = (unsigned short*)w; w += (size_t)NN * NF * 2;   // 25.6 MB
    unsigned short* h1b  = (unsigned short*)w; w += (size_t)NN * NF * 2;   // 25.6 MB
    unsigned short* aggb = (unsigned short*)w; w += (size_t)NN * NF * 2;   // 25.6 MB
    unsigned short* h2b  = (unsigned short*)w; w += (size_t)NN * NF * 2;   // 25.6 MB
    int* csr     = (int*)w; w += (size_t)NE * 4;                           // 6.4 MB
    int* row_ptr = (int*)w; w += (size_t)(NN + 4) * 4;
    int* deg     = (int*)w; w += (size_t)NN * 4;
    int* cursor  = (int*)w; w += (size_t)NN * 4;
    int* row_loc = (int*)w; w += (size_t)NN * 4;
    int* blocksum = (int*)w; w += 128 * 4;
    float* inv_cnt = (float*)w; w += (size_t)NN * 4;
    float* bnbuf3  = (float*)w; w += 2 * NF * 4;
    float* bnbuf2  = (float*)w; w += 2 * NC * 4;
    unsigned short* Bp1 = (unsigned short*)w; w += (size_t)256 * NF * 2;   // 64 KB
    unsigned short* Bpx = (unsigned short*)w; w += (size_t)256 * NF * 2;   // 64 KB
    unsigned short* Bp2 = (unsigned short*)w; w += (size_t)128 * 80 * 2;   // 20 KB
    int* bhist = (int*)w; w += NB * 4;
    int* bbase = (int*)w; w += NB * 4;
    int* bcurA = (int*)w; w += NB * 4;
    // overlays
    int2* stage = (int2*)h2b;        // 12.8 MB, dead until convx writes h2b
    unsigned short* t40 = xb;        // dead after conv1
    float* z40 = (float*)h1b;        // dead after convx

    const int nscan = (NN + 1023) / 1024;  // 98

    // ---- zeroing ----
    hipMemsetAsync(deg, 0, (size_t)NN * 4, stream);
    hipMemsetAsync(cursor, 0, (size_t)NN * 4, stream);
    hipMemsetAsync(bhist, 0, NB * 4, stream);
    hipMemsetAsync(bnbuf3, 0, 2 * NF * 4, stream);
    hipMemsetAsync(bnbuf2, 0, 2 * NC * 4, stream);

    // ---- CSR build: bucket partition (single-writer regions) ----
    bhist_kernel<<<PT_GRID, 256, 0, stream>>>(dstv, bhist);
    bscan_kernel<<<1, 256, 0, stream>>>(bhist, bbase, bcurA);
    part_kernel<<<PT_GRID, 256, 0, stream>>>(srcv, dstv, bcurA, stage);
    bucket_deg_kernel<<<NBU, 256, 0, stream>>>((const long long*)stage, bbase, bcurA, deg);
    scan1_kernel<<<nscan, 1024, 0, stream>>>(deg, row_loc, blocksum);
    scan2_kernel<<<1, 128, 0, stream>>>(blocksum, nscan);
    scan3_kernel<<<nscan, 1024, 0, stream>>>(deg, row_loc, blocksum, row_ptr, inv_cnt);
    bucket_fill_kernel<<<NBU, 256, 0, stream>>>((const long long*)stage, bbase, bcurA,
                                                row_ptr, cursor, csr);

    // ---- prep: x -> bf16; pack weights ----
    f2b4_kernel<<<(NN * NF / 4 + 255) / 256, 256, 0, stream>>>(x, xb, NN * NF / 4);
    pack_w_kernel<<<64, 64, 0, stream>>>(W1l, W1r, Bp1);
    pack_w_kernel<<<64, 64, 0, stream>>>(Wxl, Wxr, Bpx);
    pack_w80_kernel<<<20, 64, 0, stream>>>(W2l, W2r, Bp2);

    const int nblk_lin = (NN + 63) / 64;  // 1563

    // ---- conv1: h1 = relu([mean(x)|x] @ Bp1 + b1) -> h1b (bf16) ----
    agg_mean_bf16<<<(NN + 3) / 4, 256, 0, stream>>>(xb, csr, row_ptr, inv_cnt, aggb);
    lin_mfma_kernel<true><<<nblk_lin, 256, 0, stream>>>(aggb, xb, Bp1, b1, h1b);

    // ---- convx: h2 = [mean(h1)|h1] @ Bpx + bx -> h2b (bf16; stage is dead now) ----
    agg_mean_bf16<<<(NN + 3) / 4, 256, 0, stream>>>(h1b, csr, row_ptr, inv_cnt, aggb);
    lin_mfma_kernel<false><<<nblk_lin, 256, 0, stream>>>(aggb, h1b, Bpx, bx, h2b);

    // ---- batch_norm3 + relu, stats on bf16 h2, in-place apply ----
    bn_stats_b16_kernel<<<BN_GRID, 256, 0, stream>>>(h2b, bnbuf3);
    bn3_apply_b16_kernel<<<(NN * NF / 2 + 255) / 256, 256, 0, stream>>>((unsigned*)h2b, bnbuf3, g3, be3, 1.0f / NN);

    // ---- conv2 (transform-first, MFMA) ----
    lin80_mfma_kernel<<<nblk_lin, 256, 0, stream>>>(h2b, Bp2, b2, t40, z40);
    agg40_add_bf16<<<(NN + 3) / 4, 256, 0, stream>>>(t40, z40, csr, row_ptr, inv_cnt, out);

    // ---- batch_norm2 (in place on out) ----
    bn_stats2_kernel<NC><<<BN_GRID, 256, 0, stream>>>(out, bnbuf2);
    bn_apply_kernel<false><<<(NN * NC + 255) / 256, 256, 0, stream>>>(out, bnbuf2, g2, be2, NC, 1.0f / NN);
}

// Round 10
// 585.342 us; speedup vs baseline: 3.2886x; 1.0506x over previous
//
#include <hip/hip_runtime.h>
#include <hip/hip_bf16.h>

#define NN 100000
#define NE 1600000
#define NF 128
#define NC 40
#define BN_EPS 1e-5f

#define NB 256          // bucket slots (power of 2); used: (NN+511)>>9 = 196
#define NBU ((NN + 511) >> 9)
#define PT_TILE 4096    // edges per partition tile
#define PT_GRID ((NE + PT_TILE - 1) / PT_TILE)  // 391

typedef __attribute__((ext_vector_type(8))) short short8;
typedef __attribute__((ext_vector_type(4))) float float4v;
typedef __attribute__((ext_vector_type(4))) int int4v;

__device__ __forceinline__ unsigned short f2b(float f) {
    __hip_bfloat16 h = __float2bfloat16(f);
    return *reinterpret_cast<unsigned short*>(&h);
}
__device__ __forceinline__ float b2f_hi(unsigned u) { return __uint_as_float(u & 0xffff0000u); }
__device__ __forceinline__ float b2f_lo(unsigned u) { return __uint_as_float(u << 16); }

// ---------------- CSR build: bucket-partitioned (single-writer regions) ----------------

__global__ __launch_bounds__(256) void bhist_kernel(const int* __restrict__ dst,
                                                    int* __restrict__ bhist) {
    __shared__ int lh[NB];
    int tid = threadIdx.x;
    lh[tid] = 0;
    __syncthreads();
    int base = blockIdx.x * PT_TILE;
    int cnt = min(PT_TILE, NE - base);
    const int4v* d4 = (const int4v*)(dst + base);
    int cnt4 = cnt >> 2;
    for (int i = tid; i < cnt4; i += 256) {
        int4v d = __builtin_nontemporal_load(d4 + i);
        atomicAdd(&lh[d[0] >> 9], 1);
        atomicAdd(&lh[d[1] >> 9], 1);
        atomicAdd(&lh[d[2] >> 9], 1);
        atomicAdd(&lh[d[3] >> 9], 1);
    }
    __syncthreads();
    if (lh[tid]) atomicAdd(&bhist[tid], lh[tid]);
}

__global__ __launch_bounds__(256) void bscan_kernel(const int* __restrict__ bhist,
                                                    int* __restrict__ bbase,
                                                    int* __restrict__ bcur) {
    __shared__ int lds[NB];
    int t = threadIdx.x;
    int v = bhist[t];
    lds[t] = v;
    __syncthreads();
    for (int off = 1; off < NB; off <<= 1) {
        int u = (t >= off) ? lds[t - off] : 0;
        __syncthreads();
        lds[t] += u;
        __syncthreads();
    }
    int ex = lds[t] - v;
    bbase[t] = ex;
    bcur[t] = ex;
}

__global__ __launch_bounds__(256) void part_kernel(const int* __restrict__ src,
                                                   const int* __restrict__ dst,
                                                   int* __restrict__ bcur,
                                                   int2* __restrict__ stage) {
    __shared__ int2 pairs[PT_TILE];  // 32 KB
    __shared__ int lhist[NB];
    __shared__ int gbase[NB];
    int tid = threadIdx.x;
    int base = blockIdx.x * PT_TILE;
    int cnt = min(PT_TILE, NE - base);
    int cnt4 = cnt >> 2;

    lhist[tid] = 0;
    __syncthreads();

    const int4v* d4 = (const int4v*)(dst + base);
    const int4v* s4 = (const int4v*)(src + base);
    for (int i = tid; i < cnt4; i += 256) {
        int4v d = __builtin_nontemporal_load(d4 + i);
        int4v s = __builtin_nontemporal_load(s4 + i);
#pragma unroll
        for (int j = 0; j < 4; ++j) {
            pairs[j * cnt4 + i] = make_int2(d[j], s[j]);
            atomicAdd(&lhist[d[j] >> 9], 1);
        }
    }
    __syncthreads();

    int c = lhist[tid];
    gbase[tid] = (c > 0) ? atomicAdd(&bcur[tid], c) : 0;
    lhist[tid] = 0;
    __syncthreads();

    for (int k = tid; k < cnt; k += 256) {
        int2 p = pairs[k];
        int b = p.x >> 9;
        int pos = atomicAdd(&lhist[b], 1);
        stage[gbase[b] + pos] = p;
    }
}

__global__ __launch_bounds__(256) void bucket_deg_kernel(const long long* __restrict__ stage,
                                                         const int* __restrict__ bbase,
                                                         const int* __restrict__ bcur,
                                                         int* __restrict__ deg) {
    int b = blockIdx.x;
    int s = bbase[b], e = bcur[b];
    for (int i = s + threadIdx.x; i < e; i += 256) {
        long long p = __builtin_nontemporal_load(stage + i);
        int d = (int)(p & 0xffffffffLL);
        atomicAdd(&deg[d], 1);
    }
}

__global__ __launch_bounds__(1024) void scan1_kernel(const int* __restrict__ deg,
                                                     int* __restrict__ row_loc,
                                                     int* __restrict__ blocksum) {
    __shared__ int lds[1024];
    int t = threadIdx.x;
    int i = blockIdx.x * 1024 + t;
    int v = (i < NN) ? deg[i] : 0;
    lds[t] = v;
    __syncthreads();
    for (int off = 1; off < 1024; off <<= 1) {
        int u = (t >= off) ? lds[t - off] : 0;
        __syncthreads();
        lds[t] += u;
        __syncthreads();
    }
    if (i < NN) row_loc[i] = lds[t] - v;
    if (t == 1023) blocksum[blockIdx.x] = lds[1023];
}

__global__ __launch_bounds__(128) void scan2_kernel(int* __restrict__ blocksum, int nb) {
    __shared__ int lds[128];
    int t = threadIdx.x;
    int v = (t < nb) ? blocksum[t] : 0;
    lds[t] = v;
    __syncthreads();
    for (int off = 1; off < 128; off <<= 1) {
        int u = (t >= off) ? lds[t - off] : 0;
        __syncthreads();
        lds[t] += u;
        __syncthreads();
    }
    if (t < nb) blocksum[t] = lds[t] - v;
}

__global__ __launch_bounds__(1024) void scan3_kernel(const int* __restrict__ deg,
                                                     const int* __restrict__ row_loc,
                                                     const int* __restrict__ blockoff,
                                                     int* __restrict__ row_ptr,
                                                     float* __restrict__ inv_cnt) {
    int i = blockIdx.x * 1024 + threadIdx.x;
    if (i < NN) {
        row_ptr[i] = blockoff[blockIdx.x] + row_loc[i];
        int d = deg[i];
        inv_cnt[i] = 1.0f / (float)(d > 0 ? d : 1);
    }
    if (i == 0) row_ptr[NN] = NE;
}

__global__ __launch_bounds__(256) void bucket_fill_kernel(const long long* __restrict__ stage,
                                                          const int* __restrict__ bbase,
                                                          const int* __restrict__ bcur,
                                                          const int* __restrict__ row_ptr,
                                                          int* __restrict__ cursor,
                                                          int* __restrict__ csr) {
    int b = blockIdx.x;
    int s = bbase[b], e = bcur[b];
    for (int i = s + threadIdx.x; i < e; i += 256) {
        long long p = __builtin_nontemporal_load(stage + i);
        int d = (int)(p & 0xffffffffLL);
        int sv = (int)(p >> 32);
        int pos = atomicAdd(&cursor[d], 1);
        csr[row_ptr[d] + pos] = sv;
    }
}

// ---------------- fp32 -> bf16 bulk convert ----------------

__global__ __launch_bounds__(256) void f2b4_kernel(const float* __restrict__ in,
                                                   unsigned short* __restrict__ out, int n4) {
    int i = blockIdx.x * 256 + threadIdx.x;
    if (i < n4) {
        float4 v = ((const float4*)in)[i];
        ushort4 o;
        o.x = f2b(v.x); o.y = f2b(v.y); o.z = f2b(v.z); o.w = f2b(v.w);
        ((ushort4*)out)[i] = o;
    }
}

// ---------------- pack W into MFMA B-fragment order ----------------

__global__ __launch_bounds__(64) void pack_w_kernel(const float* __restrict__ Wl,
                                                    const float* __restrict__ Wr,
                                                    unsigned short* __restrict__ Bp) {
    int nt = blockIdx.x & 7;
    int kk = blockIdx.x >> 3;
    int lane = threadIdx.x;
    int n = nt * 16 + (lane & 15);
    int kb = kk * 32 + (lane >> 4) * 8;
    size_t base = ((size_t)(kk * 8 + nt) * 64 + lane) * 8;
#pragma unroll
    for (int j = 0; j < 8; ++j) {
        int k = kb + j;
        float v = (k < NF) ? Wl[(size_t)n * NF + k] : Wr[(size_t)n * NF + (k - NF)];
        Bp[base + j] = f2b(v);
    }
}

__global__ __launch_bounds__(64) void pack_w80_kernel(const float* __restrict__ Wl,
                                                      const float* __restrict__ Wr,
                                                      unsigned short* __restrict__ Bp) {
    int nt = blockIdx.x % 5;
    int kk = blockIdx.x / 5;
    int lane = threadIdx.x;
    int n = nt * 16 + (lane & 15);
    int kb = kk * 32 + (lane >> 4) * 8;
    size_t base = ((size_t)(kk * 5 + nt) * 64 + lane) * 8;
#pragma unroll
    for (int j = 0; j < 8; ++j) {
        int k = kb + j;
        float v = (n < NC) ? Wl[(size_t)n * NF + k] : Wr[(size_t)(n - NC) * NF + k];
        Bp[base + j] = f2b(v);
    }
}

// ---------------- mean aggregation: quarter-wave per node ----------------
// 16 lanes/node, lane owns 8 feats via one uint4 (16B) load; 4 nodes/wave,
// 16 nodes/block. ~4x fewer instruction issues per edge than wave-per-node.

__device__ __forceinline__ void acc8(float* a, uint4 u) {
    a[0] += b2f_lo(u.x); a[1] += b2f_hi(u.x);
    a[2] += b2f_lo(u.y); a[3] += b2f_hi(u.y);
    a[4] += b2f_lo(u.z); a[5] += b2f_hi(u.z);
    a[6] += b2f_lo(u.w); a[7] += b2f_hi(u.w);
}

__global__ __launch_bounds__(256) void agg_mean_bf16(const unsigned short* __restrict__ X,
                                                     const int* __restrict__ csr,
                                                     const int* __restrict__ row_ptr,
                                                     const float* __restrict__ inv_cnt,
                                                     unsigned short* __restrict__ out) {
    int tid = threadIdx.x;
    int lane = tid & 63;
    int wave = tid >> 6;
    int qw = lane >> 4;
    int sl = lane & 15;
    int n = blockIdx.x * 16 + wave * 4 + qw;
    if (n >= NN) return;
    int s = row_ptr[n], e = row_ptr[n + 1];
    int foff = sl * 8;  // feature offset (8 bf16 = 16B per lane)

    float a[8];
#pragma unroll
    for (int j = 0; j < 8; ++j) a[j] = 0.f;

    int i = s;
    for (; i + 4 <= e; i += 4) {
        int s0 = csr[i], s1 = csr[i + 1], s2 = csr[i + 2], s3 = csr[i + 3];
        uint4 u0 = *(const uint4*)(X + (size_t)s0 * NF + foff);
        uint4 u1 = *(const uint4*)(X + (size_t)s1 * NF + foff);
        uint4 u2 = *(const uint4*)(X + (size_t)s2 * NF + foff);
        uint4 u3 = *(const uint4*)(X + (size_t)s3 * NF + foff);
        acc8(a, u0); acc8(a, u1); acc8(a, u2); acc8(a, u3);
    }
    for (; i < e; ++i) {
        uint4 u = *(const uint4*)(X + (size_t)csr[i] * NF + foff);
        acc8(a, u);
    }

    float ic = inv_cnt[n];
    uint4 o;
    o.x = (unsigned)f2b(a[0] * ic) | ((unsigned)f2b(a[1] * ic) << 16);
    o.y = (unsigned)f2b(a[2] * ic) | ((unsigned)f2b(a[3] * ic) << 16);
    o.z = (unsigned)f2b(a[4] * ic) | ((unsigned)f2b(a[5] * ic) << 16);
    o.w = (unsigned)f2b(a[6] * ic) | ((unsigned)f2b(a[7] * ic) << 16);
    *(uint4*)(out + (size_t)n * NF + foff) = o;
}

// ---------------- MFMA linear (128-out, K=256), NO LDS ----------------

template <bool RELU>
__global__ __launch_bounds__(256, 5) void lin_mfma_kernel(const unsigned short* __restrict__ Ab,
                                                          const unsigned short* __restrict__ Xb,
                                                          const unsigned short* __restrict__ Bp,
                                                          const float* __restrict__ bias,
                                                          unsigned short* __restrict__ outb) {
    int tid = threadIdx.x;
    int wave = tid >> 6;
    int lane = tid & 63;
    int quad = lane >> 4;
    int row = blockIdx.x * 64 + wave * 16 + (lane & 15);
    int rowc = row < NN ? row : (NN - 1);
    const unsigned short* arow = Ab + (size_t)rowc * NF;
    const unsigned short* xrow = Xb + (size_t)rowc * NF;
    const short8* Bv = (const short8*)Bp;

    float4v acc[8];
#pragma unroll
    for (int nt = 0; nt < 8; ++nt) acc[nt] = (float4v){0.f, 0.f, 0.f, 0.f};

#pragma unroll
    for (int kk = 0; kk < 8; ++kk) {
        int kb = (kk & 3) * 32 + quad * 8;
        const unsigned short* asrc = (kk < 4) ? arow : xrow;
        short8 afrag = *(const short8*)(asrc + kb);
#pragma unroll
        for (int nt = 0; nt < 8; ++nt) {
            short8 bfrag = Bv[(kk * 8 + nt) * 64 + lane];
            acc[nt] = __builtin_amdgcn_mfma_f32_16x16x32_bf16(afrag, bfrag, acc[nt], 0, 0, 0);
        }
    }

    int orow = blockIdx.x * 64 + wave * 16 + quad * 4;
    int col = lane & 15;
#pragma unroll
    for (int nt = 0; nt < 8; ++nt) {
        int c = nt * 16 + col;
        float bv = bias[c];
#pragma unroll
        for (int r = 0; r < 4; ++r) {
            int rr = orow + r;
            if (rr < NN) {
                float v = acc[nt][r] + bv;
                if (RELU) v = fmaxf(v, 0.f);
                outb[(size_t)rr * NF + c] = f2b(v);
            }
        }
    }
}

// ---------------- MFMA linear for conv2 (80-out, K=128), NO LDS ----------------

__global__ __launch_bounds__(256, 5) void lin80_mfma_kernel(const unsigned short* __restrict__ Xb,
                                                            const unsigned short* __restrict__ Bp,
                                                            const float* __restrict__ b2,
                                                            unsigned short* __restrict__ t40,
                                                            float* __restrict__ z40) {
    int tid = threadIdx.x;
    int wave = tid >> 6;
    int lane = tid & 63;
    int quad = lane >> 4;
    int row = blockIdx.x * 64 + wave * 16 + (lane & 15);
    int rowc = row < NN ? row : (NN - 1);
    const unsigned short* xrow = Xb + (size_t)rowc * NF;
    const short8* Bv = (const short8*)Bp;

    float4v acc[5];
#pragma unroll
    for (int nt = 0; nt < 5; ++nt) acc[nt] = (float4v){0.f, 0.f, 0.f, 0.f};

#pragma unroll
    for (int kk = 0; kk < 4; ++kk) {
        int kb = kk * 32 + quad * 8;
        short8 afrag = *(const short8*)(xrow + kb);
#pragma unroll
        for (int nt = 0; nt < 5; ++nt) {
            short8 bfrag = Bv[(kk * 5 + nt) * 64 + lane];
            acc[nt] = __builtin_amdgcn_mfma_f32_16x16x32_bf16(afrag, bfrag, acc[nt], 0, 0, 0);
        }
    }

    int orow = blockIdx.x * 64 + wave * 16 + quad * 4;
    int col = lane & 15;
#pragma unroll
    for (int nt = 0; nt < 5; ++nt) {
        int c = nt * 16 + col;
#pragma unroll
        for (int r = 0; r < 4; ++r) {
            int rr = orow + r;
            if (rr < NN) {
                float v = acc[nt][r];
                if (c < NC) {
                    t40[(size_t)rr * NC + c] = f2b(v);
                } else {
                    z40[(size_t)rr * NC + (c - NC)] = v + b2[c - NC];
                }
            }
        }
    }
}

// ---------------- conv2 aggregation: 3 nodes/wave (20 lanes each) ----------------

__global__ __launch_bounds__(256) void agg40_add_bf16(const unsigned short* __restrict__ T,
                                                      const float* __restrict__ Z,
                                                      const int* __restrict__ csr,
                                                      const int* __restrict__ row_ptr,
                                                      const float* __restrict__ inv_cnt,
                                                      float* __restrict__ out) {
    int tid = threadIdx.x;
    int lane = tid & 63;
    int wave = tid >> 6;
    if (lane >= 60) return;
    int sub = lane / 20;
    int sl = lane % 20;
    int n = blockIdx.x * 12 + wave * 3 + sub;
    if (n >= NN) return;
    int s = row_ptr[n], e = row_ptr[n + 1];
    float a0 = 0.f, a1 = 0.f;
    int i = s;
    for (; i + 4 <= e; i += 4) {
        int s0 = csr[i], s1 = csr[i + 1], s2 = csr[i + 2], s3 = csr[i + 3];
        unsigned u0 = *(const unsigned*)(T + (size_t)s0 * NC + sl * 2);
        unsigned u1 = *(const unsigned*)(T + (size_t)s1 * NC + sl * 2);
        unsigned u2 = *(const unsigned*)(T + (size_t)s2 * NC + sl * 2);
        unsigned u3 = *(const unsigned*)(T + (size_t)s3 * NC + sl * 2);
        a0 += b2f_lo(u0) + b2f_lo(u1) + b2f_lo(u2) + b2f_lo(u3);
        a1 += b2f_hi(u0) + b2f_hi(u1) + b2f_hi(u2) + b2f_hi(u3);
    }
    for (; i < e; ++i) {
        unsigned u = *(const unsigned*)(T + (size_t)csr[i] * NC + sl * 2);
        a0 += b2f_lo(u);
        a1 += b2f_hi(u);
    }
    float ic = inv_cnt[n];
    const float2 zv = *(const float2*)(Z + (size_t)n * NC + sl * 2);
    float2 o;
    o.x = a0 * ic + zv.x;
    o.y = a1 * ic + zv.y;
    *(float2*)(out + (size_t)n * NC + sl * 2) = o;
}

// ---------------- batch norm ----------------
#define BN_GRID 640  // 640*256 divisible by 10 (F=40)

template <int F>
__global__ __launch_bounds__(256) void bn_stats2_kernel(const float* __restrict__ X,
                                                        float* __restrict__ sums) {
    __shared__ float ls[2 * F];
    int tid = threadIdx.x;
    for (int i = tid; i < 2 * F; i += 256) ls[i] = 0.f;
    __syncthreads();

    const int total4 = NN * F / 4;
    const int stride = BN_GRID * 256;
    int i0 = blockIdx.x * 256 + tid;
    int c0 = (i0 * 4) % F;
    float s0 = 0.f, s1 = 0.f, s2 = 0.f, s3 = 0.f;
    float q0 = 0.f, q1 = 0.f, q2 = 0.f, q3 = 0.f;
    for (int i = i0; i < total4; i += stride) {
        float4 v = ((const float4*)X)[i];
        s0 += v.x; q0 += v.x * v.x;
        s1 += v.y; q1 += v.y * v.y;
        s2 += v.z; q2 += v.z * v.z;
        s3 += v.w; q3 += v.w * v.w;
    }
    atomicAdd(&ls[c0 + 0], s0); atomicAdd(&ls[F + c0 + 0], q0);
    atomicAdd(&ls[c0 + 1], s1); atomicAdd(&ls[F + c0 + 1], q1);
    atomicAdd(&ls[c0 + 2], s2); atomicAdd(&ls[F + c0 + 2], q2);
    atomicAdd(&ls[c0 + 3], s3); atomicAdd(&ls[F + c0 + 3], q3);
    __syncthreads();
    for (int i = tid; i < 2 * F; i += 256) atomicAdd(&sums[i], ls[i]);
}

__global__ __launch_bounds__(256) void bn_stats_b16_kernel(const unsigned short* __restrict__ H,
                                                           float* __restrict__ sums) {
    __shared__ float ls[2 * NF];
    int tid = threadIdx.x;
    for (int i = tid; i < 2 * NF; i += 256) ls[i] = 0.f;
    __syncthreads();

    const int total8 = NN * NF / 8;
    const int stride = BN_GRID * 256;
    int i0 = blockIdx.x * 256 + tid;
    int c0 = (i0 * 8) & (NF - 1);
    float s[8], q[8];
#pragma unroll
    for (int j = 0; j < 8; ++j) { s[j] = 0.f; q[j] = 0.f; }
    for (int i = i0; i < total8; i += stride) {
        uint4 u = ((const uint4*)H)[i];
        float v;
        v = b2f_lo(u.x); s[0] += v; q[0] += v * v;
        v = b2f_hi(u.x); s[1] += v; q[1] += v * v;
        v = b2f_lo(u.y); s[2] += v; q[2] += v * v;
        v = b2f_hi(u.y); s[3] += v; q[3] += v * v;
        v = b2f_lo(u.z); s[4] += v; q[4] += v * v;
        v = b2f_hi(u.z); s[5] += v; q[5] += v * v;
        v = b2f_lo(u.w); s[6] += v; q[6] += v * v;
        v = b2f_hi(u.w); s[7] += v; q[7] += v * v;
    }
#pragma unroll
    for (int j = 0; j < 8; ++j) {
        atomicAdd(&ls[c0 + j], s[j]);
        atomicAdd(&ls[NF + c0 + j], q[j]);
    }
    __syncthreads();
    for (int i = tid; i < 2 * NF; i += 256) atomicAdd(&sums[i], ls[i]);
}

__global__ __launch_bounds__(256) void bn3_apply_b16_kernel(unsigned* __restrict__ H,
                                                            const float* __restrict__ sums,
                                                            const float* __restrict__ g,
                                                            const float* __restrict__ be,
                                                            float invN) {
    int idx = blockIdx.x * 256 + threadIdx.x;
    if (idx >= NN * NF / 2) return;
    int t0 = (idx * 2) & (NF - 1);
    float mu0 = sums[t0] * invN, mu1 = sums[t0 + 1] * invN;
    float var0 = sums[NF + t0] * invN - mu0 * mu0;
    float var1 = sums[NF + t0 + 1] * invN - mu1 * mu1;
    float sc0 = rsqrtf(var0 + BN_EPS) * g[t0];
    float sc1 = rsqrtf(var1 + BN_EPS) * g[t0 + 1];
    unsigned u = H[idx];
    float v0 = fmaxf((b2f_lo(u) - mu0) * sc0 + be[t0], 0.f);
    float v1 = fmaxf((b2f_hi(u) - mu1) * sc1 + be[t0 + 1], 0.f);
    H[idx] = (unsigned)f2b(v0) | ((unsigned)f2b(v1) << 16);
}

template <bool RELU>
__global__ __launch_bounds__(256) void bn_apply_kernel(float* __restrict__ X,
                                                       const float* __restrict__ sums,
                                                       const float* __restrict__ g,
                                                       const float* __restrict__ be,
                                                       int F, float invN) {
    size_t idx = (size_t)blockIdx.x * blockDim.x + threadIdx.x;
    size_t total = (size_t)NN * F;
    if (idx >= total) return;
    int t = (int)(idx % F);
    float mu = sums[t] * invN;
    float var = sums[F + t] * invN - mu * mu;
    float scale = rsqrtf(var + BN_EPS) * g[t];
    float v = (X[idx] - mu) * scale + be[t];
    if (RELU) v = fmaxf(v, 0.f);
    X[idx] = v;
}

// ---------------- launch ----------------

extern "C" void kernel_launch(void* const* d_in, const int* in_sizes, int n_in,
                              void* d_out, int out_size, void* d_ws, size_t ws_size,
                              hipStream_t stream) {
    const float* x   = (const float*)d_in[0];
    const int*   ei  = (const int*)d_in[1];
    const int*   srcv = ei;
    const int*   dstv = ei + NE;
    const float* W1l = (const float*)d_in[2];
    const float* b1  = (const float*)d_in[3];
    const float* W1r = (const float*)d_in[4];
    const float* Wxl = (const float*)d_in[5];
    const float* bx  = (const float*)d_in[6];
    const float* Wxr = (const float*)d_in[7];
    const float* W2l = (const float*)d_in[8];
    const float* b2  = (const float*)d_in[9];
    const float* W2r = (const float*)d_in[10];
    const float* g3  = (const float*)d_in[11];
    const float* be3 = (const float*)d_in[12];
    const float* g2  = (const float*)d_in[13];
    const float* be2 = (const float*)d_in[14];
    float* out = (float*)d_out;

    // workspace carve (16B aligned)
    char* w = (char*)d_ws;
    unsigned short* xb   = (unsigned short*)w; w += (size_t)NN * NF * 2;   // 25.6 MB
    unsigned short* h1b  = (unsigned short*)w; w += (size_t)NN * NF * 2;   // 25.6 MB
    unsigned short* aggb = (unsigned short*)w; w += (size_t)NN * NF * 2;   // 25.6 MB
    unsigned short* h2b  = (unsigned short*)w; w += (size_t)NN * NF * 2;   // 25.6 MB
    int* csr     = (int*)w; w += (size_t)NE * 4;                           // 6.4 MB
    int* row_ptr = (int*)w; w += (size_t)(NN + 4) * 4;
    int* deg     = (int*)w; w += (size_t)NN * 4;
    int* cursor  = (int*)w; w += (size_t)NN * 4;
    int* row_loc = (int*)w; w += (size_t)NN * 4;
    int* blocksum = (int*)w; w += 128 * 4;
    float* inv_cnt = (float*)w; w += (size_t)NN * 4;
    float* bnbuf3  = (float*)w; w += 2 * NF * 4;
    float* bnbuf2  = (float*)w; w += 2 * NC * 4;
    unsigned short* Bp1 = (unsigned short*)w; w += (size_t)256 * NF * 2;   // 64 KB
    unsigned short* Bpx = (unsigned short*)w; w += (size_t)256 * NF * 2;   // 64 KB
    unsigned short* Bp2 = (unsigned short*)w; w += (size_t)128 * 80 * 2;   // 20 KB
    int* bhist = (int*)w; w += NB * 4;
    int* bbase = (int*)w; w += NB * 4;
    int* bcurA = (int*)w; w += NB * 4;
    // overlays
    int2* stage = (int2*)h2b;        // 12.8 MB, dead until convx writes h2b
    unsigned short* t40 = xb;        // dead after conv1
    float* z40 = (float*)h1b;        // dead after convx

    const int nscan = (NN + 1023) / 1024;  // 98

    // ---- zeroing ----
    hipMemsetAsync(deg, 0, (size_t)NN * 4, stream);
    hipMemsetAsync(cursor, 0, (size_t)NN * 4, stream);
    hipMemsetAsync(bhist, 0, NB * 4, stream);
    hipMemsetAsync(bnbuf3, 0, 2 * NF * 4, stream);
    hipMemsetAsync(bnbuf2, 0, 2 * NC * 4, stream);

    // ---- CSR build: bucket partition (single-writer regions) ----
    bhist_kernel<<<PT_GRID, 256, 0, stream>>>(dstv, bhist);
    bscan_kernel<<<1, 256, 0, stream>>>(bhist, bbase, bcurA);
    part_kernel<<<PT_GRID, 256, 0, stream>>>(srcv, dstv, bcurA, stage);
    bucket_deg_kernel<<<NBU, 256, 0, stream>>>((const long long*)stage, bbase, bcurA, deg);
    scan1_kernel<<<nscan, 1024, 0, stream>>>(deg, row_loc, blocksum);
    scan2_kernel<<<1, 128, 0, stream>>>(blocksum, nscan);
    scan3_kernel<<<nscan, 1024, 0, stream>>>(deg, row_loc, blocksum, row_ptr, inv_cnt);
    bucket_fill_kernel<<<NBU, 256, 0, stream>>>((const long long*)stage, bbase, bcurA,
                                                row_ptr, cursor, csr);

    // ---- prep: x -> bf16; pack weights ----
    f2b4_kernel<<<(NN * NF / 4 + 255) / 256, 256, 0, stream>>>(x, xb, NN * NF / 4);
    pack_w_kernel<<<64, 64, 0, stream>>>(W1l, W1r, Bp1);
    pack_w_kernel<<<64, 64, 0, stream>>>(Wxl, Wxr, Bpx);
    pack_w80_kernel<<<20, 64, 0, stream>>>(W2l, W2r, Bp2);

    const int nblk_lin = (NN + 63) / 64;   // 1563
    const int nblk_agg = (NN + 15) / 16;   // 6250

    // ---- conv1: h1 = relu([mean(x)|x] @ Bp1 + b1) -> h1b (bf16) ----
    agg_mean_bf16<<<nblk_agg, 256, 0, stream>>>(xb, csr, row_ptr, inv_cnt, aggb);
    lin_mfma_kernel<true><<<nblk_lin, 256, 0, stream>>>(aggb, xb, Bp1, b1, h1b);

    // ---- convx: h2 = [mean(h1)|h1] @ Bpx + bx -> h2b (bf16; stage is dead now) ----
    agg_mean_bf16<<<nblk_agg, 256, 0, stream>>>(h1b, csr, row_ptr, inv_cnt, aggb);
    lin_mfma_kernel<false><<<nblk_lin, 256, 0, stream>>>(aggb, h1b, Bpx, bx, h2b);

    // ---- batch_norm3 + relu, stats on bf16 h2, in-place apply ----
    bn_stats_b16_kernel<<<BN_GRID, 256, 0, stream>>>(h2b, bnbuf3);
    bn3_apply_b16_kernel<<<(NN * NF / 2 + 255) / 256, 256, 0, stream>>>((unsigned*)h2b, bnbuf3, g3, be3, 1.0f / NN);

    // ---- conv2 (transform-first, MFMA) ----
    lin80_mfma_kernel<<<nblk_lin, 256, 0, stream>>>(h2b, Bp2, b2, t40, z40);
    agg40_add_bf16<<<(NN + 11) / 12, 256, 0, stream>>>(t40, z40, csr, row_ptr, inv_cnt, out);

    // ---- batch_norm2 (in place on out) ----
    bn_stats2_kernel<NC><<<BN_GRID, 256, 0, stream>>>(out, bnbuf2);
    bn_apply_kernel<false><<<(NN * NC + 255) / 256, 256, 0, stream>>>(out, bnbuf2, g2, be2, NC, 1.0f / NN);
}